// Round 2
// baseline (911.412 us; speedup 1.0000x reference)
//
#include <hip/hip_runtime.h>
#include <hip/hip_bf16.h>
#include <cstdint>
#include <cstddef>

#define NEG_SLOPE 0.2f

using frag = __attribute__((ext_vector_type(8))) short;   // 8 bf16 = 4 VGPRs
using facc = __attribute__((ext_vector_type(4))) float;   // 4 fp32 accum

__device__ __forceinline__ float bf_hi(unsigned u) {
    union { unsigned i; float f; } t; t.i = u & 0xffff0000u; return t.f;
}
__device__ __forceinline__ float bf_lo(unsigned u) {
    union { unsigned i; float f; } t; t.i = u << 16; return t.f;
}
__device__ __forceinline__ void unpack8(uint4 u, float* v) {
    v[0] = bf_lo(u.x); v[1] = bf_hi(u.x);
    v[2] = bf_lo(u.y); v[3] = bf_hi(u.y);
    v[4] = bf_lo(u.z); v[5] = bf_hi(u.z);
    v[6] = bf_lo(u.w); v[7] = bf_hi(u.w);
}

// async global->LDS, 16B per lane (wave-uniform LDS base + lane*16)
typedef const __attribute__((address_space(1))) void* gas_cptr;
typedef __attribute__((address_space(3))) void* las_ptr;
__device__ __forceinline__ void gload_lds16(const __hip_bfloat16* g, __hip_bfloat16* l) {
    __builtin_amdgcn_global_load_lds((gas_cptr)(const void*)g, (las_ptr)(void*)l, 16, 0, 0);
}

// ---------------------------------------------------------------- CSR build
__global__ void count_kernel(const int* __restrict__ dstv, int* __restrict__ cnt, int E) {
    int e = blockIdx.x * blockDim.x + threadIdx.x;
    if (e < E) atomicAdd(&cnt[dstv[e]], 1);
}

// 3-phase parallel exclusive scan
__global__ void scan_phase1(const int* __restrict__ in, int* __restrict__ out,
                            int* __restrict__ bsum, int n) {
    __shared__ int buf[1024];
    int tid = threadIdx.x;
    int i = blockIdx.x * 1024 + tid;
    int v = (i < n) ? in[i] : 0;
    buf[tid] = v;
    __syncthreads();
    for (int off = 1; off < 1024; off <<= 1) {
        int t = (tid >= off) ? buf[tid - off] : 0;
        __syncthreads();
        buf[tid] += t;
        __syncthreads();
    }
    if (i < n) out[i] = buf[tid] - v;           // exclusive
    if (tid == 1023) bsum[blockIdx.x] = buf[1023];
}

__global__ void scan_phase2(int* __restrict__ bsum, int B) {
    __shared__ int buf[1024];
    int tid = threadIdx.x;
    int v = (tid < B) ? bsum[tid] : 0;
    buf[tid] = v;
    __syncthreads();
    for (int off = 1; off < 1024; off <<= 1) {
        int t = (tid >= off) ? buf[tid - off] : 0;
        __syncthreads();
        buf[tid] += t;
        __syncthreads();
    }
    if (tid < B) bsum[tid] = buf[tid] - v;      // exclusive block offsets
    if (tid == 0) bsum[B] = buf[B - 1];         // total
}

__global__ void scan_phase3(int* __restrict__ out, const int* __restrict__ bsum,
                            int n, int B) {
    int i = blockIdx.x * 1024 + threadIdx.x;
    if (i < n) out[i] += bsum[i >> 10];
    else if (i == n) out[n] = bsum[B];
}

__global__ void scatter_kernel(const int* __restrict__ srcv, const int* __restrict__ dstv,
                               int* __restrict__ cursor, int* __restrict__ colv, int E) {
    int e = blockIdx.x * blockDim.x + threadIdx.x;
    if (e < E) {
        int p = atomicAdd(&cursor[dstv[e]], 1);
        colv[p] = srcv[e];
    }
}

// ---------------------------------------------------------------- bf16 MFMA GEMM
// C[M,N] (bf16) = A[M,Kp] @ Bt[N,Kp]^T.  A,Bt bf16 row-major, Kp%32==0, N%128==0.
// v6: global_load_lds width-16 staging (async direct-to-LDS, no VGPR round trip).
// LDS dest is linear in tid (dest = wave_base + lane*16B), global src per-lane.
__global__ __launch_bounds__(256)
void gemm_bf16_mfma(const __hip_bfloat16* __restrict__ A,
                    const __hip_bfloat16* __restrict__ Bt,
                    __hip_bfloat16* __restrict__ C, int M, int N, int Kp) {
    __shared__ __hip_bfloat16 As[128 * 32];
    __shared__ __hip_bfloat16 Bs[128 * 32];
    int tid = threadIdx.x;
    int lane = tid & 63;
    int wave = tid >> 6;
    int wm = wave >> 1, wn = wave & 1;
    int quad = lane >> 4, l16 = lane & 15;
    int m0 = blockIdx.y * 128;
    int n0 = blockIdx.x * 128;

    facc acc[4][4] = {};

    for (int k0 = 0; k0 < Kp; k0 += 32) {
#pragma unroll
        for (int p = 0; p < 2; ++p) {
            int idx = p * 256 + tid;          // 0..511 -> 16B chunk id
            int row = idx >> 2;               // 0..127
            int koff = (idx & 3) * 8;         // element offset in 32-elem row
            int gr = m0 + row; if (gr >= M) gr = M - 1;
            // wave-uniform LDS base (elements): chunk id of lane 0 of this wave * 8
            int lbase = (p * 256 + wave * 64) * 8;
            gload_lds16(A + (size_t)gr * Kp + k0 + koff, As + lbase);
            gload_lds16(Bt + (size_t)(n0 + row) * Kp + k0 + koff, Bs + lbase);
        }
        __syncthreads();   // drains vmcnt (global_load_lds) before ds_read

        frag a[4], b[4];
#pragma unroll
        for (int i = 0; i < 4; ++i) {
            a[i] = *reinterpret_cast<const frag*>(As + (wm * 64 + i * 16 + l16) * 32 + quad * 8);
            b[i] = *reinterpret_cast<const frag*>(Bs + (wn * 64 + i * 16 + l16) * 32 + quad * 8);
        }
#pragma unroll
        for (int i = 0; i < 4; ++i)
#pragma unroll
            for (int j = 0; j < 4; ++j)
                acc[i][j] = __builtin_amdgcn_mfma_f32_16x16x32_bf16(a[i], b[j], acc[i][j], 0, 0, 0);
        __syncthreads();
    }

    // C/D layout: col = lane&15, row = quad*4 + reg
#pragma unroll
    for (int i = 0; i < 4; ++i)
#pragma unroll
        for (int j = 0; j < 4; ++j) {
            int col = n0 + wn * 64 + j * 16 + l16;
#pragma unroll
            for (int r = 0; r < 4; ++r) {
                int row = m0 + wm * 64 + i * 16 + quad * 4 + r;
                if (row < M) C[(size_t)row * N + col] = __float2bfloat16(acc[i][j][r]);
            }
        }
}

// YL/YR[M,2] fp32 = A[M,K](bf16) @ {Wl,Wr}[K,2](fp32) — one pass over A
__global__ void gemm_n22_b(const __hip_bfloat16* __restrict__ A,
                           const float* __restrict__ Wl, const float* __restrict__ Wr,
                           float* __restrict__ YL, float* __restrict__ YR, int M, int K) {
    int i = blockIdx.x * blockDim.x + threadIdx.x;
    if (i >= M) return;
    float l0 = 0.f, l1 = 0.f, r0 = 0.f, r1 = 0.f;
    const unsigned* a = (const unsigned*)(A + (size_t)i * K);
    for (int k2 = 0; k2 < K / 2; ++k2) {
        unsigned u = a[k2];
        float v0 = bf_lo(u), v1 = bf_hi(u);
        int k = k2 * 2;
        l0 = fmaf(v0, Wl[k * 2 + 0], l0);
        l1 = fmaf(v0, Wl[k * 2 + 1], l1);
        l0 = fmaf(v1, Wl[k * 2 + 2], l0);
        l1 = fmaf(v1, Wl[k * 2 + 3], l1);
        r0 = fmaf(v0, Wr[k * 2 + 0], r0);
        r1 = fmaf(v0, Wr[k * 2 + 1], r1);
        r0 = fmaf(v1, Wr[k * 2 + 2], r0);
        r1 = fmaf(v1, Wr[k * 2 + 3], r1);
    }
    YL[(size_t)i * 2 + 0] = l0;
    YL[(size_t)i * 2 + 1] = l1;
    YR[(size_t)i * 2 + 0] = r0;
    YR[(size_t)i * 2 + 1] = r1;
}

// ---------------------------------------------------------------- converters
__global__ void wconv(const float* __restrict__ W, __hip_bfloat16* __restrict__ Wt,
                      int K, int N, int Kp) {
    int i = blockIdx.x * blockDim.x + threadIdx.x;
    if (i >= N * Kp) return;
    int n = i / Kp, k = i - n * Kp;
    Wt[i] = __float2bfloat16((k < K) ? W[(size_t)k * N + n] : 0.f);
}

// h1 weight with permuted K: EHB layout is [gat(0..127) | z | pad31].
__global__ void wconv_h1(const float* __restrict__ W, __hip_bfloat16* __restrict__ Wt, int N) {
    int i = blockIdx.x * blockDim.x + threadIdx.x;
    if (i >= N * 160) return;
    int n = i / 160, k = i - n * 160;
    float v = 0.f;
    if (k < 128) v = W[(size_t)(k + 1) * N + n];
    else if (k == 128) v = W[n];
    Wt[i] = __float2bfloat16(v);
}

__global__ void xconv(const float* __restrict__ x, __hip_bfloat16* __restrict__ xb, int n) {
    int i = blockIdx.x * blockDim.x + threadIdx.x;
    if (i >= n * 128) return;
    int r = i >> 7, c = i & 127;
    xb[i] = __float2bfloat16((c < 125) ? x[(size_t)r * 125 + c] : 0.f);
}

__global__ void outer_xr_b(const float* __restrict__ xh, const float* __restrict__ w,
                           __hip_bfloat16* __restrict__ xr, int n) {
    int i = blockIdx.x * blockDim.x + threadIdx.x;
    if (i < n * 128) {
        int r = i >> 7, c = i & 127;
        xr[i] = __float2bfloat16(xh[r] * w[c]);
    }
}

__global__ void set_colz(const float* __restrict__ z, __hip_bfloat16* __restrict__ buf, int n) {
    int i = blockIdx.x * blockDim.x + threadIdx.x;
    if (i < n) buf[(size_t)i * 160 + 128] = __float2bfloat16(z[i]);
}

// ---------------------------------------------------------------- fused GATv2 edge phase v6
// One wave per (dst, head), PERSISTENT (grid-stride over wid). 4 edges in flight
// per chunk (g=lane>>4), lane q=lane&15 owns channels 8q..8q+7 (one dwordx4
// gather per edge). v6: DEPTH-3 pipeline — two xl-row loads outstanding per
// wave, col indices fetched 3 chunks ahead (v4 was depth-2; gather latency
// ~500-900cy vs ~140cy compute per chunk was the stall).
// Scalar math (v4 form — v_pk_f32 measured a regression on gfx950).
// No online max: logits are O(3 sigma), exp(min(p,85)) exact to rounding.
__global__ void gat_c128_v6(const __hip_bfloat16* __restrict__ xl, int xls,
                            const __hip_bfloat16* __restrict__ xr, int xrs,
                            const int* __restrict__ row_off, const int* __restrict__ col,
                            const float* __restrict__ att, const float* __restrict__ bias,
                            __hip_bfloat16* __restrict__ outb, int obstride,
                            int n_dst, int lgH, int nwid) {
    int wid0 = (blockIdx.x * blockDim.x + threadIdx.x) >> 6;
    int lane = threadIdx.x & 63;
    int g = lane >> 4;        // edge slot 0..3
    int q = lane & 15;        // channel block: channels 8q..8q+7
    int total = n_dst << lgH;
    int hmask = (1 << lgH) - 1;

    for (int wid = wid0; wid < total; wid += nwid) {
        int dst = wid >> lgH;
        int h = wid & hmask;
        int cb = h * 128 + q * 8;
        int beg = row_off[dst], end = row_off[dst + 1];

        float xrv[8], av[8];
        unpack8(*(const uint4*)(xr + (size_t)dst * xrs + cb), xrv);
        {
            float4 a0 = *(const float4*)(att + cb);
            float4 a1 = *(const float4*)(att + cb + 4);
            av[0] = a0.x; av[1] = a0.y; av[2] = a0.z; av[3] = a0.w;
            av[4] = a1.x; av[5] = a1.y; av[6] = a1.z; av[7] = a1.w;
        }

        float s = 0.f;
        float acc[8] = {0.f, 0.f, 0.f, 0.f, 0.f, 0.f, 0.f, 0.f};

        if (beg < end) {
            // prologue: chunk0 + chunk1 data in flight, chunk2 index ready
            int e0g = beg + g;
            bool pv0 = e0g < end;
            int i0 = col[pv0 ? e0g : beg];
            uint4 u0 = *(const uint4*)(xl + (unsigned)(i0 * xls + cb));

            bool has1 = (beg + 4) < end;
            int e1g = beg + 4 + g;
            bool pv1 = e1g < end;
            uint4 u1;
            if (has1) {
                int i1 = col[pv1 ? e1g : beg];
                u1 = *(const uint4*)(xl + (unsigned)(i1 * xls + cb));
            }
            int e2g = beg + 8 + g;
            int i2 = (beg + 8 < end) ? col[(e2g < end) ? e2g : beg] : 0;

            for (int e0 = beg; e0 < end; e0 += 4) {
                bool has2 = (e0 + 8) < end;
                uint4 u2;
                if (has2)
                    u2 = *(const uint4*)(xl + (unsigned)(i2 * xls + cb));  // issue early
                int e3g = e0 + 12 + g;
                int i3 = (e0 + 12 < end) ? col[(e3g < end) ? e3g : beg] : 0;
                bool pv2 = (e0 + 8 + g) < end;

                // process current chunk
                float v[8];
                unpack8(u0, v);
                float p = 0.f;
#pragma unroll
                for (int c = 0; c < 8; ++c) {
                    float z = v[c] + xrv[c];
                    z = fmaxf(z, NEG_SLOPE * z);    // leaky-relu, slope<1
                    p = fmaf(z, av[c], p);
                }
                p += __shfl_xor(p, 8, 64);
                p += __shfl_xor(p, 4, 64);
                p += __shfl_xor(p, 2, 64);
                p += __shfl_xor(p, 1, 64);
                if (!pv0) p = -INFINITY;
                float w = __expf(fminf(p, 85.f));   // 0 for invalid slots
                s += w;
#pragma unroll
                for (int c = 0; c < 8; ++c) acc[c] = fmaf(w, v[c], acc[c]);

                u0 = u1; pv0 = pv1;
                u1 = u2; pv1 = pv2;
                i2 = i3;
            }
        }

        // merge the 4 edge-groups (lane^16 / lane^32 hold matching channels)
#pragma unroll
        for (int o = 16; o <= 32; o <<= 1) {
            s += __shfl_xor(s, o, 64);
#pragma unroll
            for (int c = 0; c < 8; ++c) acc[c] += __shfl_xor(acc[c], o, 64);
        }

        int deg = end - beg;
        float inv = (deg > 0) ? 1.f / (s * (float)deg) : 0.f;
        float o8[8];
#pragma unroll
        for (int c = 0; c < 8; ++c) o8[c] = acc[c] * inv;
        if (bias != nullptr) {
#pragma unroll
            for (int c = 0; c < 8; ++c) o8[c] += bias[cb + c];
        }
        if (g == 0) {
            union { uint4 u; __hip_bfloat16 hh[8]; } pk;
#pragma unroll
            for (int c = 0; c < 8; ++c) pk.hh[c] = __float2bfloat16(o8[c]);
            *(uint4*)(outb + (size_t)dst * obstride + cb) = pk.u;
        }
    }
}

// C=2, H=1 final layer: one thread per dst (fp32 xl/xr).
__global__ void gat_c2(const float* __restrict__ xl, const float* __restrict__ xr,
                       const int* __restrict__ row_off, const int* __restrict__ col,
                       const float* __restrict__ att, const float* __restrict__ bias,
                       float* __restrict__ out, int n_dst) {
    int dst = blockIdx.x * blockDim.x + threadIdx.x;
    if (dst >= n_dst) return;
    float x0 = xr[(size_t)dst * 2], x1 = xr[(size_t)dst * 2 + 1];
    float a0 = att[0], a1 = att[1];
    int beg = row_off[dst], end = row_off[dst + 1];
    float s = 0.f, acc0 = 0.f, acc1 = 0.f;
    for (int e = beg; e < end; ++e) {
        int src = col[e];
        float v0 = xl[(size_t)src * 2], v1 = xl[(size_t)src * 2 + 1];
        float z0 = v0 + x0; z0 = fmaxf(z0, NEG_SLOPE * z0);
        float z1 = v1 + x1; z1 = fmaxf(z1, NEG_SLOPE * z1);
        float p = fmaf(z0, a0, z1 * a1);
        float w = __expf(fminf(p, 85.f));
        s += w;
        acc0 = fmaf(w, v0, acc0);
        acc1 = fmaf(w, v1, acc1);
    }
    int deg = end - beg;
    float o0 = 0.f, o1 = 0.f;
    if (deg > 0) {
        float inv = 1.f / (s * (float)deg);
        o0 = acc0 * inv;
        o1 = acc1 * inv;
    }
    out[(size_t)dst * 2 + 0] = o0 + bias[0];
    out[(size_t)dst * 2 + 1] = o1 + bias[1];
}

// ---------------------------------------------------------------- BatchNorm (deterministic)
// Stage 1: 256 blocks write per-block partial sums (NO atomics -> replay-stable).
__global__ void bn_partial_d(const __hip_bfloat16* __restrict__ x, float* __restrict__ part,
                             int Nr, int rpb) {
    int C = blockDim.x;
    int c = threadIdx.x;
    int b = blockIdx.x;
    int r0 = b * rpb;
    int r1 = r0 + rpb; if (r1 > Nr) r1 = Nr;
    float s = 0.f, q = 0.f;
    for (int r = r0; r < r1; ++r) {
        float v = __bfloat162float(x[(size_t)r * C + c]);
        s += v;
        q = fmaf(v, v, q);
    }
    part[(size_t)b * C + c] = s;
    part[65536 + (size_t)b * C + c] = q;   // 256*256 slot offset
}

// Stage 2: ONE WAVE PER CHANNEL, lanes sum 4 partials each, fixed-order
// shuffle tree -> deterministic AND parallel (C/4 blocks, not 1).
__global__ void bn_finalize_w(const float* __restrict__ part,
                              const float* __restrict__ g, const float* __restrict__ b,
                              float* __restrict__ scale, float* __restrict__ shift,
                              int Nr, int C) {
    int c = (blockIdx.x * blockDim.x + threadIdx.x) >> 6;
    int lane = threadIdx.x & 63;
    if (c >= C) return;
    float s = 0.f, q = 0.f;
    for (int blk = lane; blk < 256; blk += 64) {
        s += part[(size_t)blk * C + c];
        q += part[65536 + (size_t)blk * C + c];
    }
#pragma unroll
    for (int o = 32; o; o >>= 1) {
        s += __shfl_xor(s, o, 64);
        q += __shfl_xor(q, o, 64);
    }
    if (lane == 0) {
        float mu = s / (float)Nr;
        float var = q / (float)Nr - mu * mu;
        float inv = rsqrtf(var + 1e-5f);
        float a = g[c] * inv;
        scale[c] = a;
        shift[c] = b[c] - mu * a;
    }
}

__global__ void bn_apply_b(__hip_bfloat16* __restrict__ x, const float* __restrict__ scale,
                           const float* __restrict__ shift, long n, int Cmask) {
    long i = (long)blockIdx.x * blockDim.x + threadIdx.x;
    if (i < n) {
        int c = (int)(i & Cmask);
        float v = fmaf(__bfloat162float(x[i]), scale[c], shift[c]);
        x[i] = __float2bfloat16(v);
    }
}

// ---------------------------------------------------------------- driver
extern "C" void kernel_launch(void* const* d_in, const int* in_sizes, int n_in,
                              void* d_out, int out_size, void* d_ws, size_t ws_size,
                              hipStream_t stream) {
    const float* x_low  = (const float*)d_in[0];
    const float* x_high = (const float*)d_in[1];
    const float* z_std  = (const float*)d_in[2];
    const int* e_low  = (const int*)d_in[3];
    const int* e_l2h  = (const int*)d_in[4];
    const int* e_high = (const int*)d_in[5];
    const float* l1_Wl = (const float*)d_in[6];
    const float* l1_Wr = (const float*)d_in[7];
    const float* l1_att = (const float*)d_in[8];
    const float* l1_b  = (const float*)d_in[9];
    const float* bn1_g = (const float*)d_in[10];
    const float* bn1_b = (const float*)d_in[11];
    const float* l2_Wl = (const float*)d_in[12];
    const float* l2_Wr = (const float*)d_in[13];
    const float* l2_att = (const float*)d_in[14];
    const float* l2_b  = (const float*)d_in[15];
    const float* bn2_g = (const float*)d_in[16];
    const float* bn2_b = (const float*)d_in[17];
    const float* l3_Wl = (const float*)d_in[18];
    const float* l3_Wr = (const float*)d_in[19];
    const float* l3_att = (const float*)d_in[20];
    const float* l3_b  = (const float*)d_in[21];
    const float* lh_Wl = (const float*)d_in[22];
    const float* lh_Wr = (const float*)d_in[23];
    const float* lh_att = (const float*)d_in[24];
    const float* h1_Wl = (const float*)d_in[25];
    const float* h1_Wr = (const float*)d_in[26];
    const float* h1_att = (const float*)d_in[27];
    const float* h1_b  = (const float*)d_in[28];
    const float* bn3_g = (const float*)d_in[29];
    const float* bn3_b = (const float*)d_in[30];
    const float* h2_Wl = (const float*)d_in[31];
    const float* h2_Wr = (const float*)d_in[32];
    const float* h2_att = (const float*)d_in[33];
    const float* h2_b  = (const float*)d_in[34];
    const float* bn4_g = (const float*)d_in[35];
    const float* bn4_b = (const float*)d_in[36];
    const float* h3_Wl = (const float*)d_in[37];
    const float* h3_Wr = (const float*)d_in[38];
    const float* h3_att = (const float*)d_in[39];
    const float* h3_b  = (const float*)d_in[40];

    const int N_low = in_sizes[0] / 125;
    const int N_high = in_sizes[1];
    const int E_low = in_sizes[3] / 2;
    const int E_l2h = in_sizes[4] / 2;
    const int E_high = in_sizes[5] / 2;

    char* ws = (char*)d_ws;
    size_t woff = 0;
    auto walloc = [&](size_t bytes) -> void* {
        void* p = (void*)(ws + woff);
        woff += (bytes + 255) & ~(size_t)255;
        return p;
    };
    // XLR holds merged [XL|XR] GEMM outputs (max N_high x 512 bf16 = 61 MB)
    __hip_bfloat16* XLR = (__hip_bfloat16*)walloc((size_t)N_high * 512 * 2);
    __hip_bfloat16* A1  = (__hip_bfloat16*)walloc((size_t)N_high * 256 * 2);
    __hip_bfloat16* A2  = (__hip_bfloat16*)walloc((size_t)N_high * 128 * 2);
    __hip_bfloat16* XRo = (__hip_bfloat16*)walloc((size_t)N_high * 128 * 2); // lh outer xr
    __hip_bfloat16* XLOWB = (__hip_bfloat16*)walloc((size_t)N_low * 128 * 2);
    __hip_bfloat16* EHB = (__hip_bfloat16*)walloc((size_t)N_high * 160 * 2);
    float* YL = (float*)walloc((size_t)N_high * 2 * 4);
    float* YR = (float*)walloc((size_t)N_high * 2 * 4);
    int* off_low  = (int*)walloc((size_t)(N_low + 1) * 4);
    int* col_low  = (int*)walloc((size_t)E_low * 4);
    int* off_l2h  = (int*)walloc((size_t)(N_high + 1) * 4);
    int* col_l2h  = (int*)walloc((size_t)E_l2h * 4);
    int* off_high = (int*)walloc((size_t)(N_high + 1) * 4);
    int* col_high = (int*)walloc((size_t)E_high * 4);
    int* cursor   = (int*)walloc((size_t)(N_high + 1) * 4);
    int* bsum     = (int*)walloc(1025 * 4);
    float* bnpart = (float*)walloc(2 * 256 * 256 * 4);   // deterministic BN partials
    float* bnsc   = (float*)walloc(512 * 4);
    // merged [Wl|Wr] bf16 transposed weights [Ncat][Kp]
    __hip_bfloat16* w_l1 = (__hip_bfloat16*)walloc(512 * 128 * 2);
    __hip_bfloat16* w_l2 = (__hip_bfloat16*)walloc(256 * 256 * 2);
    __hip_bfloat16* w_l3 = (__hip_bfloat16*)walloc(256 * 128 * 2);
    __hip_bfloat16* w_lh = (__hip_bfloat16*)walloc(128 * 128 * 2);
    __hip_bfloat16* w_h1 = (__hip_bfloat16*)walloc(512 * 160 * 2);
    __hip_bfloat16* w_h2 = (__hip_bfloat16*)walloc(256 * 256 * 2);

    // ---- weight & input conversion (tiny)
    auto wc = [&](const float* W, __hip_bfloat16* Wt, int K, int N, int Kp) {
        int n = N * Kp;
        wconv<<<(n + 255) / 256, 256, 0, stream>>>(W, Wt, K, N, Kp);
    };
    wc(l1_Wl, w_l1, 125, 256, 128);  wc(l1_Wr, w_l1 + 256 * 128, 125, 256, 128);
    wc(l2_Wl, w_l2, 256, 128, 256);  wc(l2_Wr, w_l2 + 128 * 256, 256, 128, 256);
    wc(l3_Wl, w_l3, 128, 128, 128);  wc(l3_Wr, w_l3 + 128 * 128, 128, 128, 128);
    wc(lh_Wl, w_lh, 128, 128, 128);
    wconv_h1<<<(256 * 160 + 255) / 256, 256, 0, stream>>>(h1_Wl, w_h1, 256);
    wconv_h1<<<(256 * 160 + 255) / 256, 256, 0, stream>>>(h1_Wr, w_h1 + 256 * 160, 256);
    wc(h2_Wl, w_h2, 256, 128, 256);  wc(h2_Wr, w_h2 + 128 * 256, 256, 128, 256);
    xconv<<<((size_t)N_low * 128 + 255) / 256, 256, 0, stream>>>(x_low, XLOWB, N_low);

    // ---- CSR build (parallel 3-phase scan)
    auto build_csr = [&](const int* edges, int E, int Nn, int* roff, int* colv) {
        hipMemsetAsync(cursor, 0, (size_t)Nn * 4, stream);
        count_kernel<<<(E + 255) / 256, 256, 0, stream>>>(edges + E, cursor, E);
        int B = (Nn + 1023) / 1024;
        scan_phase1<<<B, 1024, 0, stream>>>(cursor, roff, bsum, Nn);
        scan_phase2<<<1, 1024, 0, stream>>>(bsum, B);
        scan_phase3<<<(Nn + 1 + 1023) / 1024, 1024, 0, stream>>>(roff, bsum, Nn, B);
        hipMemcpyAsync(cursor, roff, (size_t)Nn * 4, hipMemcpyDeviceToDevice, stream);
        scatter_kernel<<<(E + 255) / 256, 256, 0, stream>>>(edges, edges + E, cursor, colv, E);
    };
    build_csr(e_low, E_low, N_low, off_low, col_low);
    build_csr(e_l2h, E_l2h, N_high, off_l2h, col_l2h);
    build_csr(e_high, E_high, N_high, off_high, col_high);

    auto gemm = [&](const __hip_bfloat16* A, const __hip_bfloat16* Bt, __hip_bfloat16* C,
                    int M, int N, int Kp) {
        dim3 g(N / 128, (M + 127) / 128);
        gemm_bf16_mfma<<<g, 256, 0, stream>>>(A, Bt, C, M, N, Kp);
    };
    auto gat = [&](const __hip_bfloat16* xl, int xls, const __hip_bfloat16* xr, int xrs,
                   const int* roff, const int* colv,
                   const float* att, const float* bias,
                   __hip_bfloat16* outb, int obs, int n_dst, int H) {
        int lgH = (H == 2) ? 1 : 0;
        long totalw = (long)n_dst * H;
        long blocks = (totalw + 3) / 4;         // 4 waves per 256-thr block
        if (blocks > 2048) blocks = 2048;       // persistent grid-stride
        int nwid = (int)blocks * 4;
        gat_c128_v6<<<(unsigned)blocks, 256, 0, stream>>>(
            xl, xls, xr, xrs, roff, colv, att, bias, outb, obs, n_dst, lgH, nwid);
    };
    // deterministic BN: no-atomic partials -> wave-per-channel fixed-tree finalize -> apply
    auto bn = [&](__hip_bfloat16* x, const float* g, const float* b, int Nr, int C) {
        int rpb = (Nr + 255) / 256;
        bn_partial_d<<<256, C, 0, stream>>>(x, bnpart, Nr, rpb);
        bn_finalize_w<<<(C * 64 + 255) / 256, 256, 0, stream>>>(bnpart, g, b, bnsc, bnsc + 256, Nr, C);
        long n = (long)Nr * C;
        bn_apply_b<<<(unsigned)((n + 255) / 256), 256, 0, stream>>>(x, bnsc, bnsc + 256, n, C - 1);
    };

    // ---- low_net layer 1: 125 -> (H=2) 256, BN   (merged [XL|XR], stride 512)
    gemm(XLOWB, w_l1, XLR, N_low, 512, 128);
    gat(XLR, 512, XLR + 256, 512, off_low, col_low, l1_att, l1_b, A1, 256, N_low, 2);
    bn(A1, bn1_g, bn1_b, N_low, 256);

    // ---- low_net layer 2: 256 -> 128, BN   (merged, stride 256)
    gemm(A1, w_l2, XLR, N_low, 256, 256);
    gat(XLR, 256, XLR + 128, 256, off_low, col_low, l2_att, l2_b, A2, 128, N_low, 1);
    bn(A2, bn2_g, bn2_b, N_low, 128);

    // ---- low_net layer 3: 128 -> 128   (merged, stride 256)
    gemm(A2, w_l3, XLR, N_low, 256, 128);
    gat(XLR, 256, XLR + 128, 256, off_low, col_low, l3_att, l3_b, A1, 128, N_low, 1);

    // ---- bipartite low2high -> EHB[N_high][160] = [gat 0..127 | z | pad]
    gemm(A1, w_lh, XLR, N_low, 128, 128);   // xl only, stride 128
    outer_xr_b<<<(unsigned)(((size_t)N_high * 128 + 255) / 256), 256, 0, stream>>>(x_high, lh_Wr, XRo, N_high);
    hipMemsetAsync(EHB, 0, (size_t)N_high * 160 * 2, stream);
    gat(XLR, 128, XRo, 128, off_l2h, col_l2h, lh_att, nullptr, EHB, 160, N_high, 1);
    set_colz<<<(N_high + 255) / 256, 256, 0, stream>>>(z_std, EHB, N_high);

    // ---- high_net layer 1: 129(perm,pad160) -> (H=2) 256, BN   (merged, stride 512)
    gemm(EHB, w_h1, XLR, N_high, 512, 160);
    gat(XLR, 512, XLR + 256, 512, off_high, col_high, h1_att, h1_b, A1, 256, N_high, 2);
    bn(A1, bn3_g, bn3_b, N_high, 256);

    // ---- high_net layer 2: 256 -> 128, BN   (merged, stride 256)
    gemm(A1, w_h2, XLR, N_high, 256, 256);
    gat(XLR, 256, XLR + 128, 256, off_high, col_high, h2_att, h2_b, A2, 128, N_high, 1);
    bn(A2, bn4_g, bn4_b, N_high, 128);

    // ---- high_net layer 3: 128 -> 2 (one pass over A2 for both Wl and Wr)
    gemm_n22_b<<<(N_high + 255) / 256, 256, 0, stream>>>(A2, h3_Wl, h3_Wr, YL, YR, N_high, 128);
    gat_c2<<<(N_high + 255) / 256, 256, 0, stream>>>(YL, YR, off_high, col_high,
                                                     h3_att, h3_b, (float*)d_out, N_high);
}

// Round 3
// 879.788 us; speedup vs baseline: 1.0359x; 1.0359x over previous
//
#include <hip/hip_runtime.h>
#include <hip/hip_bf16.h>
#include <cstdint>
#include <cstddef>

#define NEG_SLOPE 0.2f

using frag = __attribute__((ext_vector_type(8))) short;   // 8 bf16 = 4 VGPRs
using facc = __attribute__((ext_vector_type(4))) float;   // 4 fp32 accum

__device__ __forceinline__ float bf_hi(unsigned u) {
    union { unsigned i; float f; } t; t.i = u & 0xffff0000u; return t.f;
}
__device__ __forceinline__ float bf_lo(unsigned u) {
    union { unsigned i; float f; } t; t.i = u << 16; return t.f;
}
__device__ __forceinline__ void unpack8(uint4 u, float* v) {
    v[0] = bf_lo(u.x); v[1] = bf_hi(u.x);
    v[2] = bf_lo(u.y); v[3] = bf_hi(u.y);
    v[4] = bf_lo(u.z); v[5] = bf_hi(u.z);
    v[6] = bf_lo(u.w); v[7] = bf_hi(u.w);
}

// async global->LDS, 16B per lane (wave-uniform LDS base + lane*16)
typedef const __attribute__((address_space(1))) void* gas_cptr;
typedef __attribute__((address_space(3))) void* las_ptr;
__device__ __forceinline__ void gload_lds16(const __hip_bfloat16* g, __hip_bfloat16* l) {
    __builtin_amdgcn_global_load_lds((gas_cptr)(const void*)g, (las_ptr)(void*)l, 16, 0, 0);
}

// ---------------------------------------------------------------- CSR build
__global__ void count_kernel(const int* __restrict__ dstv, int* __restrict__ cnt, int E) {
    int e = blockIdx.x * blockDim.x + threadIdx.x;
    if (e < E) atomicAdd(&cnt[dstv[e]], 1);
}

// 3-phase parallel exclusive scan
__global__ void scan_phase1(const int* __restrict__ in, int* __restrict__ out,
                            int* __restrict__ bsum, int n) {
    __shared__ int buf[1024];
    int tid = threadIdx.x;
    int i = blockIdx.x * 1024 + tid;
    int v = (i < n) ? in[i] : 0;
    buf[tid] = v;
    __syncthreads();
    for (int off = 1; off < 1024; off <<= 1) {
        int t = (tid >= off) ? buf[tid - off] : 0;
        __syncthreads();
        buf[tid] += t;
        __syncthreads();
    }
    if (i < n) out[i] = buf[tid] - v;           // exclusive
    if (tid == 1023) bsum[blockIdx.x] = buf[1023];
}

__global__ void scan_phase2(int* __restrict__ bsum, int B) {
    __shared__ int buf[1024];
    int tid = threadIdx.x;
    int v = (tid < B) ? bsum[tid] : 0;
    buf[tid] = v;
    __syncthreads();
    for (int off = 1; off < 1024; off <<= 1) {
        int t = (tid >= off) ? buf[tid - off] : 0;
        __syncthreads();
        buf[tid] += t;
        __syncthreads();
    }
    if (tid < B) bsum[tid] = buf[tid] - v;      // exclusive block offsets
    if (tid == 0) bsum[B] = buf[B - 1];         // total
}

__global__ void scan_phase3(int* __restrict__ out, const int* __restrict__ bsum,
                            int n, int B) {
    int i = blockIdx.x * 1024 + threadIdx.x;
    if (i < n) out[i] += bsum[i >> 10];
    else if (i == n) out[n] = bsum[B];
}

__global__ void scatter_kernel(const int* __restrict__ srcv, const int* __restrict__ dstv,
                               int* __restrict__ cursor, int* __restrict__ colv, int E) {
    int e = blockIdx.x * blockDim.x + threadIdx.x;
    if (e < E) {
        int p = atomicAdd(&cursor[dstv[e]], 1);
        colv[p] = srcv[e];
    }
}

// ---------------------------------------------------------------- bf16 MFMA GEMM
// C[M,N] (bf16) = A[M,Kp] @ Bt[N,Kp]^T (+ bias[n]).  A,Bt bf16 row-major,
// Kp%32==0, N%128==0.  global_load_lds width-16 staging (async direct-to-LDS).
__global__ __launch_bounds__(256)
void gemm_bf16_mfma(const __hip_bfloat16* __restrict__ A,
                    const __hip_bfloat16* __restrict__ Bt,
                    __hip_bfloat16* __restrict__ C,
                    const float* __restrict__ bias, int M, int N, int Kp) {
    __shared__ __hip_bfloat16 As[128 * 32];
    __shared__ __hip_bfloat16 Bs[128 * 32];
    int tid = threadIdx.x;
    int lane = tid & 63;
    int wave = tid >> 6;
    int wm = wave >> 1, wn = wave & 1;
    int quad = lane >> 4, l16 = lane & 15;
    int m0 = blockIdx.y * 128;
    int n0 = blockIdx.x * 128;

    facc acc[4][4] = {};

    for (int k0 = 0; k0 < Kp; k0 += 32) {
#pragma unroll
        for (int p = 0; p < 2; ++p) {
            int idx = p * 256 + tid;          // 0..511 -> 16B chunk id
            int row = idx >> 2;               // 0..127
            int koff = (idx & 3) * 8;         // element offset in 32-elem row
            int gr = m0 + row; if (gr >= M) gr = M - 1;
            // wave-uniform LDS base (elements); lane dest = base + lane*16B
            int lbase = (p * 256 + wave * 64) * 8;
            gload_lds16(A + (size_t)gr * Kp + k0 + koff, As + lbase);
            gload_lds16(Bt + (size_t)(n0 + row) * Kp + k0 + koff, Bs + lbase);
        }
        __syncthreads();   // drains vmcnt (global_load_lds) before ds_read

        frag a[4], b[4];
#pragma unroll
        for (int i = 0; i < 4; ++i) {
            a[i] = *reinterpret_cast<const frag*>(As + (wm * 64 + i * 16 + l16) * 32 + quad * 8);
            b[i] = *reinterpret_cast<const frag*>(Bs + (wn * 64 + i * 16 + l16) * 32 + quad * 8);
        }
#pragma unroll
        for (int i = 0; i < 4; ++i)
#pragma unroll
            for (int j = 0; j < 4; ++j)
                acc[i][j] = __builtin_amdgcn_mfma_f32_16x16x32_bf16(a[i], b[j], acc[i][j], 0, 0, 0);
        __syncthreads();
    }

    // C/D layout: col = lane&15, row = quad*4 + reg
#pragma unroll
    for (int i = 0; i < 4; ++i)
#pragma unroll
        for (int j = 0; j < 4; ++j) {
            int col = n0 + wn * 64 + j * 16 + l16;
            float bv = (bias != nullptr) ? bias[col] : 0.f;
#pragma unroll
            for (int r = 0; r < 4; ++r) {
                int row = m0 + wm * 64 + i * 16 + quad * 4 + r;
                if (row < M) C[(size_t)row * N + col] = __float2bfloat16(acc[i][j][r] + bv);
            }
        }
}

// YL/YR[M,2] fp32 = (A*s+t)[M,K](bf16,BN-folded inline) @ {Wl,Wr}[K,2](fp32)
__global__ void gemm_n22_bn(const __hip_bfloat16* __restrict__ A,
                            const float* __restrict__ Wl, const float* __restrict__ Wr,
                            const float* __restrict__ s, const float* __restrict__ t,
                            float* __restrict__ YL, float* __restrict__ YR, int M, int K) {
    int i = blockIdx.x * blockDim.x + threadIdx.x;
    if (i >= M) return;
    float l0 = 0.f, l1 = 0.f, r0 = 0.f, r1 = 0.f;
    const unsigned* a = (const unsigned*)(A + (size_t)i * K);
    for (int k2 = 0; k2 < K / 2; ++k2) {
        unsigned u = a[k2];
        int k = k2 * 2;
        float v0 = fmaf(bf_lo(u), s[k], t[k]);          // BN applied in f32
        float v1 = fmaf(bf_hi(u), s[k + 1], t[k + 1]);
        l0 = fmaf(v0, Wl[k * 2 + 0], l0);
        l1 = fmaf(v0, Wl[k * 2 + 1], l1);
        l0 = fmaf(v1, Wl[k * 2 + 2], l0);
        l1 = fmaf(v1, Wl[k * 2 + 3], l1);
        r0 = fmaf(v0, Wr[k * 2 + 0], r0);
        r1 = fmaf(v0, Wr[k * 2 + 1], r1);
        r0 = fmaf(v1, Wr[k * 2 + 2], r0);
        r1 = fmaf(v1, Wr[k * 2 + 3], r1);
    }
    YL[(size_t)i * 2 + 0] = l0;
    YL[(size_t)i * 2 + 1] = l1;
    YR[(size_t)i * 2 + 0] = r0;
    YR[(size_t)i * 2 + 1] = r1;
}

// ---------------------------------------------------------------- converters
__global__ void wconv(const float* __restrict__ W, __hip_bfloat16* __restrict__ Wt,
                      int K, int N, int Kp) {
    int i = blockIdx.x * blockDim.x + threadIdx.x;
    if (i >= N * Kp) return;
    int n = i / Kp, k = i - n * Kp;
    Wt[i] = __float2bfloat16((k < K) ? W[(size_t)k * N + n] : 0.f);
}

// BN-folded weight transpose: Wt[n][k] = scale[k]*W[k][n] (bf16),
// bout[n] = sum_k shift[k]*W[k][n] (f32, fixed-tree deterministic).
__global__ void wconv_bnfold(const float* __restrict__ W, const float* __restrict__ scale,
                             const float* __restrict__ shift,
                             __hip_bfloat16* __restrict__ Wt, float* __restrict__ bout,
                             int K, int N, int Kp) {
    __shared__ float red[256];
    int n = blockIdx.x;          // output column (row of Wt)
    int tid = threadIdx.x;
    float acc = 0.f;
    for (int k = tid; k < Kp; k += 256) {
        float v = 0.f;
        if (k < K) {
            float w = W[(size_t)k * N + n];
            v = w * scale[k];
            acc = fmaf(w, shift[k], acc);
        }
        Wt[(size_t)n * Kp + k] = __float2bfloat16(v);
    }
    red[tid] = acc;
    __syncthreads();
    for (int o = 128; o; o >>= 1) {
        if (tid < o) red[tid] += red[tid + o];
        __syncthreads();
    }
    if (tid == 0) bout[n] = red[0];
}

// h1 weight with permuted K: EHB layout is [gat(0..127) | z | pad31].
__global__ void wconv_h1(const float* __restrict__ W, __hip_bfloat16* __restrict__ Wt, int N) {
    int i = blockIdx.x * blockDim.x + threadIdx.x;
    if (i >= N * 160) return;
    int n = i / 160, k = i - n * 160;
    float v = 0.f;
    if (k < 128) v = W[(size_t)(k + 1) * N + n];
    else if (k == 128) v = W[n];
    Wt[i] = __float2bfloat16(v);
}

__global__ void xconv(const float* __restrict__ x, __hip_bfloat16* __restrict__ xb, int n) {
    int i = blockIdx.x * blockDim.x + threadIdx.x;
    if (i >= n * 128) return;
    int r = i >> 7, c = i & 127;
    xb[i] = __float2bfloat16((c < 125) ? x[(size_t)r * 125 + c] : 0.f);
}

__global__ void outer_xr_b(const float* __restrict__ xh, const float* __restrict__ w,
                           __hip_bfloat16* __restrict__ xr, int n) {
    int i = blockIdx.x * blockDim.x + threadIdx.x;
    if (i < n * 128) {
        int r = i >> 7, c = i & 127;
        xr[i] = __float2bfloat16(xh[r] * w[c]);
    }
}

__global__ void set_colz(const float* __restrict__ z, __hip_bfloat16* __restrict__ buf, int n) {
    int i = blockIdx.x * blockDim.x + threadIdx.x;
    if (i < n) buf[(size_t)i * 160 + 128] = __float2bfloat16(z[i]);
}

// ---------------------------------------------------------------- fused GATv2 edge phase v4
// (verbatim best-measured version: 64.6us hot dispatch)
// One wave per (dst, head). 4 edges in flight (g=lane>>4), lane q=lane&15 owns
// channels 8q..8q+7 (one dwordx4 gather per edge). Pipelined gathers (depth 2).
// No online max: logits are O(3 sigma), fp32 exp overflows at 88 — plain
// exp(min(p,85)) is exact to rounding. Invalid slots: p=-inf -> exp=0.
__global__ void gat_c128_v4(const __hip_bfloat16* __restrict__ xl, int xls,
                            const __hip_bfloat16* __restrict__ xr, int xrs,
                            const int* __restrict__ row_off, const int* __restrict__ col,
                            const float* __restrict__ att, const float* __restrict__ bias,
                            __hip_bfloat16* __restrict__ outb, int obstride,
                            int n_dst, int H) {
    int wid = (blockIdx.x * blockDim.x + threadIdx.x) >> 6;
    int lane = threadIdx.x & 63;
    int total = n_dst * H;
    if (wid >= total) return;
    int dst = wid / H;
    int h = wid - dst * H;
    int g = lane >> 4;        // edge slot 0..3
    int q = lane & 15;        // channel block: channels 8q..8q+7
    int cb = h * 128 + q * 8;
    int beg = row_off[dst], end = row_off[dst + 1];

    float xrv[8], av[8];
    unpack8(*(const uint4*)(xr + (size_t)dst * xrs + cb), xrv);
    {
        float4 a0 = *(const float4*)(att + cb);
        float4 a1 = *(const float4*)(att + cb + 4);
        av[0] = a0.x; av[1] = a0.y; av[2] = a0.z; av[3] = a0.w;
        av[4] = a1.x; av[5] = a1.y; av[6] = a1.z; av[7] = a1.w;
    }

    float s = 0.f;
    float acc[8] = {0.f, 0.f, 0.f, 0.f, 0.f, 0.f, 0.f, 0.f};

    if (beg < end) {
        // prologue: chunk0 row data, chunk1 col index
        int e0g = beg + g;
        bool pv = e0g < end;
        int i0 = col[pv ? e0g : beg];
        uint4 u = *(const uint4*)(xl + (size_t)i0 * xls + cb);
        int e1g = beg + 4 + g;
        int i1 = (beg + 4 < end) ? col[(e1g < end) ? e1g : beg] : 0;

        for (int e0 = beg; e0 < end; e0 += 4) {
            bool have_next = (e0 + 4) < end;
            uint4 un;
            if (have_next)
                un = *(const uint4*)(xl + (size_t)i1 * xls + cb);   // issue early
            int e2g = e0 + 8 + g;
            int i2 = (e0 + 8 < end) ? col[(e2g < end) ? e2g : beg] : 0;
            bool nv = (e0 + 4 + g) < end;

            // process current chunk
            float v[8];
            unpack8(u, v);
            float p = 0.f;
#pragma unroll
            for (int c = 0; c < 8; ++c) {
                float z = v[c] + xrv[c];
                z = fmaxf(z, NEG_SLOPE * z);    // leaky-relu, slope<1
                p = fmaf(z, av[c], p);
            }
            p += __shfl_xor(p, 8, 64);
            p += __shfl_xor(p, 4, 64);
            p += __shfl_xor(p, 2, 64);
            p += __shfl_xor(p, 1, 64);
            if (!pv) p = -INFINITY;
            float w = __expf(fminf(p, 85.f));   // 0 for invalid slots
            s += w;
#pragma unroll
            for (int c = 0; c < 8; ++c) acc[c] = fmaf(w, v[c], acc[c]);

            if (have_next) { u = un; pv = nv; }
            i1 = i2;
        }
    }

    // merge the 4 edge-groups (lane^16 / lane^32 hold matching channels)
#pragma unroll
    for (int o = 16; o <= 32; o <<= 1) {
        s += __shfl_xor(s, o, 64);
#pragma unroll
        for (int c = 0; c < 8; ++c) acc[c] += __shfl_xor(acc[c], o, 64);
    }

    int deg = end - beg;
    float inv = (deg > 0) ? 1.f / (s * (float)deg) : 0.f;
    float o8[8];
#pragma unroll
    for (int c = 0; c < 8; ++c) o8[c] = acc[c] * inv;
    if (bias != nullptr) {
#pragma unroll
        for (int c = 0; c < 8; ++c) o8[c] += bias[cb + c];
    }
    if (g == 0) {
        union { uint4 u; __hip_bfloat16 hh[8]; } pk;
#pragma unroll
        for (int c = 0; c < 8; ++c) pk.hh[c] = __float2bfloat16(o8[c]);
        *(uint4*)(outb + (size_t)dst * obstride + cb) = pk.u;
    }
}

// C=2, H=1 final layer: one thread per dst (fp32 xl/xr).
__global__ void gat_c2(const float* __restrict__ xl, const float* __restrict__ xr,
                       const int* __restrict__ row_off, const int* __restrict__ col,
                       const float* __restrict__ att, const float* __restrict__ bias,
                       float* __restrict__ out, int n_dst) {
    int dst = blockIdx.x * blockDim.x + threadIdx.x;
    if (dst >= n_dst) return;
    float x0 = xr[(size_t)dst * 2], x1 = xr[(size_t)dst * 2 + 1];
    float a0 = att[0], a1 = att[1];
    int beg = row_off[dst], end = row_off[dst + 1];
    float s = 0.f, acc0 = 0.f, acc1 = 0.f;
    for (int e = beg; e < end; ++e) {
        int src = col[e];
        float v0 = xl[(size_t)src * 2], v1 = xl[(size_t)src * 2 + 1];
        float z0 = v0 + x0; z0 = fmaxf(z0, NEG_SLOPE * z0);
        float z1 = v1 + x1; z1 = fmaxf(z1, NEG_SLOPE * z1);
        float p = fmaf(z0, a0, z1 * a1);
        float w = __expf(fminf(p, 85.f));
        s += w;
        acc0 = fmaf(w, v0, acc0);
        acc1 = fmaf(w, v1, acc1);
    }
    int deg = end - beg;
    float o0 = 0.f, o1 = 0.f;
    if (deg > 0) {
        float inv = 1.f / (s * (float)deg);
        o0 = acc0 * inv;
        o1 = acc1 * inv;
    }
    out[(size_t)dst * 2 + 0] = o0 + bias[0];
    out[(size_t)dst * 2 + 1] = o1 + bias[1];
}

// ---------------------------------------------------------------- BatchNorm stats (deterministic)
// Stage 1: 256 blocks write per-block partial sums (NO atomics -> replay-stable).
__global__ void bn_partial_d(const __hip_bfloat16* __restrict__ x, float* __restrict__ part,
                             int Nr, int rpb) {
    int C = blockDim.x;
    int c = threadIdx.x;
    int b = blockIdx.x;
    int r0 = b * rpb;
    int r1 = r0 + rpb; if (r1 > Nr) r1 = Nr;
    float s = 0.f, q = 0.f;
    for (int r = r0; r < r1; ++r) {
        float v = __bfloat162float(x[(size_t)r * C + c]);
        s += v;
        q = fmaf(v, v, q);
    }
    part[(size_t)b * C + c] = s;
    part[65536 + (size_t)b * C + c] = q;   // 256*256 slot offset
}

// Stage 2: ONE WAVE PER CHANNEL, lanes sum 4 partials each, fixed-order
// shuffle tree -> deterministic AND parallel (C/4 blocks, not 1).
__global__ void bn_finalize_w(const float* __restrict__ part,
                              const float* __restrict__ g, const float* __restrict__ b,
                              float* __restrict__ scale, float* __restrict__ shift,
                              int Nr, int C) {
    int c = (blockIdx.x * blockDim.x + threadIdx.x) >> 6;
    int lane = threadIdx.x & 63;
    if (c >= C) return;
    float s = 0.f, q = 0.f;
    for (int blk = lane; blk < 256; blk += 64) {
        s += part[(size_t)blk * C + c];
        q += part[65536 + (size_t)blk * C + c];
    }
#pragma unroll
    for (int o = 32; o; o >>= 1) {
        s += __shfl_xor(s, o, 64);
        q += __shfl_xor(q, o, 64);
    }
    if (lane == 0) {
        float mu = s / (float)Nr;
        float var = q / (float)Nr - mu * mu;
        float inv = rsqrtf(var + 1e-5f);
        float a = g[c] * inv;
        scale[c] = a;
        shift[c] = b[c] - mu * a;
    }
}

// ---------------------------------------------------------------- driver
extern "C" void kernel_launch(void* const* d_in, const int* in_sizes, int n_in,
                              void* d_out, int out_size, void* d_ws, size_t ws_size,
                              hipStream_t stream) {
    const float* x_low  = (const float*)d_in[0];
    const float* x_high = (const float*)d_in[1];
    const float* z_std  = (const float*)d_in[2];
    const int* e_low  = (const int*)d_in[3];
    const int* e_l2h  = (const int*)d_in[4];
    const int* e_high = (const int*)d_in[5];
    const float* l1_Wl = (const float*)d_in[6];
    const float* l1_Wr = (const float*)d_in[7];
    const float* l1_att = (const float*)d_in[8];
    const float* l1_b  = (const float*)d_in[9];
    const float* bn1_g = (const float*)d_in[10];
    const float* bn1_b = (const float*)d_in[11];
    const float* l2_Wl = (const float*)d_in[12];
    const float* l2_Wr = (const float*)d_in[13];
    const float* l2_att = (const float*)d_in[14];
    const float* l2_b  = (const float*)d_in[15];
    const float* bn2_g = (const float*)d_in[16];
    const float* bn2_b = (const float*)d_in[17];
    const float* l3_Wl = (const float*)d_in[18];
    const float* l3_Wr = (const float*)d_in[19];
    const float* l3_att = (const float*)d_in[20];
    const float* l3_b  = (const float*)d_in[21];
    const float* lh_Wl = (const float*)d_in[22];
    const float* lh_Wr = (const float*)d_in[23];
    const float* lh_att = (const float*)d_in[24];
    const float* h1_Wl = (const float*)d_in[25];
    const float* h1_Wr = (const float*)d_in[26];
    const float* h1_att = (const float*)d_in[27];
    const float* h1_b  = (const float*)d_in[28];
    const float* bn3_g = (const float*)d_in[29];
    const float* bn3_b = (const float*)d_in[30];
    const float* h2_Wl = (const float*)d_in[31];
    const float* h2_Wr = (const float*)d_in[32];
    const float* h2_att = (const float*)d_in[33];
    const float* h2_b  = (const float*)d_in[34];
    const float* bn4_g = (const float*)d_in[35];
    const float* bn4_b = (const float*)d_in[36];
    const float* h3_Wl = (const float*)d_in[37];
    const float* h3_Wr = (const float*)d_in[38];
    const float* h3_att = (const float*)d_in[39];
    const float* h3_b  = (const float*)d_in[40];

    const int N_low = in_sizes[0] / 125;
    const int N_high = in_sizes[1];
    const int E_low = in_sizes[3] / 2;
    const int E_l2h = in_sizes[4] / 2;
    const int E_high = in_sizes[5] / 2;

    char* ws = (char*)d_ws;
    size_t woff = 0;
    auto walloc = [&](size_t bytes) -> void* {
        void* p = (void*)(ws + woff);
        woff += (bytes + 255) & ~(size_t)255;
        return p;
    };
    // XLR holds merged [XL|XR] GEMM outputs (max N_high x 512 bf16 = 61 MB)
    __hip_bfloat16* XLR = (__hip_bfloat16*)walloc((size_t)N_high * 512 * 2);
    __hip_bfloat16* A1  = (__hip_bfloat16*)walloc((size_t)N_high * 256 * 2);
    __hip_bfloat16* A2  = (__hip_bfloat16*)walloc((size_t)N_high * 128 * 2);
    __hip_bfloat16* XRo = (__hip_bfloat16*)walloc((size_t)N_high * 128 * 2); // lh outer xr
    __hip_bfloat16* XLOWB = (__hip_bfloat16*)walloc((size_t)N_low * 128 * 2);
    __hip_bfloat16* EHB = (__hip_bfloat16*)walloc((size_t)N_high * 160 * 2);
    float* YL = (float*)walloc((size_t)N_high * 2 * 4);
    float* YR = (float*)walloc((size_t)N_high * 2 * 4);
    int* off_low  = (int*)walloc((size_t)(N_low + 1) * 4);
    int* col_low  = (int*)walloc((size_t)E_low * 4);
    int* off_l2h  = (int*)walloc((size_t)(N_high + 1) * 4);
    int* col_l2h  = (int*)walloc((size_t)E_l2h * 4);
    int* off_high = (int*)walloc((size_t)(N_high + 1) * 4);
    int* col_high = (int*)walloc((size_t)E_high * 4);
    int* cursor   = (int*)walloc((size_t)(N_high + 1) * 4);
    int* bsum     = (int*)walloc(1025 * 4);
    float* bnpart = (float*)walloc(2 * 256 * 256 * 4);   // deterministic BN partials
    float* bnsc   = (float*)walloc(512 * 4);             // scale | shift
    float* bb     = (float*)walloc(512 * 4);             // folded gemm bias
    // merged [Wl|Wr] bf16 transposed weights [Ncat][Kp]
    __hip_bfloat16* w_l1 = (__hip_bfloat16*)walloc(512 * 128 * 2);
    __hip_bfloat16* w_l2 = (__hip_bfloat16*)walloc(256 * 256 * 2);
    __hip_bfloat16* w_l3 = (__hip_bfloat16*)walloc(256 * 128 * 2);
    __hip_bfloat16* w_lh = (__hip_bfloat16*)walloc(128 * 128 * 2);
    __hip_bfloat16* w_h1 = (__hip_bfloat16*)walloc(512 * 160 * 2);
    __hip_bfloat16* w_h2 = (__hip_bfloat16*)walloc(256 * 256 * 2);

    // ---- static weight & input conversion (tiny; BN-folded ones happen inline)
    auto wc = [&](const float* W, __hip_bfloat16* Wt, int K, int N, int Kp) {
        int n = N * Kp;
        wconv<<<(n + 255) / 256, 256, 0, stream>>>(W, Wt, K, N, Kp);
    };
    wc(l1_Wl, w_l1, 125, 256, 128);  wc(l1_Wr, w_l1 + 256 * 128, 125, 256, 128);
    wc(lh_Wl, w_lh, 128, 128, 128);
    wconv_h1<<<(256 * 160 + 255) / 256, 256, 0, stream>>>(h1_Wl, w_h1, 256);
    wconv_h1<<<(256 * 160 + 255) / 256, 256, 0, stream>>>(h1_Wr, w_h1 + 256 * 160, 256);
    xconv<<<((size_t)N_low * 128 + 255) / 256, 256, 0, stream>>>(x_low, XLOWB, N_low);

    // ---- CSR build (parallel 3-phase scan)
    auto build_csr = [&](const int* edges, int E, int Nn, int* roff, int* colv) {
        hipMemsetAsync(cursor, 0, (size_t)Nn * 4, stream);
        count_kernel<<<(E + 255) / 256, 256, 0, stream>>>(edges + E, cursor, E);
        int B = (Nn + 1023) / 1024;
        scan_phase1<<<B, 1024, 0, stream>>>(cursor, roff, bsum, Nn);
        scan_phase2<<<1, 1024, 0, stream>>>(bsum, B);
        scan_phase3<<<(Nn + 1 + 1023) / 1024, 1024, 0, stream>>>(roff, bsum, Nn, B);
        hipMemcpyAsync(cursor, roff, (size_t)Nn * 4, hipMemcpyDeviceToDevice, stream);
        scatter_kernel<<<(E + 255) / 256, 256, 0, stream>>>(edges, edges + E, cursor, colv, E);
    };
    build_csr(e_low, E_low, N_low, off_low, col_low);
    build_csr(e_l2h, E_l2h, N_high, off_l2h, col_l2h);
    build_csr(e_high, E_high, N_high, off_high, col_high);

    auto gemm = [&](const __hip_bfloat16* A, const __hip_bfloat16* Bt, __hip_bfloat16* C,
                    int M, int N, int Kp, const float* bias) {
        dim3 g(N / 128, (M + 127) / 128);
        gemm_bf16_mfma<<<g, 256, 0, stream>>>(A, Bt, C, bias, M, N, Kp);
    };
    auto gat = [&](const __hip_bfloat16* xl, int xls, const __hip_bfloat16* xr, int xrs,
                   const int* roff, const int* colv,
                   const float* att, const float* bias,
                   __hip_bfloat16* outb, int obs, int n_dst, int H) {
        long thr = (long)n_dst * H * 64;
        gat_c128_v4<<<(unsigned)((thr + 255) / 256), 256, 0, stream>>>(
            xl, xls, xr, xrs, roff, colv, att, bias, outb, obs, n_dst, H);
    };
    // deterministic BN stats only (apply is folded into the consumer GEMM weights)
    auto bn_stats = [&](__hip_bfloat16* x, const float* g, const float* b, int Nr, int C) {
        int rpb = (Nr + 255) / 256;
        bn_partial_d<<<256, C, 0, stream>>>(x, bnpart, Nr, rpb);
        bn_finalize_w<<<(C * 64 + 255) / 256, 256, 0, stream>>>(bnpart, g, b, bnsc, bnsc + 256, Nr, C);
    };
    // fold bn (bnsc) into a merged [Wl|Wr] weight + bias pair
    auto fold2 = [&](const float* Wl, const float* Wr, __hip_bfloat16* Wt,
                     int K, int Nn, int Kp) {
        wconv_bnfold<<<Nn, 256, 0, stream>>>(Wl, bnsc, bnsc + 256, Wt, bb, K, Nn, Kp);
        wconv_bnfold<<<Nn, 256, 0, stream>>>(Wr, bnsc, bnsc + 256, Wt + (size_t)Nn * Kp, bb + Nn, K, Nn, Kp);
    };

    // ---- low_net layer 1: 125 -> (H=2) 256   (merged [XL|XR], stride 512)
    gemm(XLOWB, w_l1, XLR, N_low, 512, 128, nullptr);
    gat(XLR, 512, XLR + 256, 512, off_low, col_low, l1_att, l1_b, A1, 256, N_low, 2);
    bn_stats(A1, bn1_g, bn1_b, N_low, 256);

    // ---- low_net layer 2: 256 -> 128 (BN1 folded into w_l2 + bias)
    fold2(l2_Wl, l2_Wr, w_l2, 256, 128, 256);
    gemm(A1, w_l2, XLR, N_low, 256, 256, bb);
    gat(XLR, 256, XLR + 128, 256, off_low, col_low, l2_att, l2_b, A2, 128, N_low, 1);
    bn_stats(A2, bn2_g, bn2_b, N_low, 128);

    // ---- low_net layer 3: 128 -> 128 (BN2 folded into w_l3 + bias)
    fold2(l3_Wl, l3_Wr, w_l3, 128, 128, 128);
    gemm(A2, w_l3, XLR, N_low, 256, 128, bb);
    gat(XLR, 256, XLR + 128, 256, off_low, col_low, l3_att, l3_b, A1, 128, N_low, 1);

    // ---- bipartite low2high -> EHB[N_high][160] = [gat 0..127 | z | pad]
    gemm(A1, w_lh, XLR, N_low, 128, 128, nullptr);   // xl only, stride 128
    outer_xr_b<<<(unsigned)(((size_t)N_high * 128 + 255) / 256), 256, 0, stream>>>(x_high, lh_Wr, XRo, N_high);
    hipMemsetAsync(EHB, 0, (size_t)N_high * 160 * 2, stream);
    gat(XLR, 128, XRo, 128, off_l2h, col_l2h, lh_att, nullptr, EHB, 160, N_high, 1);
    set_colz<<<(N_high + 255) / 256, 256, 0, stream>>>(z_std, EHB, N_high);

    // ---- high_net layer 1: 129(perm,pad160) -> (H=2) 256   (merged, stride 512)
    gemm(EHB, w_h1, XLR, N_high, 512, 160, nullptr);
    gat(XLR, 512, XLR + 256, 512, off_high, col_high, h1_att, h1_b, A1, 256, N_high, 2);
    bn_stats(A1, bn3_g, bn3_b, N_high, 256);

    // ---- high_net layer 2: 256 -> 128 (BN3 folded into w_h2 + bias)
    fold2(h2_Wl, h2_Wr, w_h2, 256, 128, 256);
    gemm(A1, w_h2, XLR, N_high, 256, 256, bb);
    gat(XLR, 256, XLR + 128, 256, off_high, col_high, h2_att, h2_b, A2, 128, N_high, 1);
    bn_stats(A2, bn4_g, bn4_b, N_high, 128);

    // ---- high_net layer 3: 128 -> 2 (BN4 applied inline in f32; one pass over A2)
    gemm_n22_bn<<<(N_high + 255) / 256, 256, 0, stream>>>(A2, h3_Wl, h3_Wr,
                                                          bnsc, bnsc + 256, YL, YR, N_high, 128);
    gat_c2<<<(N_high + 255) / 256, 256, 0, stream>>>(YL, YR, off_high, col_high,
                                                     h3_att, h3_b, (float*)d_out, N_high);
}

// Round 4
// 843.083 us; speedup vs baseline: 1.0810x; 1.0435x over previous
//
#include <hip/hip_runtime.h>
#include <hip/hip_bf16.h>
#include <cstdint>
#include <cstddef>

#define NEG_SLOPE 0.2f

using frag = __attribute__((ext_vector_type(8))) short;   // 8 bf16 = 4 VGPRs
using facc = __attribute__((ext_vector_type(4))) float;   // 4 fp32 accum

__device__ __forceinline__ float bf_hi(unsigned u) {
    union { unsigned i; float f; } t; t.i = u & 0xffff0000u; return t.f;
}
__device__ __forceinline__ float bf_lo(unsigned u) {
    union { unsigned i; float f; } t; t.i = u << 16; return t.f;
}
__device__ __forceinline__ void unpack8(uint4 u, float* v) {
    v[0] = bf_lo(u.x); v[1] = bf_hi(u.x);
    v[2] = bf_lo(u.y); v[3] = bf_hi(u.y);
    v[4] = bf_lo(u.z); v[5] = bf_hi(u.z);
    v[6] = bf_lo(u.w); v[7] = bf_hi(u.w);
}

// async global->LDS, 16B per lane (wave-uniform LDS base + lane*16)
typedef const __attribute__((address_space(1))) void* gas_cptr;
typedef __attribute__((address_space(3))) void* las_ptr;
__device__ __forceinline__ void gload_lds16(const __hip_bfloat16* g, __hip_bfloat16* l) {
    __builtin_amdgcn_global_load_lds((gas_cptr)(const void*)g, (las_ptr)(void*)l, 16, 0, 0);
}

// ---------------------------------------------------------------- batched CSR build
// All three graphs (low, l2h, high) in one kernel per phase: 21 launches -> 6.
__global__ void zero3(int* c0, int n0, int* c1, int n1, int* c2, int n2) {
    int i = blockIdx.x * blockDim.x + threadIdx.x;
    if (i < n0) c0[i] = 0;
    if (i < n1) c1[i] = 0;
    if (i < n2) c2[i] = 0;
}

__global__ void count3(const int* __restrict__ d0, int E0, int* c0,
                       const int* __restrict__ d1, int E1, int* c1,
                       const int* __restrict__ d2, int E2, int* c2) {
    int i = blockIdx.x * blockDim.x + threadIdx.x;
    if (i < E0) atomicAdd(&c0[d0[i]], 1);
    else if (i < E0 + E1) atomicAdd(&c1[d1[i - E0]], 1);
    else if (i < E0 + E1 + E2) atomicAdd(&c2[d2[i - E0 - E1]], 1);
}

// segmented scan phase 1: block -> (segment, local block). bsum stride 128/seg.
__global__ void scan1_b(const int* in0, int* out0, int n0,
                        const int* in1, int* out1, int n1,
                        const int* in2, int* out2, int n2,
                        int B0, int B1, int* bsum) {
    __shared__ int buf[1024];
    int b = blockIdx.x;
    const int* in; int* out; int n; int lb; int* bs;
    if (b < B0)           { in = in0; out = out0; n = n0; lb = b;          bs = bsum; }
    else if (b < B0 + B1) { in = in1; out = out1; n = n1; lb = b - B0;     bs = bsum + 128; }
    else                  { in = in2; out = out2; n = n2; lb = b - B0 - B1; bs = bsum + 256; }
    int tid = threadIdx.x;
    int i = lb * 1024 + tid;
    int v = (i < n) ? in[i] : 0;
    buf[tid] = v;
    __syncthreads();
    for (int off = 1; off < 1024; off <<= 1) {
        int t = (tid >= off) ? buf[tid - off] : 0;
        __syncthreads();
        buf[tid] += t;
        __syncthreads();
    }
    if (i < n) out[i] = buf[tid] - v;           // exclusive
    if (tid == 1023) bs[lb] = buf[1023];
}

// phase 2: 3 wave-level scans (one wave per segment), B<=64 fast path.
__global__ void scan2_b(int* bsum, int B0, int B1, int B2) {
    int w = threadIdx.x >> 6;
    int lane = threadIdx.x & 63;
    if (w >= 3) return;
    int B = (w == 0) ? B0 : (w == 1) ? B1 : B2;
    int* bs = bsum + w * 128;
    if (B <= 64) {
        int v = (lane < B) ? bs[lane] : 0;
        int orig = v;
#pragma unroll
        for (int off = 1; off < 64; off <<= 1) {
            int t = __shfl_up(v, off, 64);
            if (lane >= off) v += t;
        }
        if (lane < B) bs[lane] = v - orig;       // exclusive
        if (lane == B - 1) bs[B] = v;            // total
    } else if (lane == 0) {
        int acc = 0;
        for (int i = 0; i < B; ++i) { int t = bs[i]; bs[i] = acc; acc += t; }
        bs[B] = acc;
    }
}

// phase 3: add block offsets; ALSO writes the scatter cursor (kills 3 D2D memcpys).
__global__ void scan3_b(int* out0, int* cur0, int n0, int B0,
                        int* out1, int* cur1, int n1, int B1,
                        int* out2, int* cur2, int n2, int B2,
                        const int* bsum) {
    int b = blockIdx.x;
    int* out; int* cur; int n; int lb; const int* bs; int B;
    if (b < B0)           { out = out0; cur = cur0; n = n0; lb = b;          bs = bsum;       B = B0; }
    else if (b < B0 + B1) { out = out1; cur = cur1; n = n1; lb = b - B0;     bs = bsum + 128; B = B1; }
    else                  { out = out2; cur = cur2; n = n2; lb = b - B0 - B1; bs = bsum + 256; B = B2; }
    int idx = lb * 1024 + threadIdx.x;
    if (idx < n) {
        int v = out[idx] + bs[idx >> 10];
        out[idx] = v;
        cur[idx] = v;
    } else if (idx == n) {
        out[n] = bs[B];
    }
}

__global__ void scatter3(const int* __restrict__ s0, const int* __restrict__ d0, int E0,
                         int* c0, int* col0,
                         const int* __restrict__ s1, const int* __restrict__ d1, int E1,
                         int* c1, int* col1,
                         const int* __restrict__ s2, const int* __restrict__ d2, int E2,
                         int* c2, int* col2) {
    int i = blockIdx.x * blockDim.x + threadIdx.x;
    if (i < E0) {
        int p = atomicAdd(&c0[d0[i]], 1); col0[p] = s0[i];
    } else if (i < E0 + E1) {
        int j = i - E0;
        int p = atomicAdd(&c1[d1[j]], 1); col1[p] = s1[j];
    } else if (i < E0 + E1 + E2) {
        int j = i - E0 - E1;
        int p = atomicAdd(&c2[d2[j]], 1); col2[p] = s2[j];
    }
}

// ---------------------------------------------------------------- bf16 MFMA GEMM
// C[M,N] (bf16) = A[M,Kp] @ Bt[N,Kp]^T (+ bias[n]).  A,Bt bf16 row-major,
// Kp%32==0, N%128==0.  global_load_lds width-16 staging (async direct-to-LDS).
__global__ __launch_bounds__(256)
void gemm_bf16_mfma(const __hip_bfloat16* __restrict__ A,
                    const __hip_bfloat16* __restrict__ Bt,
                    __hip_bfloat16* __restrict__ C,
                    const float* __restrict__ bias, int M, int N, int Kp) {
    __shared__ __hip_bfloat16 As[128 * 32];
    __shared__ __hip_bfloat16 Bs[128 * 32];
    int tid = threadIdx.x;
    int lane = tid & 63;
    int wave = tid >> 6;
    int wm = wave >> 1, wn = wave & 1;
    int quad = lane >> 4, l16 = lane & 15;
    int m0 = blockIdx.y * 128;
    int n0 = blockIdx.x * 128;

    facc acc[4][4] = {};

    for (int k0 = 0; k0 < Kp; k0 += 32) {
#pragma unroll
        for (int p = 0; p < 2; ++p) {
            int idx = p * 256 + tid;          // 0..511 -> 16B chunk id
            int row = idx >> 2;               // 0..127
            int koff = (idx & 3) * 8;         // element offset in 32-elem row
            int gr = m0 + row; if (gr >= M) gr = M - 1;
            // wave-uniform LDS base (elements); lane dest = base + lane*16B
            int lbase = (p * 256 + wave * 64) * 8;
            gload_lds16(A + (size_t)gr * Kp + k0 + koff, As + lbase);
            gload_lds16(Bt + (size_t)(n0 + row) * Kp + k0 + koff, Bs + lbase);
        }
        __syncthreads();   // drains vmcnt (global_load_lds) before ds_read

        frag a[4], b[4];
#pragma unroll
        for (int i = 0; i < 4; ++i) {
            a[i] = *reinterpret_cast<const frag*>(As + (wm * 64 + i * 16 + l16) * 32 + quad * 8);
            b[i] = *reinterpret_cast<const frag*>(Bs + (wn * 64 + i * 16 + l16) * 32 + quad * 8);
        }
#pragma unroll
        for (int i = 0; i < 4; ++i)
#pragma unroll
            for (int j = 0; j < 4; ++j)
                acc[i][j] = __builtin_amdgcn_mfma_f32_16x16x32_bf16(a[i], b[j], acc[i][j], 0, 0, 0);
        __syncthreads();
    }

    // C/D layout: col = lane&15, row = quad*4 + reg
#pragma unroll
    for (int i = 0; i < 4; ++i)
#pragma unroll
        for (int j = 0; j < 4; ++j) {
            int col = n0 + wn * 64 + j * 16 + l16;
            float bv = (bias != nullptr) ? bias[col] : 0.f;
#pragma unroll
            for (int r = 0; r < 4; ++r) {
                int row = m0 + wm * 64 + i * 16 + quad * 4 + r;
                if (row < M) C[(size_t)row * N + col] = __float2bfloat16(acc[i][j][r] + bv);
            }
        }
}

// YL/YR[M,2] fp32 = (A*s+t)[M,K](bf16,BN-folded inline) @ {Wl,Wr}[K,2](fp32)
__global__ void gemm_n22_bn(const __hip_bfloat16* __restrict__ A,
                            const float* __restrict__ Wl, const float* __restrict__ Wr,
                            const float* __restrict__ s, const float* __restrict__ t,
                            float* __restrict__ YL, float* __restrict__ YR, int M, int K) {
    int i = blockIdx.x * blockDim.x + threadIdx.x;
    if (i >= M) return;
    float l0 = 0.f, l1 = 0.f, r0 = 0.f, r1 = 0.f;
    const unsigned* a = (const unsigned*)(A + (size_t)i * K);
    for (int k2 = 0; k2 < K / 2; ++k2) {
        unsigned u = a[k2];
        int k = k2 * 2;
        float v0 = fmaf(bf_lo(u), s[k], t[k]);          // BN applied in f32
        float v1 = fmaf(bf_hi(u), s[k + 1], t[k + 1]);
        l0 = fmaf(v0, Wl[k * 2 + 0], l0);
        l1 = fmaf(v0, Wl[k * 2 + 1], l1);
        l0 = fmaf(v1, Wl[k * 2 + 2], l0);
        l1 = fmaf(v1, Wl[k * 2 + 3], l1);
        r0 = fmaf(v0, Wr[k * 2 + 0], r0);
        r1 = fmaf(v0, Wr[k * 2 + 1], r1);
        r0 = fmaf(v1, Wr[k * 2 + 2], r0);
        r1 = fmaf(v1, Wr[k * 2 + 3], r1);
    }
    YL[(size_t)i * 2 + 0] = l0;
    YL[(size_t)i * 2 + 1] = l1;
    YR[(size_t)i * 2 + 0] = r0;
    YR[(size_t)i * 2 + 1] = r1;
}

// ---------------------------------------------------------------- batched prep
// All static weight transposes + input conversions + EHB pad/z init: 9 launches -> 1.
__global__ void prep_all(const float* __restrict__ l1Wl, const float* __restrict__ l1Wr,
                         const float* __restrict__ lhWl,
                         const float* __restrict__ h1Wl, const float* __restrict__ h1Wr,
                         const float* __restrict__ x_low, const float* __restrict__ x_high,
                         const float* __restrict__ lhWr, const float* __restrict__ z_std,
                         __hip_bfloat16* __restrict__ w_l1, __hip_bfloat16* __restrict__ w_lh,
                         __hip_bfloat16* __restrict__ w_h1,
                         __hip_bfloat16* __restrict__ XLOWB, __hip_bfloat16* __restrict__ XRo,
                         __hip_bfloat16* __restrict__ EHB,
                         int o1, int o2, int o3, int o4, int o5, int o6, int o7, int o8) {
    int i = blockIdx.x * blockDim.x + threadIdx.x;
    if (i < o1) {                              // xconv: N_low x 128 (pad 125->128)
        int r = i >> 7, c = i & 127;
        XLOWB[i] = __float2bfloat16((c < 125) ? x_low[(size_t)r * 125 + c] : 0.f);
    } else if (i < o2) {                       // outer_xr: N_high x 128
        int j = i - o1; int r = j >> 7, c = j & 127;
        XRo[j] = __float2bfloat16(x_high[r] * lhWr[c]);
    } else if (i < o3) {                       // EHB cols 128..159: z + zero pad
        int j = i - o2; int r = j >> 5, c = (j & 31) + 128;
        EHB[(size_t)r * 160 + c] = __float2bfloat16((c == 128) ? z_std[r] : 0.f);
    } else if (i < o4) {                       // w_l1 Wl [256][128], K=125
        int j = i - o3; int n = j >> 7, k = j & 127;
        w_l1[j] = __float2bfloat16((k < 125) ? l1Wl[(size_t)k * 256 + n] : 0.f);
    } else if (i < o5) {                       // w_l1 Wr
        int j = i - o4; int n = j >> 7, k = j & 127;
        w_l1[256 * 128 + j] = __float2bfloat16((k < 125) ? l1Wr[(size_t)k * 256 + n] : 0.f);
    } else if (i < o6) {                       // w_lh [128][128], K=128
        int j = i - o5; int n = j >> 7, k = j & 127;
        w_lh[j] = __float2bfloat16(lhWl[(size_t)k * 128 + n]);
    } else if (i < o7) {                       // w_h1 Wl perm [256][160]
        int j = i - o6; int n = j / 160, k = j - n * 160;
        float v = 0.f;
        if (k < 128) v = h1Wl[(size_t)(k + 1) * 256 + n];
        else if (k == 128) v = h1Wl[n];
        w_h1[j] = __float2bfloat16(v);
    } else if (i < o8) {                       // w_h1 Wr perm
        int j = i - o7; int n = j / 160, k = j - n * 160;
        float v = 0.f;
        if (k < 128) v = h1Wr[(size_t)(k + 1) * 256 + n];
        else if (k == 128) v = h1Wr[n];
        w_h1[256 * 160 + j] = __float2bfloat16(v);
    }
}

// BN-folded weight transpose, both Wl and Wr via blockIdx.y:
// Wt[y][n][k] = scale[k]*W[k][n] (bf16), bout[y*N+n] = sum_k shift[k]*W[k][n].
__global__ void wconv_bnfold2(const float* __restrict__ Wl, const float* __restrict__ Wr,
                              const float* __restrict__ scale, const float* __restrict__ shift,
                              __hip_bfloat16* __restrict__ Wt, float* __restrict__ bout,
                              int K, int N, int Kp) {
    __shared__ float red[256];
    const float* W = blockIdx.y ? Wr : Wl;
    __hip_bfloat16* wt = Wt + (size_t)blockIdx.y * N * Kp;
    float* bo = bout + blockIdx.y * N;
    int n = blockIdx.x;
    int tid = threadIdx.x;
    float acc = 0.f;
    for (int k = tid; k < Kp; k += 256) {
        float v = 0.f;
        if (k < K) {
            float w = W[(size_t)k * N + n];
            v = w * scale[k];
            acc = fmaf(w, shift[k], acc);
        }
        wt[(size_t)n * Kp + k] = __float2bfloat16(v);
    }
    red[tid] = acc;
    __syncthreads();
    for (int o = 128; o; o >>= 1) {
        if (tid < o) red[tid] += red[tid + o];
        __syncthreads();
    }
    if (tid == 0) bo[n] = red[0];
}

// ---------------------------------------------------------------- fused GATv2 edge phase v4
// (verbatim best-measured version: 64.6us hot dispatch)
__global__ void gat_c128_v4(const __hip_bfloat16* __restrict__ xl, int xls,
                            const __hip_bfloat16* __restrict__ xr, int xrs,
                            const int* __restrict__ row_off, const int* __restrict__ col,
                            const float* __restrict__ att, const float* __restrict__ bias,
                            __hip_bfloat16* __restrict__ outb, int obstride,
                            int n_dst, int H) {
    int wid = (blockIdx.x * blockDim.x + threadIdx.x) >> 6;
    int lane = threadIdx.x & 63;
    int total = n_dst * H;
    if (wid >= total) return;
    int dst = wid / H;
    int h = wid - dst * H;
    int g = lane >> 4;        // edge slot 0..3
    int q = lane & 15;        // channel block: channels 8q..8q+7
    int cb = h * 128 + q * 8;
    int beg = row_off[dst], end = row_off[dst + 1];

    float xrv[8], av[8];
    unpack8(*(const uint4*)(xr + (size_t)dst * xrs + cb), xrv);
    {
        float4 a0 = *(const float4*)(att + cb);
        float4 a1 = *(const float4*)(att + cb + 4);
        av[0] = a0.x; av[1] = a0.y; av[2] = a0.z; av[3] = a0.w;
        av[4] = a1.x; av[5] = a1.y; av[6] = a1.z; av[7] = a1.w;
    }

    float s = 0.f;
    float acc[8] = {0.f, 0.f, 0.f, 0.f, 0.f, 0.f, 0.f, 0.f};

    if (beg < end) {
        // prologue: chunk0 row data, chunk1 col index
        int e0g = beg + g;
        bool pv = e0g < end;
        int i0 = col[pv ? e0g : beg];
        uint4 u = *(const uint4*)(xl + (size_t)i0 * xls + cb);
        int e1g = beg + 4 + g;
        int i1 = (beg + 4 < end) ? col[(e1g < end) ? e1g : beg] : 0;

        for (int e0 = beg; e0 < end; e0 += 4) {
            bool have_next = (e0 + 4) < end;
            uint4 un;
            if (have_next)
                un = *(const uint4*)(xl + (size_t)i1 * xls + cb);   // issue early
            int e2g = e0 + 8 + g;
            int i2 = (e0 + 8 < end) ? col[(e2g < end) ? e2g : beg] : 0;
            bool nv = (e0 + 4 + g) < end;

            // process current chunk
            float v[8];
            unpack8(u, v);
            float p = 0.f;
#pragma unroll
            for (int c = 0; c < 8; ++c) {
                float z = v[c] + xrv[c];
                z = fmaxf(z, NEG_SLOPE * z);    // leaky-relu, slope<1
                p = fmaf(z, av[c], p);
            }
            p += __shfl_xor(p, 8, 64);
            p += __shfl_xor(p, 4, 64);
            p += __shfl_xor(p, 2, 64);
            p += __shfl_xor(p, 1, 64);
            if (!pv) p = -INFINITY;
            float w = __expf(fminf(p, 85.f));   // 0 for invalid slots
            s += w;
#pragma unroll
            for (int c = 0; c < 8; ++c) acc[c] = fmaf(w, v[c], acc[c]);

            if (have_next) { u = un; pv = nv; }
            i1 = i2;
        }
    }

    // merge the 4 edge-groups (lane^16 / lane^32 hold matching channels)
#pragma unroll
    for (int o = 16; o <= 32; o <<= 1) {
        s += __shfl_xor(s, o, 64);
#pragma unroll
        for (int c = 0; c < 8; ++c) acc[c] += __shfl_xor(acc[c], o, 64);
    }

    int deg = end - beg;
    float inv = (deg > 0) ? 1.f / (s * (float)deg) : 0.f;
    float o8[8];
#pragma unroll
    for (int c = 0; c < 8; ++c) o8[c] = acc[c] * inv;
    if (bias != nullptr) {
#pragma unroll
        for (int c = 0; c < 8; ++c) o8[c] += bias[cb + c];
    }
    if (g == 0) {
        union { uint4 u; __hip_bfloat16 hh[8]; } pk;
#pragma unroll
        for (int c = 0; c < 8; ++c) pk.hh[c] = __float2bfloat16(o8[c]);
        *(uint4*)(outb + (size_t)dst * obstride + cb) = pk.u;
    }
}

// C=2, H=1 final layer: one thread per dst (fp32 xl/xr).
__global__ void gat_c2(const float* __restrict__ xl, const float* __restrict__ xr,
                       const int* __restrict__ row_off, const int* __restrict__ col,
                       const float* __restrict__ att, const float* __restrict__ bias,
                       float* __restrict__ out, int n_dst) {
    int dst = blockIdx.x * blockDim.x + threadIdx.x;
    if (dst >= n_dst) return;
    float x0 = xr[(size_t)dst * 2], x1 = xr[(size_t)dst * 2 + 1];
    float a0 = att[0], a1 = att[1];
    int beg = row_off[dst], end = row_off[dst + 1];
    float s = 0.f, acc0 = 0.f, acc1 = 0.f;
    for (int e = beg; e < end; ++e) {
        int src = col[e];
        float v0 = xl[(size_t)src * 2], v1 = xl[(size_t)src * 2 + 1];
        float z0 = v0 + x0; z0 = fmaxf(z0, NEG_SLOPE * z0);
        float z1 = v1 + x1; z1 = fmaxf(z1, NEG_SLOPE * z1);
        float p = fmaf(z0, a0, z1 * a1);
        float w = __expf(fminf(p, 85.f));
        s += w;
        acc0 = fmaf(w, v0, acc0);
        acc1 = fmaf(w, v1, acc1);
    }
    int deg = end - beg;
    float o0 = 0.f, o1 = 0.f;
    if (deg > 0) {
        float inv = 1.f / (s * (float)deg);
        o0 = acc0 * inv;
        o1 = acc1 * inv;
    }
    out[(size_t)dst * 2 + 0] = o0 + bias[0];
    out[(size_t)dst * 2 + 1] = o1 + bias[1];
}

// ---------------------------------------------------------------- BatchNorm stats (deterministic)
__global__ void bn_partial_d(const __hip_bfloat16* __restrict__ x, float* __restrict__ part,
                             int Nr, int rpb) {
    int C = blockDim.x;
    int c = threadIdx.x;
    int b = blockIdx.x;
    int r0 = b * rpb;
    int r1 = r0 + rpb; if (r1 > Nr) r1 = Nr;
    float s = 0.f, q = 0.f;
    for (int r = r0; r < r1; ++r) {
        float v = __bfloat162float(x[(size_t)r * C + c]);
        s += v;
        q = fmaf(v, v, q);
    }
    part[(size_t)b * C + c] = s;
    part[65536 + (size_t)b * C + c] = q;   // 256*256 slot offset
}

__global__ void bn_finalize_w(const float* __restrict__ part,
                              const float* __restrict__ g, const float* __restrict__ b,
                              float* __restrict__ scale, float* __restrict__ shift,
                              int Nr, int C) {
    int c = (blockIdx.x * blockDim.x + threadIdx.x) >> 6;
    int lane = threadIdx.x & 63;
    if (c >= C) return;
    float s = 0.f, q = 0.f;
    for (int blk = lane; blk < 256; blk += 64) {
        s += part[(size_t)blk * C + c];
        q += part[65536 + (size_t)blk * C + c];
    }
#pragma unroll
    for (int o = 32; o; o >>= 1) {
        s += __shfl_xor(s, o, 64);
        q += __shfl_xor(q, o, 64);
    }
    if (lane == 0) {
        float mu = s / (float)Nr;
        float var = q / (float)Nr - mu * mu;
        float inv = rsqrtf(var + 1e-5f);
        float a = g[c] * inv;
        scale[c] = a;
        shift[c] = b[c] - mu * a;
    }
}

// ---------------------------------------------------------------- driver
extern "C" void kernel_launch(void* const* d_in, const int* in_sizes, int n_in,
                              void* d_out, int out_size, void* d_ws, size_t ws_size,
                              hipStream_t stream) {
    const float* x_low  = (const float*)d_in[0];
    const float* x_high = (const float*)d_in[1];
    const float* z_std  = (const float*)d_in[2];
    const int* e_low  = (const int*)d_in[3];
    const int* e_l2h  = (const int*)d_in[4];
    const int* e_high = (const int*)d_in[5];
    const float* l1_Wl = (const float*)d_in[6];
    const float* l1_Wr = (const float*)d_in[7];
    const float* l1_att = (const float*)d_in[8];
    const float* l1_b  = (const float*)d_in[9];
    const float* bn1_g = (const float*)d_in[10];
    const float* bn1_b = (const float*)d_in[11];
    const float* l2_Wl = (const float*)d_in[12];
    const float* l2_Wr = (const float*)d_in[13];
    const float* l2_att = (const float*)d_in[14];
    const float* l2_b  = (const float*)d_in[15];
    const float* bn2_g = (const float*)d_in[16];
    const float* bn2_b = (const float*)d_in[17];
    const float* l3_Wl = (const float*)d_in[18];
    const float* l3_Wr = (const float*)d_in[19];
    const float* l3_att = (const float*)d_in[20];
    const float* l3_b  = (const float*)d_in[21];
    const float* lh_Wl = (const float*)d_in[22];
    const float* lh_Wr = (const float*)d_in[23];
    const float* lh_att = (const float*)d_in[24];
    const float* h1_Wl = (const float*)d_in[25];
    const float* h1_Wr = (const float*)d_in[26];
    const float* h1_att = (const float*)d_in[27];
    const float* h1_b  = (const float*)d_in[28];
    const float* bn3_g = (const float*)d_in[29];
    const float* bn3_b = (const float*)d_in[30];
    const float* h2_Wl = (const float*)d_in[31];
    const float* h2_Wr = (const float*)d_in[32];
    const float* h2_att = (const float*)d_in[33];
    const float* h2_b  = (const float*)d_in[34];
    const float* bn4_g = (const float*)d_in[35];
    const float* bn4_b = (const float*)d_in[36];
    const float* h3_Wl = (const float*)d_in[37];
    const float* h3_Wr = (const float*)d_in[38];
    const float* h3_att = (const float*)d_in[39];
    const float* h3_b  = (const float*)d_in[40];

    const int N_low = in_sizes[0] / 125;
    const int N_high = in_sizes[1];
    const int E_low = in_sizes[3] / 2;
    const int E_l2h = in_sizes[4] / 2;
    const int E_high = in_sizes[5] / 2;

    char* ws = (char*)d_ws;
    size_t woff = 0;
    auto walloc = [&](size_t bytes) -> void* {
        void* p = (void*)(ws + woff);
        woff += (bytes + 255) & ~(size_t)255;
        return p;
    };
    // XLR holds merged [XL|XR] GEMM outputs (max N_high x 512 bf16 = 61 MB)
    __hip_bfloat16* XLR = (__hip_bfloat16*)walloc((size_t)N_high * 512 * 2);
    __hip_bfloat16* A1  = (__hip_bfloat16*)walloc((size_t)N_high * 256 * 2);
    __hip_bfloat16* A2  = (__hip_bfloat16*)walloc((size_t)N_high * 128 * 2);
    __hip_bfloat16* XRo = (__hip_bfloat16*)walloc((size_t)N_high * 128 * 2); // lh outer xr
    __hip_bfloat16* XLOWB = (__hip_bfloat16*)walloc((size_t)N_low * 128 * 2);
    __hip_bfloat16* EHB = (__hip_bfloat16*)walloc((size_t)N_high * 160 * 2);
    float* YL = (float*)walloc((size_t)N_high * 2 * 4);
    float* YR = (float*)walloc((size_t)N_high * 2 * 4);
    int* off_low  = (int*)walloc((size_t)(N_low + 1) * 4);
    int* col_low  = (int*)walloc((size_t)E_low * 4);
    int* off_l2h  = (int*)walloc((size_t)(N_high + 1) * 4);
    int* col_l2h  = (int*)walloc((size_t)E_l2h * 4);
    int* off_high = (int*)walloc((size_t)(N_high + 1) * 4);
    int* col_high = (int*)walloc((size_t)E_high * 4);
    int* cur_low  = (int*)walloc((size_t)(N_low + 1) * 4);   // also cnt
    int* cur_l2h  = (int*)walloc((size_t)(N_high + 1) * 4);  // also cnt
    int* cur_high = (int*)walloc((size_t)(N_high + 1) * 4);  // also cnt
    int* bsum     = (int*)walloc(512 * 4);                   // 3 segs x 128
    float* bnpart = (float*)walloc(2 * 256 * 256 * 4);   // deterministic BN partials
    float* bnsc   = (float*)walloc(512 * 4);             // scale | shift
    float* bb     = (float*)walloc(512 * 4);             // folded gemm bias
    // merged [Wl|Wr] bf16 transposed weights [Ncat][Kp]
    __hip_bfloat16* w_l1 = (__hip_bfloat16*)walloc(512 * 128 * 2);
    __hip_bfloat16* w_l2 = (__hip_bfloat16*)walloc(256 * 256 * 2);
    __hip_bfloat16* w_l3 = (__hip_bfloat16*)walloc(256 * 128 * 2);
    __hip_bfloat16* w_lh = (__hip_bfloat16*)walloc(128 * 128 * 2);
    __hip_bfloat16* w_h1 = (__hip_bfloat16*)walloc(512 * 160 * 2);
    __hip_bfloat16* w_h2 = (__hip_bfloat16*)walloc(256 * 256 * 2);

    // ---- batched prep: all static converts + EHB pad/z init in ONE launch
    {
        int o1 = N_low * 128;              // xconv
        int o2 = o1 + N_high * 128;        // outer_xr
        int o3 = o2 + N_high * 32;         // EHB cols 128..159
        int o4 = o3 + 256 * 128;           // w_l1 Wl
        int o5 = o4 + 256 * 128;           // w_l1 Wr
        int o6 = o5 + 128 * 128;           // w_lh
        int o7 = o6 + 256 * 160;           // w_h1 Wl
        int o8 = o7 + 256 * 160;           // w_h1 Wr
        prep_all<<<(o8 + 255) / 256, 256, 0, stream>>>(
            l1_Wl, l1_Wr, lh_Wl, h1_Wl, h1_Wr, x_low, x_high, lh_Wr, z_std,
            w_l1, w_lh, w_h1, XLOWB, XRo, EHB, o1, o2, o3, o4, o5, o6, o7, o8);
    }

    // ---- batched CSR build for all 3 graphs (6 launches total)
    {
        int B0 = (N_low + 1023) / 1024;
        int B1 = (N_high + 1023) / 1024;
        int B2 = (N_high + 1023) / 1024;
        int Etot = E_low + E_l2h + E_high;
        zero3<<<(N_high + 255) / 256, 256, 0, stream>>>(cur_low, N_low, cur_l2h, N_high, cur_high, N_high);
        count3<<<(Etot + 255) / 256, 256, 0, stream>>>(e_low + E_low, E_low, cur_low,
                                                       e_l2h + E_l2h, E_l2h, cur_l2h,
                                                       e_high + E_high, E_high, cur_high);
        scan1_b<<<B0 + B1 + B2, 1024, 0, stream>>>(cur_low, off_low, N_low,
                                                   cur_l2h, off_l2h, N_high,
                                                   cur_high, off_high, N_high, B0, B1, bsum);
        scan2_b<<<1, 192, 0, stream>>>(bsum, B0, B1, B2);
        scan3_b<<<B0 + B1 + B2, 1024, 0, stream>>>(off_low, cur_low, N_low, B0,
                                                   off_l2h, cur_l2h, N_high, B1,
                                                   off_high, cur_high, N_high, B2, bsum);
        scatter3<<<(Etot + 255) / 256, 256, 0, stream>>>(e_low, e_low + E_low, E_low, cur_low, col_low,
                                                         e_l2h, e_l2h + E_l2h, E_l2h, cur_l2h, col_l2h,
                                                         e_high, e_high + E_high, E_high, cur_high, col_high);
    }

    auto gemm = [&](const __hip_bfloat16* A, const __hip_bfloat16* Bt, __hip_bfloat16* C,
                    int M, int N, int Kp, const float* bias) {
        dim3 g(N / 128, (M + 127) / 128);
        gemm_bf16_mfma<<<g, 256, 0, stream>>>(A, Bt, C, bias, M, N, Kp);
    };
    auto gat = [&](const __hip_bfloat16* xl, int xls, const __hip_bfloat16* xr, int xrs,
                   const int* roff, const int* colv,
                   const float* att, const float* bias,
                   __hip_bfloat16* outb, int obs, int n_dst, int H) {
        long thr = (long)n_dst * H * 64;
        gat_c128_v4<<<(unsigned)((thr + 255) / 256), 256, 0, stream>>>(
            xl, xls, xr, xrs, roff, colv, att, bias, outb, obs, n_dst, H);
    };
    // deterministic BN stats only (apply is folded into the consumer GEMM weights)
    auto bn_stats = [&](__hip_bfloat16* x, const float* g, const float* b, int Nr, int C) {
        int rpb = (Nr + 255) / 256;
        bn_partial_d<<<256, C, 0, stream>>>(x, bnpart, Nr, rpb);
        bn_finalize_w<<<(C * 64 + 255) / 256, 256, 0, stream>>>(bnpart, g, b, bnsc, bnsc + 256, Nr, C);
    };
    // fold bn (bnsc) into a merged [Wl|Wr] weight + bias pair (one launch)
    auto fold2 = [&](const float* Wl, const float* Wr, __hip_bfloat16* Wt,
                     int K, int Nn, int Kp) {
        dim3 g(Nn, 2);
        wconv_bnfold2<<<g, 256, 0, stream>>>(Wl, Wr, bnsc, bnsc + 256, Wt, bb, K, Nn, Kp);
    };

    // ---- low_net layer 1: 125 -> (H=2) 256   (merged [XL|XR], stride 512)
    gemm(XLOWB, w_l1, XLR, N_low, 512, 128, nullptr);
    gat(XLR, 512, XLR + 256, 512, off_low, col_low, l1_att, l1_b, A1, 256, N_low, 2);
    bn_stats(A1, bn1_g, bn1_b, N_low, 256);

    // ---- low_net layer 2: 256 -> 128 (BN1 folded into w_l2 + bias)
    fold2(l2_Wl, l2_Wr, w_l2, 256, 128, 256);
    gemm(A1, w_l2, XLR, N_low, 256, 256, bb);
    gat(XLR, 256, XLR + 128, 256, off_low, col_low, l2_att, l2_b, A2, 128, N_low, 1);
    bn_stats(A2, bn2_g, bn2_b, N_low, 128);

    // ---- low_net layer 3: 128 -> 128 (BN2 folded into w_l3 + bias)
    fold2(l3_Wl, l3_Wr, w_l3, 128, 128, 128);
    gemm(A2, w_l3, XLR, N_low, 256, 128, bb);
    gat(XLR, 256, XLR + 128, 256, off_low, col_low, l3_att, l3_b, A1, 128, N_low, 1);

    // ---- bipartite low2high -> EHB[N_high][160] = [gat 0..127 | z | pad] (pad/z pre-inited)
    gemm(A1, w_lh, XLR, N_low, 128, 128, nullptr);   // xl only, stride 128
    gat(XLR, 128, XRo, 128, off_l2h, col_l2h, lh_att, nullptr, EHB, 160, N_high, 1);

    // ---- high_net layer 1: 129(perm,pad160) -> (H=2) 256   (merged, stride 512)
    gemm(EHB, w_h1, XLR, N_high, 512, 160, nullptr);
    gat(XLR, 512, XLR + 256, 512, off_high, col_high, h1_att, h1_b, A1, 256, N_high, 2);
    bn_stats(A1, bn3_g, bn3_b, N_high, 256);

    // ---- high_net layer 2: 256 -> 128 (BN3 folded into w_h2 + bias)
    fold2(h2_Wl, h2_Wr, w_h2, 256, 128, 256);
    gemm(A1, w_h2, XLR, N_high, 256, 256, bb);
    gat(XLR, 256, XLR + 128, 256, off_high, col_high, h2_att, h2_b, A2, 128, N_high, 1);
    bn_stats(A2, bn4_g, bn4_b, N_high, 128);

    // ---- high_net layer 3: 128 -> 2 (BN4 applied inline in f32; one pass over A2)
    gemm_n22_bn<<<(N_high + 255) / 256, 256, 0, stream>>>(A2, h3_Wl, h3_Wr,
                                                          bnsc, bnsc + 256, YL, YR, N_high, 128);
    gat_c2<<<(N_high + 255) / 256, 256, 0, stream>>>(YL, YR, off_high, col_high,
                                                     h3_att, h3_b, (float*)d_out, N_high);
}

// Round 5
// 804.621 us; speedup vs baseline: 1.1327x; 1.0478x over previous
//
#include <hip/hip_runtime.h>
#include <hip/hip_bf16.h>
#include <cstdint>
#include <cstddef>

#define NEG_SLOPE 0.2f

// bucketed CSR build params
#define BSH 6                    // 64 dsts per bucket
#define BS  (1 << BSH)
#define BCAP 1408                // >= mean+12sigma of bucket occupancy for all graphs
#define BPAD 16                  // cursor stride (ints) = 64B -> one L2 line per counter

using frag = __attribute__((ext_vector_type(8))) short;   // 8 bf16 = 4 VGPRs
using facc = __attribute__((ext_vector_type(4))) float;   // 4 fp32 accum

__device__ __forceinline__ float bf_hi(unsigned u) {
    union { unsigned i; float f; } t; t.i = u & 0xffff0000u; return t.f;
}
__device__ __forceinline__ float bf_lo(unsigned u) {
    union { unsigned i; float f; } t; t.i = u << 16; return t.f;
}
__device__ __forceinline__ void unpack8(uint4 u, float* v) {
    v[0] = bf_lo(u.x); v[1] = bf_hi(u.x);
    v[2] = bf_lo(u.y); v[3] = bf_hi(u.y);
    v[4] = bf_lo(u.z); v[5] = bf_hi(u.z);
    v[6] = bf_lo(u.w); v[7] = bf_hi(u.w);
}

// async global->LDS, 16B per lane (wave-uniform LDS base + lane*16)
typedef const __attribute__((address_space(1))) void* gas_cptr;
typedef __attribute__((address_space(3))) void* las_ptr;
__device__ __forceinline__ void gload_lds16(const __hip_bfloat16* g, __hip_bfloat16* l) {
    __builtin_amdgcn_global_load_lds((gas_cptr)(const void*)g, (las_ptr)(void*)l, 16, 0, 0);
}

// ---------------------------------------------------------------- bucketed CSR build
// Phase A: scatter edges into fixed-cap bucket regions (bucket = dst>>BSH).
// Cursor table is small (L2-hot) and 64B-padded; stage writes are localized
// per bucket -> L2 write-combining kills the 14x dword-scatter amplification.
__global__ void scatterA(const int* __restrict__ s0, const int* __restrict__ d0, int E0,
                         const int* __restrict__ s1, const int* __restrict__ d1, int E1,
                         const int* __restrict__ s2, const int* __restrict__ d2, int E2,
                         int nb0, int nb1, int* __restrict__ bcur, int2* __restrict__ stage) {
    int i = blockIdx.x * blockDim.x + threadIdx.x;
    int src, dst, gb;
    if (i < E0) { src = s0[i]; dst = d0[i]; gb = dst >> BSH; }
    else if (i < E0 + E1) { int j = i - E0; src = s1[j]; dst = d1[j]; gb = nb0 + (dst >> BSH); }
    else if (i < E0 + E1 + E2) { int j = i - E0 - E1; src = s2[j]; dst = d2[j]; gb = nb0 + nb1 + (dst >> BSH); }
    else return;
    int p = atomicAdd(&bcur[gb * BPAD], 1);
    if (p < BCAP) stage[(size_t)gb * BCAP + p] = make_int2(src, dst);
}

// Phase A.5: exclusive scan of bucket sizes -> global bstart. Single wave,
// 64-wide shfl chunks with carry (NBT ~ 2200 -> ~35 chunks, us-scale).
__global__ void scanB(const int* __restrict__ bcur, int* __restrict__ bstart, int NBT) {
    int lane = threadIdx.x;
    int carry = 0;
    for (int base = 0; base < NBT; base += 64) {
        int g = base + lane;
        int v = (g < NBT) ? bcur[g * BPAD] : 0;
        int sum = v;
#pragma unroll
        for (int o = 1; o < 64; o <<= 1) {
            int t = __shfl_up(sum, o, 64);
            if (lane >= o) sum += t;
        }
        if (g < NBT) bstart[g] = carry + sum - v;    // exclusive
        carry += __shfl(sum, 63, 64);
    }
}

// Phase B: one block per bucket. Entries -> LDS; per-dst count+scan+cursors in
// LDS (no global atomics); writes off[] for its 64 dsts and col confined to the
// bucket's contiguous region. Replaces count3 + 3 scan kernels + scatter3.
__global__ __launch_bounds__(256)
void scatterB(const int* __restrict__ bcur, const int* __restrict__ bstart,
              const int2* __restrict__ stage, int nb0, int nb1,
              int* __restrict__ off0, int* __restrict__ col0, int n0, int E0,
              int* __restrict__ off1, int* __restrict__ col1, int n1, int E1,
              int* __restrict__ off2, int* __restrict__ col2, int n2, int E2) {
    __shared__ int2 ent[BCAP];
    __shared__ int cnt[BS];
    int gb = blockIdx.x;
    int lb, n, ebase, El;
    int* off; int* col;
    if (gb < nb0)            { lb = gb;             off = off0; col = col0; n = n0; ebase = 0;       El = E0; }
    else if (gb < nb0 + nb1) { lb = gb - nb0;       off = off1; col = col1; n = n1; ebase = E0;      El = E1; }
    else                     { lb = gb - nb0 - nb1; off = off2; col = col2; n = n2; ebase = E0 + E1; El = E2; }
    int nbg = (n + BS - 1) >> BSH;
    int sz = bcur[gb * BPAD];
    if (sz > BCAP) sz = BCAP;
    int base = bstart[gb] - ebase;      // graph-local col offset
    int dlo = lb << BSH;
    int tid = threadIdx.x;
    if (tid < BS) cnt[tid] = 0;
    __syncthreads();
    const int2* st = stage + (size_t)gb * BCAP;
    for (int i = tid; i < sz; i += 256) {
        int2 e = st[i];
        ent[i] = e;
        atomicAdd(&cnt[e.y - dlo], 1);
    }
    __syncthreads();
    if (tid < BS) {
        int v = cnt[tid];
        int sum = v;
#pragma unroll
        for (int o = 1; o < BS; o <<= 1) {
            int t = __shfl_up(sum, o, 64);
            if (tid >= o) sum += t;
        }
        int excl = sum - v;
        cnt[tid] = base + excl;          // cursor start
        int d = dlo + tid;
        if (d < n) off[d] = base + excl;
        if (tid == 0 && lb == nbg - 1) off[n] = El;
    }
    __syncthreads();
    for (int i = tid; i < sz; i += 256) {
        int2 e = ent[i];
        int p = atomicAdd(&cnt[e.y - dlo], 1);   // LDS atomic
        col[p] = e.x;
    }
}

// ---------------------------------------------------------------- bf16 MFMA GEMM
// C[M,N] (bf16) = A[M,Kp] @ Bt[N,Kp]^T (+ bias[n]).  A,Bt bf16 row-major,
// Kp%32==0, N%128==0.  global_load_lds width-16 staging (async direct-to-LDS).
__global__ __launch_bounds__(256)
void gemm_bf16_mfma(const __hip_bfloat16* __restrict__ A,
                    const __hip_bfloat16* __restrict__ Bt,
                    __hip_bfloat16* __restrict__ C,
                    const float* __restrict__ bias, int M, int N, int Kp) {
    __shared__ __hip_bfloat16 As[128 * 32];
    __shared__ __hip_bfloat16 Bs[128 * 32];
    int tid = threadIdx.x;
    int lane = tid & 63;
    int wave = tid >> 6;
    int wm = wave >> 1, wn = wave & 1;
    int quad = lane >> 4, l16 = lane & 15;
    int m0 = blockIdx.y * 128;
    int n0 = blockIdx.x * 128;

    facc acc[4][4] = {};

    for (int k0 = 0; k0 < Kp; k0 += 32) {
#pragma unroll
        for (int p = 0; p < 2; ++p) {
            int idx = p * 256 + tid;          // 0..511 -> 16B chunk id
            int row = idx >> 2;               // 0..127
            int koff = (idx & 3) * 8;         // element offset in 32-elem row
            int gr = m0 + row; if (gr >= M) gr = M - 1;
            // wave-uniform LDS base (elements); lane dest = base + lane*16B
            int lbase = (p * 256 + wave * 64) * 8;
            gload_lds16(A + (size_t)gr * Kp + k0 + koff, As + lbase);
            gload_lds16(Bt + (size_t)(n0 + row) * Kp + k0 + koff, Bs + lbase);
        }
        __syncthreads();   // drains vmcnt (global_load_lds) before ds_read

        frag a[4], b[4];
#pragma unroll
        for (int i = 0; i < 4; ++i) {
            a[i] = *reinterpret_cast<const frag*>(As + (wm * 64 + i * 16 + l16) * 32 + quad * 8);
            b[i] = *reinterpret_cast<const frag*>(Bs + (wn * 64 + i * 16 + l16) * 32 + quad * 8);
        }
#pragma unroll
        for (int i = 0; i < 4; ++i)
#pragma unroll
            for (int j = 0; j < 4; ++j)
                acc[i][j] = __builtin_amdgcn_mfma_f32_16x16x32_bf16(a[i], b[j], acc[i][j], 0, 0, 0);
        __syncthreads();
    }

    // C/D layout: col = lane&15, row = quad*4 + reg
#pragma unroll
    for (int i = 0; i < 4; ++i)
#pragma unroll
        for (int j = 0; j < 4; ++j) {
            int col = n0 + wn * 64 + j * 16 + l16;
            float bv = (bias != nullptr) ? bias[col] : 0.f;
#pragma unroll
            for (int r = 0; r < 4; ++r) {
                int row = m0 + wm * 64 + i * 16 + quad * 4 + r;
                if (row < M) C[(size_t)row * N + col] = __float2bfloat16(acc[i][j][r] + bv);
            }
        }
}

// YL/YR[M,2] fp32 = (A*s+t)[M,K](bf16,BN-folded inline) @ {Wl,Wr}[K,2](fp32)
__global__ void gemm_n22_bn(const __hip_bfloat16* __restrict__ A,
                            const float* __restrict__ Wl, const float* __restrict__ Wr,
                            const float* __restrict__ s, const float* __restrict__ t,
                            float* __restrict__ YL, float* __restrict__ YR, int M, int K) {
    int i = blockIdx.x * blockDim.x + threadIdx.x;
    if (i >= M) return;
    float l0 = 0.f, l1 = 0.f, r0 = 0.f, r1 = 0.f;
    const unsigned* a = (const unsigned*)(A + (size_t)i * K);
    for (int k2 = 0; k2 < K / 2; ++k2) {
        unsigned u = a[k2];
        int k = k2 * 2;
        float v0 = fmaf(bf_lo(u), s[k], t[k]);          // BN applied in f32
        float v1 = fmaf(bf_hi(u), s[k + 1], t[k + 1]);
        l0 = fmaf(v0, Wl[k * 2 + 0], l0);
        l1 = fmaf(v0, Wl[k * 2 + 1], l1);
        l0 = fmaf(v1, Wl[k * 2 + 2], l0);
        l1 = fmaf(v1, Wl[k * 2 + 3], l1);
        r0 = fmaf(v0, Wr[k * 2 + 0], r0);
        r1 = fmaf(v0, Wr[k * 2 + 1], r1);
        r0 = fmaf(v1, Wr[k * 2 + 2], r0);
        r1 = fmaf(v1, Wr[k * 2 + 3], r1);
    }
    YL[(size_t)i * 2 + 0] = l0;
    YL[(size_t)i * 2 + 1] = l1;
    YR[(size_t)i * 2 + 0] = r0;
    YR[(size_t)i * 2 + 1] = r1;
}

// ---------------------------------------------------------------- batched prep
// All static weight transposes + input conversions + EHB pad/z init + bcur zero.
__global__ void prep_all(const float* __restrict__ l1Wl, const float* __restrict__ l1Wr,
                         const float* __restrict__ lhWl,
                         const float* __restrict__ h1Wl, const float* __restrict__ h1Wr,
                         const float* __restrict__ x_low, const float* __restrict__ x_high,
                         const float* __restrict__ lhWr, const float* __restrict__ z_std,
                         __hip_bfloat16* __restrict__ w_l1, __hip_bfloat16* __restrict__ w_lh,
                         __hip_bfloat16* __restrict__ w_h1,
                         __hip_bfloat16* __restrict__ XLOWB, __hip_bfloat16* __restrict__ XRo,
                         __hip_bfloat16* __restrict__ EHB, int* __restrict__ bcur,
                         int o1, int o2, int o3, int o4, int o5, int o6, int o7, int o8, int o9) {
    int i = blockIdx.x * blockDim.x + threadIdx.x;
    if (i < o1) {                              // xconv: N_low x 128 (pad 125->128)
        int r = i >> 7, c = i & 127;
        XLOWB[i] = __float2bfloat16((c < 125) ? x_low[(size_t)r * 125 + c] : 0.f);
    } else if (i < o2) {                       // outer_xr: N_high x 128
        int j = i - o1; int r = j >> 7, c = j & 127;
        XRo[j] = __float2bfloat16(x_high[r] * lhWr[c]);
    } else if (i < o3) {                       // EHB cols 128..159: z + zero pad
        int j = i - o2; int r = j >> 5, c = (j & 31) + 128;
        EHB[(size_t)r * 160 + c] = __float2bfloat16((c == 128) ? z_std[r] : 0.f);
    } else if (i < o4) {                       // w_l1 Wl [256][128], K=125
        int j = i - o3; int n = j >> 7, k = j & 127;
        w_l1[j] = __float2bfloat16((k < 125) ? l1Wl[(size_t)k * 256 + n] : 0.f);
    } else if (i < o5) {                       // w_l1 Wr
        int j = i - o4; int n = j >> 7, k = j & 127;
        w_l1[256 * 128 + j] = __float2bfloat16((k < 125) ? l1Wr[(size_t)k * 256 + n] : 0.f);
    } else if (i < o6) {                       // w_lh [128][128], K=128
        int j = i - o5; int n = j >> 7, k = j & 127;
        w_lh[j] = __float2bfloat16(lhWl[(size_t)k * 128 + n]);
    } else if (i < o7) {                       // w_h1 Wl perm [256][160]
        int j = i - o6; int n = j / 160, k = j - n * 160;
        float v = 0.f;
        if (k < 128) v = h1Wl[(size_t)(k + 1) * 256 + n];
        else if (k == 128) v = h1Wl[n];
        w_h1[j] = __float2bfloat16(v);
    } else if (i < o8) {                       // w_h1 Wr perm
        int j = i - o7; int n = j / 160, k = j - n * 160;
        float v = 0.f;
        if (k < 128) v = h1Wr[(size_t)(k + 1) * 256 + n];
        else if (k == 128) v = h1Wr[n];
        w_h1[256 * 160 + j] = __float2bfloat16(v);
    } else if (i < o9) {                       // zero bucket cursors
        bcur[i - o8] = 0;
    }
}

// BN-folded weight transpose, both Wl and Wr via blockIdx.y:
// Wt[y][n][k] = scale[k]*W[k][n] (bf16), bout[y*N+n] = sum_k shift[k]*W[k][n].
__global__ void wconv_bnfold2(const float* __restrict__ Wl, const float* __restrict__ Wr,
                              const float* __restrict__ scale, const float* __restrict__ shift,
                              __hip_bfloat16* __restrict__ Wt, float* __restrict__ bout,
                              int K, int N, int Kp) {
    __shared__ float red[256];
    const float* W = blockIdx.y ? Wr : Wl;
    __hip_bfloat16* wt = Wt + (size_t)blockIdx.y * N * Kp;
    float* bo = bout + blockIdx.y * N;
    int n = blockIdx.x;
    int tid = threadIdx.x;
    float acc = 0.f;
    for (int k = tid; k < Kp; k += 256) {
        float v = 0.f;
        if (k < K) {
            float w = W[(size_t)k * N + n];
            v = w * scale[k];
            acc = fmaf(w, shift[k], acc);
        }
        wt[(size_t)n * Kp + k] = __float2bfloat16(v);
    }
    red[tid] = acc;
    __syncthreads();
    for (int o = 128; o; o >>= 1) {
        if (tid < o) red[tid] += red[tid + o];
        __syncthreads();
    }
    if (tid == 0) bo[n] = red[0];
}

// ---------------------------------------------------------------- fused GATv2 edge phase v4
// (verbatim best-measured version: 64.6us hot dispatch)
__global__ void gat_c128_v4(const __hip_bfloat16* __restrict__ xl, int xls,
                            const __hip_bfloat16* __restrict__ xr, int xrs,
                            const int* __restrict__ row_off, const int* __restrict__ col,
                            const float* __restrict__ att, const float* __restrict__ bias,
                            __hip_bfloat16* __restrict__ outb, int obstride,
                            int n_dst, int H) {
    int wid = (blockIdx.x * blockDim.x + threadIdx.x) >> 6;
    int lane = threadIdx.x & 63;
    int total = n_dst * H;
    if (wid >= total) return;
    int dst = wid / H;
    int h = wid - dst * H;
    int g = lane >> 4;        // edge slot 0..3
    int q = lane & 15;        // channel block: channels 8q..8q+7
    int cb = h * 128 + q * 8;
    int beg = row_off[dst], end = row_off[dst + 1];

    float xrv[8], av[8];
    unpack8(*(const uint4*)(xr + (size_t)dst * xrs + cb), xrv);
    {
        float4 a0 = *(const float4*)(att + cb);
        float4 a1 = *(const float4*)(att + cb + 4);
        av[0] = a0.x; av[1] = a0.y; av[2] = a0.z; av[3] = a0.w;
        av[4] = a1.x; av[5] = a1.y; av[6] = a1.z; av[7] = a1.w;
    }

    float s = 0.f;
    float acc[8] = {0.f, 0.f, 0.f, 0.f, 0.f, 0.f, 0.f, 0.f};

    if (beg < end) {
        // prologue: chunk0 row data, chunk1 col index
        int e0g = beg + g;
        bool pv = e0g < end;
        int i0 = col[pv ? e0g : beg];
        uint4 u = *(const uint4*)(xl + (size_t)i0 * xls + cb);
        int e1g = beg + 4 + g;
        int i1 = (beg + 4 < end) ? col[(e1g < end) ? e1g : beg] : 0;

        for (int e0 = beg; e0 < end; e0 += 4) {
            bool have_next = (e0 + 4) < end;
            uint4 un;
            if (have_next)
                un = *(const uint4*)(xl + (size_t)i1 * xls + cb);   // issue early
            int e2g = e0 + 8 + g;
            int i2 = (e0 + 8 < end) ? col[(e2g < end) ? e2g : beg] : 0;
            bool nv = (e0 + 4 + g) < end;

            // process current chunk
            float v[8];
            unpack8(u, v);
            float p = 0.f;
#pragma unroll
            for (int c = 0; c < 8; ++c) {
                float z = v[c] + xrv[c];
                z = fmaxf(z, NEG_SLOPE * z);    // leaky-relu, slope<1
                p = fmaf(z, av[c], p);
            }
            p += __shfl_xor(p, 8, 64);
            p += __shfl_xor(p, 4, 64);
            p += __shfl_xor(p, 2, 64);
            p += __shfl_xor(p, 1, 64);
            if (!pv) p = -INFINITY;
            float w = __expf(fminf(p, 85.f));   // 0 for invalid slots
            s += w;
#pragma unroll
            for (int c = 0; c < 8; ++c) acc[c] = fmaf(w, v[c], acc[c]);

            if (have_next) { u = un; pv = nv; }
            i1 = i2;
        }
    }

    // merge the 4 edge-groups (lane^16 / lane^32 hold matching channels)
#pragma unroll
    for (int o = 16; o <= 32; o <<= 1) {
        s += __shfl_xor(s, o, 64);
#pragma unroll
        for (int c = 0; c < 8; ++c) acc[c] += __shfl_xor(acc[c], o, 64);
    }

    int deg = end - beg;
    float inv = (deg > 0) ? 1.f / (s * (float)deg) : 0.f;
    float o8[8];
#pragma unroll
    for (int c = 0; c < 8; ++c) o8[c] = acc[c] * inv;
    if (bias != nullptr) {
#pragma unroll
        for (int c = 0; c < 8; ++c) o8[c] += bias[cb + c];
    }
    if (g == 0) {
        union { uint4 u; __hip_bfloat16 hh[8]; } pk;
#pragma unroll
        for (int c = 0; c < 8; ++c) pk.hh[c] = __float2bfloat16(o8[c]);
        *(uint4*)(outb + (size_t)dst * obstride + cb) = pk.u;
    }
}

// C=2, H=1 final layer: one thread per dst (fp32 xl/xr).
__global__ void gat_c2(const float* __restrict__ xl, const float* __restrict__ xr,
                       const int* __restrict__ row_off, const int* __restrict__ col,
                       const float* __restrict__ att, const float* __restrict__ bias,
                       float* __restrict__ out, int n_dst) {
    int dst = blockIdx.x * blockDim.x + threadIdx.x;
    if (dst >= n_dst) return;
    float x0 = xr[(size_t)dst * 2], x1 = xr[(size_t)dst * 2 + 1];
    float a0 = att[0], a1 = att[1];
    int beg = row_off[dst], end = row_off[dst + 1];
    float s = 0.f, acc0 = 0.f, acc1 = 0.f;
    for (int e = beg; e < end; ++e) {
        int src = col[e];
        float v0 = xl[(size_t)src * 2], v1 = xl[(size_t)src * 2 + 1];
        float z0 = v0 + x0; z0 = fmaxf(z0, NEG_SLOPE * z0);
        float z1 = v1 + x1; z1 = fmaxf(z1, NEG_SLOPE * z1);
        float p = fmaf(z0, a0, z1 * a1);
        float w = __expf(fminf(p, 85.f));
        s += w;
        acc0 = fmaf(w, v0, acc0);
        acc1 = fmaf(w, v1, acc1);
    }
    int deg = end - beg;
    float o0 = 0.f, o1 = 0.f;
    if (deg > 0) {
        float inv = 1.f / (s * (float)deg);
        o0 = acc0 * inv;
        o1 = acc1 * inv;
    }
    out[(size_t)dst * 2 + 0] = o0 + bias[0];
    out[(size_t)dst * 2 + 1] = o1 + bias[1];
}

// ---------------------------------------------------------------- BatchNorm stats (deterministic)
__global__ void bn_partial_d(const __hip_bfloat16* __restrict__ x, float* __restrict__ part,
                             int Nr, int rpb) {
    int C = blockDim.x;
    int c = threadIdx.x;
    int b = blockIdx.x;
    int r0 = b * rpb;
    int r1 = r0 + rpb; if (r1 > Nr) r1 = Nr;
    float s = 0.f, q = 0.f;
    for (int r = r0; r < r1; ++r) {
        float v = __bfloat162float(x[(size_t)r * C + c]);
        s += v;
        q = fmaf(v, v, q);
    }
    part[(size_t)b * C + c] = s;
    part[65536 + (size_t)b * C + c] = q;   // 256*256 slot offset
}

__global__ void bn_finalize_w(const float* __restrict__ part,
                              const float* __restrict__ g, const float* __restrict__ b,
                              float* __restrict__ scale, float* __restrict__ shift,
                              int Nr, int C) {
    int c = (blockIdx.x * blockDim.x + threadIdx.x) >> 6;
    int lane = threadIdx.x & 63;
    if (c >= C) return;
    float s = 0.f, q = 0.f;
    for (int blk = lane; blk < 256; blk += 64) {
        s += part[(size_t)blk * C + c];
        q += part[65536 + (size_t)blk * C + c];
    }
#pragma unroll
    for (int o = 32; o; o >>= 1) {
        s += __shfl_xor(s, o, 64);
        q += __shfl_xor(q, o, 64);
    }
    if (lane == 0) {
        float mu = s / (float)Nr;
        float var = q / (float)Nr - mu * mu;
        float inv = rsqrtf(var + 1e-5f);
        float a = g[c] * inv;
        scale[c] = a;
        shift[c] = b[c] - mu * a;
    }
}

// ---------------------------------------------------------------- driver
extern "C" void kernel_launch(void* const* d_in, const int* in_sizes, int n_in,
                              void* d_out, int out_size, void* d_ws, size_t ws_size,
                              hipStream_t stream) {
    const float* x_low  = (const float*)d_in[0];
    const float* x_high = (const float*)d_in[1];
    const float* z_std  = (const float*)d_in[2];
    const int* e_low  = (const int*)d_in[3];
    const int* e_l2h  = (const int*)d_in[4];
    const int* e_high = (const int*)d_in[5];
    const float* l1_Wl = (const float*)d_in[6];
    const float* l1_Wr = (const float*)d_in[7];
    const float* l1_att = (const float*)d_in[8];
    const float* l1_b  = (const float*)d_in[9];
    const float* bn1_g = (const float*)d_in[10];
    const float* bn1_b = (const float*)d_in[11];
    const float* l2_Wl = (const float*)d_in[12];
    const float* l2_Wr = (const float*)d_in[13];
    const float* l2_att = (const float*)d_in[14];
    const float* l2_b  = (const float*)d_in[15];
    const float* bn2_g = (const float*)d_in[16];
    const float* bn2_b = (const float*)d_in[17];
    const float* l3_Wl = (const float*)d_in[18];
    const float* l3_Wr = (const float*)d_in[19];
    const float* l3_att = (const float*)d_in[20];
    const float* l3_b  = (const float*)d_in[21];
    const float* lh_Wl = (const float*)d_in[22];
    const float* lh_Wr = (const float*)d_in[23];
    const float* lh_att = (const float*)d_in[24];
    const float* h1_Wl = (const float*)d_in[25];
    const float* h1_Wr = (const float*)d_in[26];
    const float* h1_att = (const float*)d_in[27];
    const float* h1_b  = (const float*)d_in[28];
    const float* bn3_g = (const float*)d_in[29];
    const float* bn3_b = (const float*)d_in[30];
    const float* h2_Wl = (const float*)d_in[31];
    const float* h2_Wr = (const float*)d_in[32];
    const float* h2_att = (const float*)d_in[33];
    const float* h2_b  = (const float*)d_in[34];
    const float* bn4_g = (const float*)d_in[35];
    const float* bn4_b = (const float*)d_in[36];
    const float* h3_Wl = (const float*)d_in[37];
    const float* h3_Wr = (const float*)d_in[38];
    const float* h3_att = (const float*)d_in[39];
    const float* h3_b  = (const float*)d_in[40];

    const int N_low = in_sizes[0] / 125;
    const int N_high = in_sizes[1];
    const int E_low = in_sizes[3] / 2;
    const int E_l2h = in_sizes[4] / 2;
    const int E_high = in_sizes[5] / 2;

    char* ws = (char*)d_ws;
    size_t woff = 0;
    auto walloc = [&](size_t bytes) -> void* {
        void* p = (void*)(ws + woff);
        woff += (bytes + 255) & ~(size_t)255;
        return p;
    };
    // XLR holds merged [XL|XR] GEMM outputs (max N_high x 512 bf16 = 61 MB).
    // Before the first GEMM it is dead -> the CSR stage array aliases it.
    __hip_bfloat16* XLR = (__hip_bfloat16*)walloc((size_t)N_high * 512 * 2);
    __hip_bfloat16* A1  = (__hip_bfloat16*)walloc((size_t)N_high * 256 * 2);
    __hip_bfloat16* A2  = (__hip_bfloat16*)walloc((size_t)N_high * 128 * 2);
    __hip_bfloat16* XRo = (__hip_bfloat16*)walloc((size_t)N_high * 128 * 2); // lh outer xr
    __hip_bfloat16* XLOWB = (__hip_bfloat16*)walloc((size_t)N_low * 128 * 2);
    __hip_bfloat16* EHB = (__hip_bfloat16*)walloc((size_t)N_high * 160 * 2);
    float* YL = (float*)walloc((size_t)N_high * 2 * 4);
    float* YR = (float*)walloc((size_t)N_high * 2 * 4);
    int* off_low  = (int*)walloc((size_t)(N_low + 1) * 4);
    int* col_low  = (int*)walloc((size_t)E_low * 4);
    int* off_l2h  = (int*)walloc((size_t)(N_high + 1) * 4);
    int* col_l2h  = (int*)walloc((size_t)E_l2h * 4);
    int* off_high = (int*)walloc((size_t)(N_high + 1) * 4);
    int* col_high = (int*)walloc((size_t)E_high * 4);
    // bucketed CSR build state
    const int nb0 = (N_low + BS - 1) >> BSH;
    const int nb1 = (N_high + BS - 1) >> BSH;
    const int nb2 = (N_high + BS - 1) >> BSH;
    const int NBT = nb0 + nb1 + nb2;
    int* bcur   = (int*)walloc((size_t)NBT * BPAD * 4);
    int* bstart = (int*)walloc((size_t)(NBT + 1) * 4);
    float* bnpart = (float*)walloc(2 * 256 * 256 * 4);   // deterministic BN partials
    float* bnsc   = (float*)walloc(512 * 4);             // scale | shift
    float* bb     = (float*)walloc(512 * 4);             // folded gemm bias
    // merged [Wl|Wr] bf16 transposed weights [Ncat][Kp]
    __hip_bfloat16* w_l1 = (__hip_bfloat16*)walloc(512 * 128 * 2);
    __hip_bfloat16* w_l2 = (__hip_bfloat16*)walloc(256 * 256 * 2);
    __hip_bfloat16* w_l3 = (__hip_bfloat16*)walloc(256 * 128 * 2);
    __hip_bfloat16* w_lh = (__hip_bfloat16*)walloc(128 * 128 * 2);
    __hip_bfloat16* w_h1 = (__hip_bfloat16*)walloc(512 * 160 * 2);
    __hip_bfloat16* w_h2 = (__hip_bfloat16*)walloc(256 * 256 * 2);

    int2* stage = (int2*)XLR;   // 24.7 MB needed, 61 MB available; dead until first gemm

    // ---- batched prep: all static converts + EHB pad/z init + bcur zero in ONE launch
    {
        int o1 = N_low * 128;              // xconv
        int o2 = o1 + N_high * 128;        // outer_xr
        int o3 = o2 + N_high * 32;         // EHB cols 128..159
        int o4 = o3 + 256 * 128;           // w_l1 Wl
        int o5 = o4 + 256 * 128;           // w_l1 Wr
        int o6 = o5 + 128 * 128;           // w_lh
        int o7 = o6 + 256 * 160;           // w_h1 Wl
        int o8 = o7 + 256 * 160;           // w_h1 Wr
        int o9 = o8 + NBT * BPAD;          // bcur zero
        prep_all<<<(o9 + 255) / 256, 256, 0, stream>>>(
            l1_Wl, l1_Wr, lh_Wl, h1_Wl, h1_Wr, x_low, x_high, lh_Wr, z_std,
            w_l1, w_lh, w_h1, XLOWB, XRo, EHB, bcur,
            o1, o2, o3, o4, o5, o6, o7, o8, o9);
    }

    // ---- bucketed CSR build for all 3 graphs (3 launches)
    {
        int Etot = E_low + E_l2h + E_high;
        scatterA<<<(Etot + 255) / 256, 256, 0, stream>>>(
            e_low, e_low + E_low, E_low,
            e_l2h, e_l2h + E_l2h, E_l2h,
            e_high, e_high + E_high, E_high,
            nb0, nb1, bcur, stage);
        scanB<<<1, 64, 0, stream>>>(bcur, bstart, NBT);
        scatterB<<<NBT, 256, 0, stream>>>(bcur, bstart, stage, nb0, nb1,
                                          off_low, col_low, N_low, E_low,
                                          off_l2h, col_l2h, N_high, E_l2h,
                                          off_high, col_high, N_high, E_high);
    }

    auto gemm = [&](const __hip_bfloat16* A, const __hip_bfloat16* Bt, __hip_bfloat16* C,
                    int M, int N, int Kp, const float* bias) {
        dim3 g(N / 128, (M + 127) / 128);
        gemm_bf16_mfma<<<g, 256, 0, stream>>>(A, Bt, C, bias, M, N, Kp);
    };
    auto gat = [&](const __hip_bfloat16* xl, int xls, const __hip_bfloat16* xr, int xrs,
                   const int* roff, const int* colv,
                   const float* att, const float* bias,
                   __hip_bfloat16* outb, int obs, int n_dst, int H) {
        long thr = (long)n_dst * H * 64;
        gat_c128_v4<<<(unsigned)((thr + 255) / 256), 256, 0, stream>>>(
            xl, xls, xr, xrs, roff, colv, att, bias, outb, obs, n_dst, H);
    };
    // deterministic BN stats only (apply is folded into the consumer GEMM weights)
    auto bn_stats = [&](__hip_bfloat16* x, const float* g, const float* b, int Nr, int C) {
        int rpb = (Nr + 255) / 256;
        bn_partial_d<<<256, C, 0, stream>>>(x, bnpart, Nr, rpb);
        bn_finalize_w<<<(C * 64 + 255) / 256, 256, 0, stream>>>(bnpart, g, b, bnsc, bnsc + 256, Nr, C);
    };
    // fold bn (bnsc) into a merged [Wl|Wr] weight + bias pair (one launch)
    auto fold2 = [&](const float* Wl, const float* Wr, __hip_bfloat16* Wt,
                     int K, int Nn, int Kp) {
        dim3 g(Nn, 2);
        wconv_bnfold2<<<g, 256, 0, stream>>>(Wl, Wr, bnsc, bnsc + 256, Wt, bb, K, Nn, Kp);
    };

    // ---- low_net layer 1: 125 -> (H=2) 256   (merged [XL|XR], stride 512)
    gemm(XLOWB, w_l1, XLR, N_low, 512, 128, nullptr);
    gat(XLR, 512, XLR + 256, 512, off_low, col_low, l1_att, l1_b, A1, 256, N_low, 2);
    bn_stats(A1, bn1_g, bn1_b, N_low, 256);

    // ---- low_net layer 2: 256 -> 128 (BN1 folded into w_l2 + bias)
    fold2(l2_Wl, l2_Wr, w_l2, 256, 128, 256);
    gemm(A1, w_l2, XLR, N_low, 256, 256, bb);
    gat(XLR, 256, XLR + 128, 256, off_low, col_low, l2_att, l2_b, A2, 128, N_low, 1);
    bn_stats(A2, bn2_g, bn2_b, N_low, 128);

    // ---- low_net layer 3: 128 -> 128 (BN2 folded into w_l3 + bias)
    fold2(l3_Wl, l3_Wr, w_l3, 128, 128, 128);
    gemm(A2, w_l3, XLR, N_low, 256, 128, bb);
    gat(XLR, 256, XLR + 128, 256, off_low, col_low, l3_att, l3_b, A1, 128, N_low, 1);

    // ---- bipartite low2high -> EHB[N_high][160] = [gat 0..127 | z | pad] (pad/z pre-inited)
    gemm(A1, w_lh, XLR, N_low, 128, 128, nullptr);   // xl only, stride 128
    gat(XLR, 128, XRo, 128, off_l2h, col_l2h, lh_att, nullptr, EHB, 160, N_high, 1);

    // ---- high_net layer 1: 129(perm,pad160) -> (H=2) 256   (merged, stride 512)
    gemm(EHB, w_h1, XLR, N_high, 512, 160, nullptr);
    gat(XLR, 512, XLR + 256, 512, off_high, col_high, h1_att, h1_b, A1, 256, N_high, 2);
    bn_stats(A1, bn3_g, bn3_b, N_high, 256);

    // ---- high_net layer 2: 256 -> 128 (BN3 folded into w_h2 + bias)
    fold2(h2_Wl, h2_Wr, w_h2, 256, 128, 256);
    gemm(A1, w_h2, XLR, N_high, 256, 256, bb);
    gat(XLR, 256, XLR + 128, 256, off_high, col_high, h2_att, h2_b, A2, 128, N_high, 1);
    bn_stats(A2, bn4_g, bn4_b, N_high, 128);

    // ---- high_net layer 3: 128 -> 2 (BN4 applied inline in f32; one pass over A2)
    gemm_n22_bn<<<(N_high + 255) / 256, 256, 0, stream>>>(A2, h3_Wl, h3_Wr,
                                                          bnsc, bnsc + 256, YL, YR, N_high, 128);
    gat_c2<<<(N_high + 255) / 256, 256, 0, stream>>>(YL, YR, off_high, col_high,
                                                     h3_att, h3_b, (float*)d_out, N_high);
}

// Round 6
// 767.088 us; speedup vs baseline: 1.1881x; 1.0489x over previous
//
#include <hip/hip_runtime.h>
#include <hip/hip_bf16.h>
#include <cstdint>
#include <cstddef>
#include <cmath>

#define NEG_SLOPE 0.2f

// two-level multisplit CSR build params
#define PB  256                  // pass-1 blocks (each owns a private stage region)
#define CSH 10                   // 1024 dsts per coarse bucket
#define CBS 1024
#define NBCMAX 160

using frag = __attribute__((ext_vector_type(8))) short;   // 8 bf16 = 4 VGPRs
using facc = __attribute__((ext_vector_type(4))) float;   // 4 fp32 accum

__device__ __forceinline__ float bf_hi(unsigned u) {
    union { unsigned i; float f; } t; t.i = u & 0xffff0000u; return t.f;
}
__device__ __forceinline__ float bf_lo(unsigned u) {
    union { unsigned i; float f; } t; t.i = u << 16; return t.f;
}
__device__ __forceinline__ void unpack8(uint4 u, float* v) {
    v[0] = bf_lo(u.x); v[1] = bf_hi(u.x);
    v[2] = bf_lo(u.y); v[3] = bf_hi(u.y);
    v[4] = bf_lo(u.z); v[5] = bf_hi(u.z);
    v[6] = bf_lo(u.w); v[7] = bf_hi(u.w);
}

// async global->LDS, 16B per lane (wave-uniform LDS base + lane*16)
typedef const __attribute__((address_space(1))) void* gas_cptr;
typedef __attribute__((address_space(3))) void* las_ptr;
__device__ __forceinline__ void gload_lds16(const __hip_bfloat16* g, __hip_bfloat16* l) {
    __builtin_amdgcn_global_load_lds((gas_cptr)(const void*)g, (las_ptr)(void*)l, 16, 0, 0);
}

// ---------------------------------------------------------------- multisplit CSR build
// Pass 1: block-private coarse multisplit. Each block reorders its chunk in LDS
// per round and appends per-bucket runs to PRIVATE regions -> every 64B line has
// a single writer (one XCD): kills the partial-line writeback amplification
// (old scatterA: 76MB WRITE for 5.4MB useful). No global atomics at all.
__global__ __launch_bounds__(256)
void msplitA(const int* __restrict__ s0, const int* __restrict__ d0, int E0,
             const int* __restrict__ s1, const int* __restrict__ d1, int E1,
             const int* __restrict__ s2, const int* __restrict__ d2, int E2,
             int nc0, int nc1, int nc2, int cap0, int cap1, int cap2,
             int* __restrict__ stage, int* __restrict__ cnt2) {
    __shared__ int hist[NBCMAX];
    __shared__ int rbase[NBCMAX];
    __shared__ int curs[NBCMAX];
    __shared__ int ord[1024];
    __shared__ int obkt[1024];
    const int NBC = nc0 + nc1 + nc2;
    const long Etot = (long)E0 + E1 + E2;
    int tid = threadIdx.x;
    int lane = tid & 63;
    long chunk = (Etot + PB - 1) / PB;
    long c0 = (long)blockIdx.x * chunk;
    long c1 = c0 + chunk; if (c1 > Etot) c1 = Etot;
    const long sec1 = (long)PB * nc0 * cap0;
    const long sec2 = sec1 + (long)PB * nc1 * cap1;
    for (int t = tid; t < NBC; t += 256) curs[t] = 0;
    __syncthreads();
    for (long r0 = c0; r0 < c1; r0 += 1024) {
        int n = (int)((c1 - r0 < 1024) ? (c1 - r0) : 1024);
        for (int t = tid; t < NBC; t += 256) hist[t] = 0;
        __syncthreads();
        int mye[4], myb[4], myr[4];
#pragma unroll
        for (int k = 0; k < 4; ++k) {
            int li = k * 256 + tid;
            myb[k] = -1;
            if (li < n) {
                long i = r0 + li;
                int src, dst, gb;
                if (i < E0) { src = s0[i]; dst = d0[i]; gb = dst >> CSH; }
                else if (i < (long)E0 + E1) { long j = i - E0; src = s1[j]; dst = d1[j]; gb = nc0 + (dst >> CSH); }
                else { long j = i - E0 - E1; src = s2[j]; dst = d2[j]; gb = nc0 + nc1 + (dst >> CSH); }
                mye[k] = (src << CSH) | (dst & (CBS - 1));
                myb[k] = gb;
                myr[k] = atomicAdd(&hist[gb], 1);
            }
        }
        __syncthreads();
        // exclusive scan of hist (NBC<=160) by wave 0
        if (tid < 64) {
            int carry = 0;
            for (int base = 0; base < NBC; base += 64) {
                int g = base + lane;
                int v = (g < NBC) ? hist[g] : 0;
                int sum = v;
#pragma unroll
                for (int o = 1; o < 64; o <<= 1) {
                    int t = __shfl_up(sum, o, 64);
                    if (lane >= o) sum += t;
                }
                if (g < NBC) rbase[g] = carry + sum - v;
                carry += __shfl(sum, 63, 64);
            }
        }
        __syncthreads();
#pragma unroll
        for (int k = 0; k < 4; ++k)
            if (myb[k] >= 0) {
                int pos = rbase[myb[k]] + myr[k];
                ord[pos] = mye[k];
                obkt[pos] = myb[k];
            }
        __syncthreads();
        // append runs to block-private regions (consecutive lanes -> consecutive addrs)
        for (int pos = tid; pos < n; pos += 256) {
            int b = obkt[pos];
            int rank = pos - rbase[b] + curs[b];
            long addr; int cap;
            if (b < nc0)            { cap = cap0; addr = (long)(blockIdx.x * nc0 + b) * cap0; }
            else if (b < nc0 + nc1) { cap = cap1; addr = sec1 + (long)(blockIdx.x * nc1 + (b - nc0)) * cap1; }
            else                    { cap = cap2; addr = sec2 + (long)(blockIdx.x * nc2 + (b - nc0 - nc1)) * cap2; }
            if (rank < cap) stage[addr + rank] = ord[pos];
        }
        __syncthreads();
        for (int t = tid; t < NBC; t += 256) curs[t] += hist[t];
        __syncthreads();
    }
    for (int t = tid; t < NBC; t += 256) {
        int cap = (t < nc0) ? cap0 : (t < nc0 + nc1) ? cap1 : cap2;
        int c = curs[t]; if (c > cap) c = cap;
        cnt2[(long)blockIdx.x * NBC + t] = c;
    }
}

// exclusive scan of coarse-bucket totals, per graph -> col-region bases
__global__ void scanC(const int* __restrict__ cnt2, int* __restrict__ cstart,
                      int NBC, int nc0, int nc1) {
    __shared__ int tot[NBCMAX];
    int tid = threadIdx.x;
    for (int gb = tid; gb < NBC; gb += 256) {
        int s = 0;
        for (int b = 0; b < PB; ++b) s += cnt2[(long)b * NBC + gb];
        tot[gb] = s;
    }
    __syncthreads();
    if (tid == 0) {
        int c = 0;
        for (int gb = 0; gb < NBC; ++gb) {
            if (gb == nc0 || gb == nc0 + nc1) c = 0;
            cstart[gb] = c;
            c += tot[gb];
        }
    }
}

// Pass 2: one block per coarse bucket. Scan the 256 fragment counts, map flat
// positions -> fragments via binary search, LDS-count the 1024 dsts, block-scan,
// write off[], scatter col within a ~64KB window (LDS cursors, no global atomics
// outside this bucket's private col range).
__global__ __launch_bounds__(1024)
void fineB(const int* __restrict__ cnt2, const int* __restrict__ cstart,
           const int* __restrict__ stage,
           int nc0, int nc1, int nc2, int cap0, int cap1, int cap2,
           int* __restrict__ off0, int* __restrict__ col0, int n0,
           int* __restrict__ off1, int* __restrict__ col1, int n1,
           int* __restrict__ off2, int* __restrict__ col2, int n2) {
    __shared__ int fragb[257];
    __shared__ int cnt[1024];
    __shared__ int wsum[17];
    const int NBC = nc0 + nc1 + nc2;
    int gb = blockIdx.x;
    int tid = threadIdx.x;
    int lane = tid & 63;
    int wv = tid >> 6;
    int cb, ncg, n; long base2, stride; int* off; int* col;
    const long sec1 = (long)PB * nc0 * cap0;
    const long sec2 = sec1 + (long)PB * nc1 * cap1;
    if (gb < nc0) {
        cb = gb; ncg = nc0; n = n0; off = off0; col = col0;
        base2 = (long)cb * cap0; stride = (long)nc0 * cap0;
    } else if (gb < nc0 + nc1) {
        cb = gb - nc0; ncg = nc1; n = n1; off = off1; col = col1;
        base2 = sec1 + (long)cb * cap1; stride = (long)nc1 * cap1;
    } else {
        cb = gb - nc0 - nc1; ncg = nc2; n = n2; off = off2; col = col2;
        base2 = sec2 + (long)cb * cap2; stride = (long)nc2 * cap2;
    }
    int dlo = cb << CSH;
    int colbase = cstart[gb];
    // ---- exclusive scan of per-source-block fragment counts (256)
    int v = 0, sum = 0;
    if (tid < 256) {
        v = cnt2[(long)tid * NBC + gb];
        sum = v;
#pragma unroll
        for (int o = 1; o < 64; o <<= 1) {
            int t = __shfl_up(sum, o, 64);
            if (lane >= o) sum += t;
        }
        if (lane == 63) wsum[wv] = sum;
    }
    __syncthreads();
    if (tid == 0) {
        int c = 0;
        for (int w = 0; w < 4; ++w) { int t = wsum[w]; wsum[w] = c; c += t; }
        wsum[16] = c;
    }
    __syncthreads();
    if (tid < 256) fragb[tid] = wsum[wv] + sum - v;
    if (tid == 0) fragb[256] = wsum[16];
    __syncthreads();
    int sz = fragb[256];
    // ---- per-dst counts
    cnt[tid] = 0;
    __syncthreads();
    for (int p = tid; p < sz; p += 1024) {
        int lo = 0, hi = 256;
        while (hi - lo > 1) { int mid = (lo + hi) >> 1; if (fragb[mid] <= p) lo = mid; else hi = mid; }
        int e = stage[base2 + (long)lo * stride + (p - fragb[lo])];
        atomicAdd(&cnt[e & (CBS - 1)], 1);
    }
    __syncthreads();
    // ---- exclusive scan of cnt[1024]
    int cv = cnt[tid];
    int csum = cv;
#pragma unroll
    for (int o = 1; o < 64; o <<= 1) {
        int t = __shfl_up(csum, o, 64);
        if (lane >= o) csum += t;
    }
    if (lane == 63) wsum[wv] = csum;
    __syncthreads();
    if (tid == 0) {
        int c = 0;
        for (int w = 0; w < 16; ++w) { int t = wsum[w]; wsum[w] = c; c += t; }
    }
    __syncthreads();
    int excl = wsum[wv] + csum - cv;
    int d = dlo + tid;
    if (d < n) off[d] = colbase + excl;
    if (cb == ncg - 1 && tid == 0) off[n] = colbase + sz;
    __syncthreads();
    cnt[tid] = colbase + excl;      // cursors
    __syncthreads();
    // ---- scatter col
    for (int p = tid; p < sz; p += 1024) {
        int lo = 0, hi = 256;
        while (hi - lo > 1) { int mid = (lo + hi) >> 1; if (fragb[mid] <= p) lo = mid; else hi = mid; }
        int e = stage[base2 + (long)lo * stride + (p - fragb[lo])];
        int pos = atomicAdd(&cnt[e & (CBS - 1)], 1);
        col[pos] = e >> CSH;
    }
}

// ---------------------------------------------------------------- bf16 MFMA GEMM
// C[M,N] (bf16) = A[M,Kp] @ Bt[N,Kp]^T (+ bias[n]).  A,Bt bf16 row-major,
// Kp%32==0, N%128==0.  global_load_lds width-16 staging (async direct-to-LDS).
__global__ __launch_bounds__(256)
void gemm_bf16_mfma(const __hip_bfloat16* __restrict__ A,
                    const __hip_bfloat16* __restrict__ Bt,
                    __hip_bfloat16* __restrict__ C,
                    const float* __restrict__ bias, int M, int N, int Kp) {
    __shared__ __hip_bfloat16 As[128 * 32];
    __shared__ __hip_bfloat16 Bs[128 * 32];
    int tid = threadIdx.x;
    int lane = tid & 63;
    int wave = tid >> 6;
    int wm = wave >> 1, wn = wave & 1;
    int quad = lane >> 4, l16 = lane & 15;
    int m0 = blockIdx.y * 128;
    int n0 = blockIdx.x * 128;

    facc acc[4][4] = {};

    for (int k0 = 0; k0 < Kp; k0 += 32) {
#pragma unroll
        for (int p = 0; p < 2; ++p) {
            int idx = p * 256 + tid;          // 0..511 -> 16B chunk id
            int row = idx >> 2;               // 0..127
            int koff = (idx & 3) * 8;         // element offset in 32-elem row
            int gr = m0 + row; if (gr >= M) gr = M - 1;
            // wave-uniform LDS base (elements); lane dest = base + lane*16B
            int lbase = (p * 256 + wave * 64) * 8;
            gload_lds16(A + (size_t)gr * Kp + k0 + koff, As + lbase);
            gload_lds16(Bt + (size_t)(n0 + row) * Kp + k0 + koff, Bs + lbase);
        }
        __syncthreads();   // drains vmcnt (global_load_lds) before ds_read

        frag a[4], b[4];
#pragma unroll
        for (int i = 0; i < 4; ++i) {
            a[i] = *reinterpret_cast<const frag*>(As + (wm * 64 + i * 16 + l16) * 32 + quad * 8);
            b[i] = *reinterpret_cast<const frag*>(Bs + (wn * 64 + i * 16 + l16) * 32 + quad * 8);
        }
#pragma unroll
        for (int i = 0; i < 4; ++i)
#pragma unroll
            for (int j = 0; j < 4; ++j)
                acc[i][j] = __builtin_amdgcn_mfma_f32_16x16x32_bf16(a[i], b[j], acc[i][j], 0, 0, 0);
        __syncthreads();
    }

    // C/D layout: col = lane&15, row = quad*4 + reg
#pragma unroll
    for (int i = 0; i < 4; ++i)
#pragma unroll
        for (int j = 0; j < 4; ++j) {
            int col = n0 + wn * 64 + j * 16 + l16;
            float bv = (bias != nullptr) ? bias[col] : 0.f;
#pragma unroll
            for (int r = 0; r < 4; ++r) {
                int row = m0 + wm * 64 + i * 16 + quad * 4 + r;
                if (row < M) C[(size_t)row * N + col] = __float2bfloat16(acc[i][j][r] + bv);
            }
        }
}

// YL/YR[M,2] fp32 = (A*s+t)[M,K](bf16,BN-folded inline) @ {Wl,Wr}[K,2](fp32)
__global__ void gemm_n22_bn(const __hip_bfloat16* __restrict__ A,
                            const float* __restrict__ Wl, const float* __restrict__ Wr,
                            const float* __restrict__ s, const float* __restrict__ t,
                            float* __restrict__ YL, float* __restrict__ YR, int M, int K) {
    int i = blockIdx.x * blockDim.x + threadIdx.x;
    if (i >= M) return;
    float l0 = 0.f, l1 = 0.f, r0 = 0.f, r1 = 0.f;
    const unsigned* a = (const unsigned*)(A + (size_t)i * K);
    for (int k2 = 0; k2 < K / 2; ++k2) {
        unsigned u = a[k2];
        int k = k2 * 2;
        float v0 = fmaf(bf_lo(u), s[k], t[k]);          // BN applied in f32
        float v1 = fmaf(bf_hi(u), s[k + 1], t[k + 1]);
        l0 = fmaf(v0, Wl[k * 2 + 0], l0);
        l1 = fmaf(v0, Wl[k * 2 + 1], l1);
        l0 = fmaf(v1, Wl[k * 2 + 2], l0);
        l1 = fmaf(v1, Wl[k * 2 + 3], l1);
        r0 = fmaf(v0, Wr[k * 2 + 0], r0);
        r1 = fmaf(v0, Wr[k * 2 + 1], r1);
        r0 = fmaf(v1, Wr[k * 2 + 2], r0);
        r1 = fmaf(v1, Wr[k * 2 + 3], r1);
    }
    YL[(size_t)i * 2 + 0] = l0;
    YL[(size_t)i * 2 + 1] = l1;
    YR[(size_t)i * 2 + 0] = r0;
    YR[(size_t)i * 2 + 1] = r1;
}

// ---------------------------------------------------------------- batched prep
// All static weight transposes + input conversions + EHB pad/z init.
__global__ void prep_all(const float* __restrict__ l1Wl, const float* __restrict__ l1Wr,
                         const float* __restrict__ lhWl,
                         const float* __restrict__ h1Wl, const float* __restrict__ h1Wr,
                         const float* __restrict__ x_low, const float* __restrict__ x_high,
                         const float* __restrict__ lhWr, const float* __restrict__ z_std,
                         __hip_bfloat16* __restrict__ w_l1, __hip_bfloat16* __restrict__ w_lh,
                         __hip_bfloat16* __restrict__ w_h1,
                         __hip_bfloat16* __restrict__ XLOWB, __hip_bfloat16* __restrict__ XRo,
                         __hip_bfloat16* __restrict__ EHB,
                         int o1, int o2, int o3, int o4, int o5, int o6, int o7, int o8) {
    int i = blockIdx.x * blockDim.x + threadIdx.x;
    if (i < o1) {                              // xconv: N_low x 128 (pad 125->128)
        int r = i >> 7, c = i & 127;
        XLOWB[i] = __float2bfloat16((c < 125) ? x_low[(size_t)r * 125 + c] : 0.f);
    } else if (i < o2) {                       // outer_xr: N_high x 128
        int j = i - o1; int r = j >> 7, c = j & 127;
        XRo[j] = __float2bfloat16(x_high[r] * lhWr[c]);
    } else if (i < o3) {                       // EHB cols 128..159: z + zero pad
        int j = i - o2; int r = j >> 5, c = (j & 31) + 128;
        EHB[(size_t)r * 160 + c] = __float2bfloat16((c == 128) ? z_std[r] : 0.f);
    } else if (i < o4) {                       // w_l1 Wl [256][128], K=125
        int j = i - o3; int n = j >> 7, k = j & 127;
        w_l1[j] = __float2bfloat16((k < 125) ? l1Wl[(size_t)k * 256 + n] : 0.f);
    } else if (i < o5) {                       // w_l1 Wr
        int j = i - o4; int n = j >> 7, k = j & 127;
        w_l1[256 * 128 + j] = __float2bfloat16((k < 125) ? l1Wr[(size_t)k * 256 + n] : 0.f);
    } else if (i < o6) {                       // w_lh [128][128], K=128
        int j = i - o5; int n = j >> 7, k = j & 127;
        w_lh[j] = __float2bfloat16(lhWl[(size_t)k * 128 + n]);
    } else if (i < o7) {                       // w_h1 Wl perm [256][160]
        int j = i - o6; int n = j / 160, k = j - n * 160;
        float v = 0.f;
        if (k < 128) v = h1Wl[(size_t)(k + 1) * 256 + n];
        else if (k == 128) v = h1Wl[n];
        w_h1[j] = __float2bfloat16(v);
    } else if (i < o8) {                       // w_h1 Wr perm
        int j = i - o7; int n = j / 160, k = j - n * 160;
        float v = 0.f;
        if (k < 128) v = h1Wr[(size_t)(k + 1) * 256 + n];
        else if (k == 128) v = h1Wr[n];
        w_h1[256 * 160 + j] = __float2bfloat16(v);
    }
}

// BN-folded weight transpose, both Wl and Wr via blockIdx.y:
// Wt[y][n][k] = scale[k]*W[k][n] (bf16), bout[y*N+n] = sum_k shift[k]*W[k][n].
__global__ void wconv_bnfold2(const float* __restrict__ Wl, const float* __restrict__ Wr,
                              const float* __restrict__ scale, const float* __restrict__ shift,
                              __hip_bfloat16* __restrict__ Wt, float* __restrict__ bout,
                              int K, int N, int Kp) {
    __shared__ float red[256];
    const float* W = blockIdx.y ? Wr : Wl;
    __hip_bfloat16* wt = Wt + (size_t)blockIdx.y * N * Kp;
    float* bo = bout + blockIdx.y * N;
    int n = blockIdx.x;
    int tid = threadIdx.x;
    float acc = 0.f;
    for (int k = tid; k < Kp; k += 256) {
        float v = 0.f;
        if (k < K) {
            float w = W[(size_t)k * N + n];
            v = w * scale[k];
            acc = fmaf(w, shift[k], acc);
        }
        wt[(size_t)n * Kp + k] = __float2bfloat16(v);
    }
    red[tid] = acc;
    __syncthreads();
    for (int o = 128; o; o >>= 1) {
        if (tid < o) red[tid] += red[tid + o];
        __syncthreads();
    }
    if (tid == 0) bo[n] = red[0];
}

// ---------------------------------------------------------------- fused GATv2 edge phase v4
// (verbatim best-measured version: 64.6us hot dispatch)
__global__ void gat_c128_v4(const __hip_bfloat16* __restrict__ xl, int xls,
                            const __hip_bfloat16* __restrict__ xr, int xrs,
                            const int* __restrict__ row_off, const int* __restrict__ col,
                            const float* __restrict__ att, const float* __restrict__ bias,
                            __hip_bfloat16* __restrict__ outb, int obstride,
                            int n_dst, int H) {
    int wid = (blockIdx.x * blockDim.x + threadIdx.x) >> 6;
    int lane = threadIdx.x & 63;
    int total = n_dst * H;
    if (wid >= total) return;
    int dst = wid / H;
    int h = wid - dst * H;
    int g = lane >> 4;        // edge slot 0..3
    int q = lane & 15;        // channel block: channels 8q..8q+7
    int cb = h * 128 + q * 8;
    int beg = row_off[dst], end = row_off[dst + 1];

    float xrv[8], av[8];
    unpack8(*(const uint4*)(xr + (size_t)dst * xrs + cb), xrv);
    {
        float4 a0 = *(const float4*)(att + cb);
        float4 a1 = *(const float4*)(att + cb + 4);
        av[0] = a0.x; av[1] = a0.y; av[2] = a0.z; av[3] = a0.w;
        av[4] = a1.x; av[5] = a1.y; av[6] = a1.z; av[7] = a1.w;
    }

    float s = 0.f;
    float acc[8] = {0.f, 0.f, 0.f, 0.f, 0.f, 0.f, 0.f, 0.f};

    if (beg < end) {
        // prologue: chunk0 row data, chunk1 col index
        int e0g = beg + g;
        bool pv = e0g < end;
        int i0 = col[pv ? e0g : beg];
        uint4 u = *(const uint4*)(xl + (size_t)i0 * xls + cb);
        int e1g = beg + 4 + g;
        int i1 = (beg + 4 < end) ? col[(e1g < end) ? e1g : beg] : 0;

        for (int e0 = beg; e0 < end; e0 += 4) {
            bool have_next = (e0 + 4) < end;
            uint4 un;
            if (have_next)
                un = *(const uint4*)(xl + (size_t)i1 * xls + cb);   // issue early
            int e2g = e0 + 8 + g;
            int i2 = (e0 + 8 < end) ? col[(e2g < end) ? e2g : beg] : 0;
            bool nv = (e0 + 4 + g) < end;

            // process current chunk
            float v[8];
            unpack8(u, v);
            float p = 0.f;
#pragma unroll
            for (int c = 0; c < 8; ++c) {
                float z = v[c] + xrv[c];
                z = fmaxf(z, NEG_SLOPE * z);    // leaky-relu, slope<1
                p = fmaf(z, av[c], p);
            }
            p += __shfl_xor(p, 8, 64);
            p += __shfl_xor(p, 4, 64);
            p += __shfl_xor(p, 2, 64);
            p += __shfl_xor(p, 1, 64);
            if (!pv) p = -INFINITY;
            float w = __expf(fminf(p, 85.f));   // 0 for invalid slots
            s += w;
#pragma unroll
            for (int c = 0; c < 8; ++c) acc[c] = fmaf(w, v[c], acc[c]);

            if (have_next) { u = un; pv = nv; }
            i1 = i2;
        }
    }

    // merge the 4 edge-groups (lane^16 / lane^32 hold matching channels)
#pragma unroll
    for (int o = 16; o <= 32; o <<= 1) {
        s += __shfl_xor(s, o, 64);
#pragma unroll
        for (int c = 0; c < 8; ++c) acc[c] += __shfl_xor(acc[c], o, 64);
    }

    int deg = end - beg;
    float inv = (deg > 0) ? 1.f / (s * (float)deg) : 0.f;
    float o8[8];
#pragma unroll
    for (int c = 0; c < 8; ++c) o8[c] = acc[c] * inv;
    if (bias != nullptr) {
#pragma unroll
        for (int c = 0; c < 8; ++c) o8[c] += bias[cb + c];
    }
    if (g == 0) {
        union { uint4 u; __hip_bfloat16 hh[8]; } pk;
#pragma unroll
        for (int c = 0; c < 8; ++c) pk.hh[c] = __float2bfloat16(o8[c]);
        *(uint4*)(outb + (size_t)dst * obstride + cb) = pk.u;
    }
}

// C=2, H=1 final layer: one thread per dst (fp32 xl/xr).
__global__ void gat_c2(const float* __restrict__ xl, const float* __restrict__ xr,
                       const int* __restrict__ row_off, const int* __restrict__ col,
                       const float* __restrict__ att, const float* __restrict__ bias,
                       float* __restrict__ out, int n_dst) {
    int dst = blockIdx.x * blockDim.x + threadIdx.x;
    if (dst >= n_dst) return;
    float x0 = xr[(size_t)dst * 2], x1 = xr[(size_t)dst * 2 + 1];
    float a0 = att[0], a1 = att[1];
    int beg = row_off[dst], end = row_off[dst + 1];
    float s = 0.f, acc0 = 0.f, acc1 = 0.f;
    for (int e = beg; e < end; ++e) {
        int src = col[e];
        float v0 = xl[(size_t)src * 2], v1 = xl[(size_t)src * 2 + 1];
        float z0 = v0 + x0; z0 = fmaxf(z0, NEG_SLOPE * z0);
        float z1 = v1 + x1; z1 = fmaxf(z1, NEG_SLOPE * z1);
        float p = fmaf(z0, a0, z1 * a1);
        float w = __expf(fminf(p, 85.f));
        s += w;
        acc0 = fmaf(w, v0, acc0);
        acc1 = fmaf(w, v1, acc1);
    }
    int deg = end - beg;
    float o0 = 0.f, o1 = 0.f;
    if (deg > 0) {
        float inv = 1.f / (s * (float)deg);
        o0 = acc0 * inv;
        o1 = acc1 * inv;
    }
    out[(size_t)dst * 2 + 0] = o0 + bias[0];
    out[(size_t)dst * 2 + 1] = o1 + bias[1];
}

// ---------------------------------------------------------------- BatchNorm stats (deterministic)
__global__ void bn_partial_d(const __hip_bfloat16* __restrict__ x, float* __restrict__ part,
                             int Nr, int rpb) {
    int C = blockDim.x;
    int c = threadIdx.x;
    int b = blockIdx.x;
    int r0 = b * rpb;
    int r1 = r0 + rpb; if (r1 > Nr) r1 = Nr;
    float s = 0.f, q = 0.f;
    for (int r = r0; r < r1; ++r) {
        float v = __bfloat162float(x[(size_t)r * C + c]);
        s += v;
        q = fmaf(v, v, q);
    }
    part[(size_t)b * C + c] = s;
    part[65536 + (size_t)b * C + c] = q;   // 256*256 slot offset
}

__global__ void bn_finalize_w(const float* __restrict__ part,
                              const float* __restrict__ g, const float* __restrict__ b,
                              float* __restrict__ scale, float* __restrict__ shift,
                              int Nr, int C) {
    int c = (blockIdx.x * blockDim.x + threadIdx.x) >> 6;
    int lane = threadIdx.x & 63;
    if (c >= C) return;
    float s = 0.f, q = 0.f;
    for (int blk = lane; blk < 256; blk += 64) {
        s += part[(size_t)blk * C + c];
        q += part[65536 + (size_t)blk * C + c];
    }
#pragma unroll
    for (int o = 32; o; o >>= 1) {
        s += __shfl_xor(s, o, 64);
        q += __shfl_xor(q, o, 64);
    }
    if (lane == 0) {
        float mu = s / (float)Nr;
        float var = q / (float)Nr - mu * mu;
        float inv = rsqrtf(var + 1e-5f);
        float a = g[c] * inv;
        scale[c] = a;
        shift[c] = b[c] - mu * a;
    }
}

// ---------------------------------------------------------------- driver
extern "C" void kernel_launch(void* const* d_in, const int* in_sizes, int n_in,
                              void* d_out, int out_size, void* d_ws, size_t ws_size,
                              hipStream_t stream) {
    const float* x_low  = (const float*)d_in[0];
    const float* x_high = (const float*)d_in[1];
    const float* z_std  = (const float*)d_in[2];
    const int* e_low  = (const int*)d_in[3];
    const int* e_l2h  = (const int*)d_in[4];
    const int* e_high = (const int*)d_in[5];
    const float* l1_Wl = (const float*)d_in[6];
    const float* l1_Wr = (const float*)d_in[7];
    const float* l1_att = (const float*)d_in[8];
    const float* l1_b  = (const float*)d_in[9];
    const float* bn1_g = (const float*)d_in[10];
    const float* bn1_b = (const float*)d_in[11];
    const float* l2_Wl = (const float*)d_in[12];
    const float* l2_Wr = (const float*)d_in[13];
    const float* l2_att = (const float*)d_in[14];
    const float* l2_b  = (const float*)d_in[15];
    const float* bn2_g = (const float*)d_in[16];
    const float* bn2_b = (const float*)d_in[17];
    const float* l3_Wl = (const float*)d_in[18];
    const float* l3_Wr = (const float*)d_in[19];
    const float* l3_att = (const float*)d_in[20];
    const float* l3_b  = (const float*)d_in[21];
    const float* lh_Wl = (const float*)d_in[22];
    const float* lh_Wr = (const float*)d_in[23];
    const float* lh_att = (const float*)d_in[24];
    const float* h1_Wl = (const float*)d_in[25];
    const float* h1_Wr = (const float*)d_in[26];
    const float* h1_att = (const float*)d_in[27];
    const float* h1_b  = (const float*)d_in[28];
    const float* bn3_g = (const float*)d_in[29];
    const float* bn3_b = (const float*)d_in[30];
    const float* h2_Wl = (const float*)d_in[31];
    const float* h2_Wr = (const float*)d_in[32];
    const float* h2_att = (const float*)d_in[33];
    const float* h2_b  = (const float*)d_in[34];
    const float* bn4_g = (const float*)d_in[35];
    const float* bn4_b = (const float*)d_in[36];
    const float* h3_Wl = (const float*)d_in[37];
    const float* h3_Wr = (const float*)d_in[38];
    const float* h3_att = (const float*)d_in[39];
    const float* h3_b  = (const float*)d_in[40];

    const int N_low = in_sizes[0] / 125;
    const int N_high = in_sizes[1];
    const int E_low = in_sizes[3] / 2;
    const int E_l2h = in_sizes[4] / 2;
    const int E_high = in_sizes[5] / 2;

    char* ws = (char*)d_ws;
    size_t woff = 0;
    auto walloc = [&](size_t bytes) -> void* {
        void* p = (void*)(ws + woff);
        woff += (bytes + 255) & ~(size_t)255;
        return p;
    };
    // XLR holds merged [XL|XR] GEMM outputs (max N_high x 512 bf16 = 61 MB).
    // Before the first GEMM it is dead -> the CSR stage array aliases it.
    __hip_bfloat16* XLR = (__hip_bfloat16*)walloc((size_t)N_high * 512 * 2);
    __hip_bfloat16* A1  = (__hip_bfloat16*)walloc((size_t)N_high * 256 * 2);
    __hip_bfloat16* A2  = (__hip_bfloat16*)walloc((size_t)N_high * 128 * 2);
    __hip_bfloat16* XRo = (__hip_bfloat16*)walloc((size_t)N_high * 128 * 2); // lh outer xr
    __hip_bfloat16* XLOWB = (__hip_bfloat16*)walloc((size_t)N_low * 128 * 2);
    __hip_bfloat16* EHB = (__hip_bfloat16*)walloc((size_t)N_high * 160 * 2);
    float* YL = (float*)walloc((size_t)N_high * 2 * 4);
    float* YR = (float*)walloc((size_t)N_high * 2 * 4);
    int* off_low  = (int*)walloc((size_t)(N_low + 1) * 4);
    int* col_low  = (int*)walloc((size_t)E_low * 4);
    int* off_l2h  = (int*)walloc((size_t)(N_high + 1) * 4);
    int* col_l2h  = (int*)walloc((size_t)E_l2h * 4);
    int* off_high = (int*)walloc((size_t)(N_high + 1) * 4);
    int* col_high = (int*)walloc((size_t)E_high * 4);
    // multisplit CSR state
    const int nc0 = (N_low + CBS - 1) >> CSH;
    const int nc1 = (N_high + CBS - 1) >> CSH;
    const int nc2 = (N_high + CBS - 1) >> CSH;
    const int NBC = nc0 + nc1 + nc2;
    const long Etot = (long)E_low + E_l2h + E_high;
    const long chunk = (Etot + PB - 1) / PB;
    auto capf = [&](int ng) {
        double m = (double)chunk * CBS / ng;
        int c = (int)(m + 8.0 * sqrt(m) + 16.0);
        return (c + 15) & ~15;
    };
    const int cap0 = capf(N_low);
    const int cap1 = capf(N_high);
    const int cap2 = capf(N_high);
    int* cnt2   = (int*)walloc((size_t)PB * NBC * 4);
    int* cstart = (int*)walloc((size_t)(NBC + 1) * 4);
    float* bnpart = (float*)walloc(2 * 256 * 256 * 4);   // deterministic BN partials
    float* bnsc   = (float*)walloc(512 * 4);             // scale | shift
    float* bb     = (float*)walloc(512 * 4);             // folded gemm bias
    // merged [Wl|Wr] bf16 transposed weights [Ncat][Kp]
    __hip_bfloat16* w_l1 = (__hip_bfloat16*)walloc(512 * 128 * 2);
    __hip_bfloat16* w_l2 = (__hip_bfloat16*)walloc(256 * 256 * 2);
    __hip_bfloat16* w_l3 = (__hip_bfloat16*)walloc(256 * 128 * 2);
    __hip_bfloat16* w_lh = (__hip_bfloat16*)walloc(128 * 128 * 2);
    __hip_bfloat16* w_h1 = (__hip_bfloat16*)walloc(512 * 160 * 2);
    __hip_bfloat16* w_h2 = (__hip_bfloat16*)walloc(256 * 256 * 2);

    int* stage = (int*)XLR;   // ~32 MB needed, 61 MB available; dead until first gemm

    // ---- batched prep: all static converts + EHB pad/z init in ONE launch
    {
        int o1 = N_low * 128;              // xconv
        int o2 = o1 + N_high * 128;        // outer_xr
        int o3 = o2 + N_high * 32;         // EHB cols 128..159
        int o4 = o3 + 256 * 128;           // w_l1 Wl
        int o5 = o4 + 256 * 128;           // w_l1 Wr
        int o6 = o5 + 128 * 128;           // w_lh
        int o7 = o6 + 256 * 160;           // w_h1 Wl
        int o8 = o7 + 256 * 160;           // w_h1 Wr
        prep_all<<<(o8 + 255) / 256, 256, 0, stream>>>(
            l1_Wl, l1_Wr, lh_Wl, h1_Wl, h1_Wr, x_low, x_high, lh_Wr, z_std,
            w_l1, w_lh, w_h1, XLOWB, XRo, EHB,
            o1, o2, o3, o4, o5, o6, o7, o8);
    }

    // ---- multisplit CSR build for all 3 graphs (3 launches, no global atomics)
    msplitA<<<PB, 256, 0, stream>>>(
        e_low, e_low + E_low, E_low,
        e_l2h, e_l2h + E_l2h, E_l2h,
        e_high, e_high + E_high, E_high,
        nc0, nc1, nc2, cap0, cap1, cap2, stage, cnt2);
    scanC<<<1, 256, 0, stream>>>(cnt2, cstart, NBC, nc0, nc1);
    fineB<<<NBC, 1024, 0, stream>>>(cnt2, cstart, stage,
                                    nc0, nc1, nc2, cap0, cap1, cap2,
                                    off_low, col_low, N_low,
                                    off_l2h, col_l2h, N_high,
                                    off_high, col_high, N_high);

    auto gemm = [&](const __hip_bfloat16* A, const __hip_bfloat16* Bt, __hip_bfloat16* C,
                    int M, int N, int Kp, const float* bias) {
        dim3 g(N / 128, (M + 127) / 128);
        gemm_bf16_mfma<<<g, 256, 0, stream>>>(A, Bt, C, bias, M, N, Kp);
    };
    auto gat = [&](const __hip_bfloat16* xl, int xls, const __hip_bfloat16* xr, int xrs,
                   const int* roff, const int* colv,
                   const float* att, const float* bias,
                   __hip_bfloat16* outb, int obs, int n_dst, int H) {
        long thr = (long)n_dst * H * 64;
        gat_c128_v4<<<(unsigned)((thr + 255) / 256), 256, 0, stream>>>(
            xl, xls, xr, xrs, roff, colv, att, bias, outb, obs, n_dst, H);
    };
    // deterministic BN stats only (apply is folded into the consumer GEMM weights)
    auto bn_stats = [&](__hip_bfloat16* x, const float* g, const float* b, int Nr, int C) {
        int rpb = (Nr + 255) / 256;
        bn_partial_d<<<256, C, 0, stream>>>(x, bnpart, Nr, rpb);
        bn_finalize_w<<<(C * 64 + 255) / 256, 256, 0, stream>>>(bnpart, g, b, bnsc, bnsc + 256, Nr, C);
    };
    // fold bn (bnsc) into a merged [Wl|Wr] weight + bias pair (one launch)
    auto fold2 = [&](const float* Wl, const float* Wr, __hip_bfloat16* Wt,
                     int K, int Nn, int Kp) {
        dim3 g(Nn, 2);
        wconv_bnfold2<<<g, 256, 0, stream>>>(Wl, Wr, bnsc, bnsc + 256, Wt, bb, K, Nn, Kp);
    };

    // ---- low_net layer 1: 125 -> (H=2) 256   (merged [XL|XR], stride 512)
    gemm(XLOWB, w_l1, XLR, N_low, 512, 128, nullptr);
    gat(XLR, 512, XLR + 256, 512, off_low, col_low, l1_att, l1_b, A1, 256, N_low, 2);
    bn_stats(A1, bn1_g, bn1_b, N_low, 256);

    // ---- low_net layer 2: 256 -> 128 (BN1 folded into w_l2 + bias)
    fold2(l2_Wl, l2_Wr, w_l2, 256, 128, 256);
    gemm(A1, w_l2, XLR, N_low, 256, 256, bb);
    gat(XLR, 256, XLR + 128, 256, off_low, col_low, l2_att, l2_b, A2, 128, N_low, 1);
    bn_stats(A2, bn2_g, bn2_b, N_low, 128);

    // ---- low_net layer 3: 128 -> 128 (BN2 folded into w_l3 + bias)
    fold2(l3_Wl, l3_Wr, w_l3, 128, 128, 128);
    gemm(A2, w_l3, XLR, N_low, 256, 128, bb);
    gat(XLR, 256, XLR + 128, 256, off_low, col_low, l3_att, l3_b, A1, 128, N_low, 1);

    // ---- bipartite low2high -> EHB[N_high][160] = [gat 0..127 | z | pad] (pad/z pre-inited)
    gemm(A1, w_lh, XLR, N_low, 128, 128, nullptr);   // xl only, stride 128
    gat(XLR, 128, XRo, 128, off_l2h, col_l2h, lh_att, nullptr, EHB, 160, N_high, 1);

    // ---- high_net layer 1: 129(perm,pad160) -> (H=2) 256   (merged, stride 512)
    gemm(EHB, w_h1, XLR, N_high, 512, 160, nullptr);
    gat(XLR, 512, XLR + 256, 512, off_high, col_high, h1_att, h1_b, A1, 256, N_high, 2);
    bn_stats(A1, bn3_g, bn3_b, N_high, 256);

    // ---- high_net layer 2: 256 -> 128 (BN3 folded into w_h2 + bias)
    fold2(h2_Wl, h2_Wr, w_h2, 256, 128, 256);
    gemm(A1, w_h2, XLR, N_high, 256, 256, bb);
    gat(XLR, 256, XLR + 128, 256, off_high, col_high, h2_att, h2_b, A2, 128, N_high, 1);
    bn_stats(A2, bn4_g, bn4_b, N_high, 128);

    // ---- high_net layer 3: 128 -> 2 (BN4 applied inline in f32; one pass over A2)
    gemm_n22_bn<<<(N_high + 255) / 256, 256, 0, stream>>>(A2, h3_Wl, h3_Wr,
                                                          bnsc, bnsc + 256, YL, YR, N_high, 128);
    gat_c2<<<(N_high + 255) / 256, 256, 0, stream>>>(YL, YR, off_high, col_high,
                                                     h3_att, h3_b, (float*)d_out, N_high);
}

// Round 7
// 750.764 us; speedup vs baseline: 1.2140x; 1.0217x over previous
//
#include <hip/hip_runtime.h>
#include <hip/hip_bf16.h>
#include <cstdint>
#include <cstddef>
#include <cmath>

#define NEG_SLOPE 0.2f

// two-level multisplit CSR build params
#define PB  1024                 // pass-1 blocks (4 blocks/CU resident -> barriers overlap)
#define CSH 10                   // 1024 dsts per coarse bucket
#define CBS 1024
#define NBCMAX 160

using frag = __attribute__((ext_vector_type(8))) short;   // 8 bf16 = 4 VGPRs
using facc = __attribute__((ext_vector_type(4))) float;   // 4 fp32 accum

__device__ __forceinline__ float bf_hi(unsigned u) {
    union { unsigned i; float f; } t; t.i = u & 0xffff0000u; return t.f;
}
__device__ __forceinline__ float bf_lo(unsigned u) {
    union { unsigned i; float f; } t; t.i = u << 16; return t.f;
}
__device__ __forceinline__ void unpack8(uint4 u, float* v) {
    v[0] = bf_lo(u.x); v[1] = bf_hi(u.x);
    v[2] = bf_lo(u.y); v[3] = bf_hi(u.y);
    v[4] = bf_lo(u.z); v[5] = bf_hi(u.z);
    v[6] = bf_lo(u.w); v[7] = bf_hi(u.w);
}

// async global->LDS, 16B per lane (wave-uniform LDS base + lane*16)
typedef const __attribute__((address_space(1))) void* gas_cptr;
typedef __attribute__((address_space(3))) void* las_ptr;
__device__ __forceinline__ void gload_lds16(const __hip_bfloat16* g, __hip_bfloat16* l) {
    __builtin_amdgcn_global_load_lds((gas_cptr)(const void*)g, (las_ptr)(void*)l, 16, 0, 0);
}

// ---------------------------------------------------------------- multisplit CSR build
// Pass 1: block-private coarse multisplit. Each block reorders its chunk in LDS
// per round and appends per-bucket runs to PRIVATE regions -> every 64B line has
// a single writer (one XCD). No global atomics. PB=1024 -> full-machine occupancy
// (R6's PB=256 was 1 block/CU = 12.5% occupancy, barrier latency exposed).
__global__ __launch_bounds__(256)
void msplitA(const int* __restrict__ s0, const int* __restrict__ d0, int E0,
             const int* __restrict__ s1, const int* __restrict__ d1, int E1,
             const int* __restrict__ s2, const int* __restrict__ d2, int E2,
             int nc0, int nc1, int nc2, int cap0, int cap1, int cap2,
             int* __restrict__ stage, int* __restrict__ cnt2) {
    __shared__ int hist[NBCMAX];
    __shared__ int rbase[NBCMAX];
    __shared__ int curs[NBCMAX];
    __shared__ int ord[1024];
    __shared__ int obkt[1024];
    const int NBC = nc0 + nc1 + nc2;
    const long Etot = (long)E0 + E1 + E2;
    int tid = threadIdx.x;
    int lane = tid & 63;
    long chunk = (Etot + PB - 1) / PB;
    long c0 = (long)blockIdx.x * chunk;
    long c1 = c0 + chunk; if (c1 > Etot) c1 = Etot;
    const long sec1 = (long)PB * nc0 * cap0;
    const long sec2 = sec1 + (long)PB * nc1 * cap1;
    for (int t = tid; t < NBC; t += 256) curs[t] = 0;
    __syncthreads();
    for (long r0 = c0; r0 < c1; r0 += 1024) {
        int n = (int)((c1 - r0 < 1024) ? (c1 - r0) : 1024);
        for (int t = tid; t < NBC; t += 256) hist[t] = 0;
        __syncthreads();
        int mye[4], myb[4], myr[4];
#pragma unroll
        for (int k = 0; k < 4; ++k) {
            int li = k * 256 + tid;
            myb[k] = -1;
            if (li < n) {
                long i = r0 + li;
                int src, dst, gb;
                if (i < E0) { src = s0[i]; dst = d0[i]; gb = dst >> CSH; }
                else if (i < (long)E0 + E1) { long j = i - E0; src = s1[j]; dst = d1[j]; gb = nc0 + (dst >> CSH); }
                else { long j = i - E0 - E1; src = s2[j]; dst = d2[j]; gb = nc0 + nc1 + (dst >> CSH); }
                mye[k] = (src << CSH) | (dst & (CBS - 1));
                myb[k] = gb;
                myr[k] = atomicAdd(&hist[gb], 1);
            }
        }
        __syncthreads();
        // exclusive scan of hist (NBC<=160) by wave 0
        if (tid < 64) {
            int carry = 0;
            for (int base = 0; base < NBC; base += 64) {
                int g = base + lane;
                int v = (g < NBC) ? hist[g] : 0;
                int sum = v;
#pragma unroll
                for (int o = 1; o < 64; o <<= 1) {
                    int t = __shfl_up(sum, o, 64);
                    if (lane >= o) sum += t;
                }
                if (g < NBC) rbase[g] = carry + sum - v;
                carry += __shfl(sum, 63, 64);
            }
        }
        __syncthreads();
#pragma unroll
        for (int k = 0; k < 4; ++k)
            if (myb[k] >= 0) {
                int pos = rbase[myb[k]] + myr[k];
                ord[pos] = mye[k];
                obkt[pos] = myb[k];
            }
        __syncthreads();
        // append runs to block-private regions (consecutive lanes -> consecutive addrs)
        for (int pos = tid; pos < n; pos += 256) {
            int b = obkt[pos];
            int rank = pos - rbase[b] + curs[b];
            long addr; int cap;
            if (b < nc0)            { cap = cap0; addr = (long)(blockIdx.x * nc0 + b) * cap0; }
            else if (b < nc0 + nc1) { cap = cap1; addr = sec1 + (long)(blockIdx.x * nc1 + (b - nc0)) * cap1; }
            else                    { cap = cap2; addr = sec2 + (long)(blockIdx.x * nc2 + (b - nc0 - nc1)) * cap2; }
            if (rank < cap) stage[addr + rank] = ord[pos];
        }
        __syncthreads();
        for (int t = tid; t < NBC; t += 256) curs[t] += hist[t];
        __syncthreads();
    }
    for (int t = tid; t < NBC; t += 256) {
        int cap = (t < nc0) ? cap0 : (t < nc0 + nc1) ? cap1 : cap2;
        int c = curs[t]; if (c > cap) c = cap;
        cnt2[(long)blockIdx.x * NBC + t] = c;
    }
}

// per-coarse-bucket total (one block per bucket; replaces single-CU reduction)
__global__ void scanC1(const int* __restrict__ cnt2, int* __restrict__ tot, int NBC) {
    __shared__ int red[256];
    int gb = blockIdx.x;
    int tid = threadIdx.x;
    int s = 0;
    for (int p = tid; p < PB; p += 256) s += cnt2[(long)p * NBC + gb];
    red[tid] = s;
    __syncthreads();
    for (int o = 128; o; o >>= 1) {
        if (tid < o) red[tid] += red[tid + o];
        __syncthreads();
    }
    if (tid == 0) tot[gb] = red[0];
}

// serial exclusive scan of ~138 totals with per-graph reset (trivial)
__global__ void scanC2(const int* __restrict__ tot, int* __restrict__ cstart,
                       int NBC, int nc0, int nc1) {
    if (threadIdx.x == 0) {
        int c = 0;
        for (int gb = 0; gb < NBC; ++gb) {
            if (gb == nc0 || gb == nc0 + nc1) c = 0;
            cstart[gb] = c;
            c += tot[gb];
        }
    }
}

// Pass 2: one block per coarse bucket. Scan the PB fragment counts, map flat
// positions -> fragments via binary search, LDS-count the 1024 dsts, block-scan,
// write off[], scatter col within a ~64KB window (LDS cursors only).
__global__ __launch_bounds__(1024)
void fineB(const int* __restrict__ cnt2, const int* __restrict__ cstart,
           const int* __restrict__ stage,
           int nc0, int nc1, int nc2, int cap0, int cap1, int cap2,
           int* __restrict__ off0, int* __restrict__ col0, int n0,
           int* __restrict__ off1, int* __restrict__ col1, int n1,
           int* __restrict__ off2, int* __restrict__ col2, int n2) {
    __shared__ int fragb[PB + 1];
    __shared__ int cnt[1024];
    __shared__ int wsum[17];
    const int NBC = nc0 + nc1 + nc2;
    int gb = blockIdx.x;
    int tid = threadIdx.x;
    int lane = tid & 63;
    int wv = tid >> 6;
    int cb, ncg, n; long base2, stride; int* off; int* col;
    const long sec1 = (long)PB * nc0 * cap0;
    const long sec2 = sec1 + (long)PB * nc1 * cap1;
    if (gb < nc0) {
        cb = gb; ncg = nc0; n = n0; off = off0; col = col0;
        base2 = (long)cb * cap0; stride = (long)nc0 * cap0;
    } else if (gb < nc0 + nc1) {
        cb = gb - nc0; ncg = nc1; n = n1; off = off1; col = col1;
        base2 = sec1 + (long)cb * cap1; stride = (long)nc1 * cap1;
    } else {
        cb = gb - nc0 - nc1; ncg = nc2; n = n2; off = off2; col = col2;
        base2 = sec2 + (long)cb * cap2; stride = (long)nc2 * cap2;
    }
    int dlo = cb << CSH;
    int colbase = cstart[gb];
    // ---- exclusive scan of the PB(=1024) fragment counts
    int v = cnt2[(long)tid * NBC + gb];
    int sum = v;
#pragma unroll
    for (int o = 1; o < 64; o <<= 1) {
        int t = __shfl_up(sum, o, 64);
        if (lane >= o) sum += t;
    }
    if (lane == 63) wsum[wv] = sum;
    __syncthreads();
    if (tid == 0) {
        int c = 0;
        for (int w = 0; w < 16; ++w) { int t = wsum[w]; wsum[w] = c; c += t; }
        wsum[16] = c;
    }
    __syncthreads();
    fragb[tid] = wsum[wv] + sum - v;
    if (tid == 0) fragb[PB] = wsum[16];
    __syncthreads();
    int sz = fragb[PB];
    // ---- per-dst counts
    cnt[tid] = 0;
    __syncthreads();
    for (int p = tid; p < sz; p += 1024) {
        int lo = 0, hi = PB;
        while (hi - lo > 1) { int mid = (lo + hi) >> 1; if (fragb[mid] <= p) lo = mid; else hi = mid; }
        int e = stage[base2 + (long)lo * stride + (p - fragb[lo])];
        atomicAdd(&cnt[e & (CBS - 1)], 1);
    }
    __syncthreads();
    // ---- exclusive scan of cnt[1024]
    int cv = cnt[tid];
    int csum = cv;
#pragma unroll
    for (int o = 1; o < 64; o <<= 1) {
        int t = __shfl_up(csum, o, 64);
        if (lane >= o) csum += t;
    }
    if (lane == 63) wsum[wv] = csum;
    __syncthreads();
    if (tid == 0) {
        int c = 0;
        for (int w = 0; w < 16; ++w) { int t = wsum[w]; wsum[w] = c; c += t; }
    }
    __syncthreads();
    int excl = wsum[wv] + csum - cv;
    int d = dlo + tid;
    if (d < n) off[d] = colbase + excl;
    if (cb == ncg - 1 && tid == 0) off[n] = colbase + sz;
    __syncthreads();
    cnt[tid] = colbase + excl;      // cursors
    __syncthreads();
    // ---- scatter col
    for (int p = tid; p < sz; p += 1024) {
        int lo = 0, hi = PB;
        while (hi - lo > 1) { int mid = (lo + hi) >> 1; if (fragb[mid] <= p) lo = mid; else hi = mid; }
        int e = stage[base2 + (long)lo * stride + (p - fragb[lo])];
        int pos = atomicAdd(&cnt[e & (CBS - 1)], 1);
        col[pos] = e >> CSH;
    }
}

// ---------------------------------------------------------------- bf16 MFMA GEMM
// C[M,N] (bf16) = A[M,Kp] @ Bt[N,Kp]^T (+ bias[n]).  A,Bt bf16 row-major,
// Kp%32==0, N%128==0.  global_load_lds width-16 staging (async direct-to-LDS).
__global__ __launch_bounds__(256)
void gemm_bf16_mfma(const __hip_bfloat16* __restrict__ A,
                    const __hip_bfloat16* __restrict__ Bt,
                    __hip_bfloat16* __restrict__ C,
                    const float* __restrict__ bias, int M, int N, int Kp) {
    __shared__ __hip_bfloat16 As[128 * 32];
    __shared__ __hip_bfloat16 Bs[128 * 32];
    int tid = threadIdx.x;
    int lane = tid & 63;
    int wave = tid >> 6;
    int wm = wave >> 1, wn = wave & 1;
    int quad = lane >> 4, l16 = lane & 15;
    int m0 = blockIdx.y * 128;
    int n0 = blockIdx.x * 128;

    facc acc[4][4] = {};

    for (int k0 = 0; k0 < Kp; k0 += 32) {
#pragma unroll
        for (int p = 0; p < 2; ++p) {
            int idx = p * 256 + tid;          // 0..511 -> 16B chunk id
            int row = idx >> 2;               // 0..127
            int koff = (idx & 3) * 8;         // element offset in 32-elem row
            int gr = m0 + row; if (gr >= M) gr = M - 1;
            // wave-uniform LDS base (elements); lane dest = base + lane*16B
            int lbase = (p * 256 + wave * 64) * 8;
            gload_lds16(A + (size_t)gr * Kp + k0 + koff, As + lbase);
            gload_lds16(Bt + (size_t)(n0 + row) * Kp + k0 + koff, Bs + lbase);
        }
        __syncthreads();   // drains vmcnt (global_load_lds) before ds_read

        frag a[4], b[4];
#pragma unroll
        for (int i = 0; i < 4; ++i) {
            a[i] = *reinterpret_cast<const frag*>(As + (wm * 64 + i * 16 + l16) * 32 + quad * 8);
            b[i] = *reinterpret_cast<const frag*>(Bs + (wn * 64 + i * 16 + l16) * 32 + quad * 8);
        }
#pragma unroll
        for (int i = 0; i < 4; ++i)
#pragma unroll
            for (int j = 0; j < 4; ++j)
                acc[i][j] = __builtin_amdgcn_mfma_f32_16x16x32_bf16(a[i], b[j], acc[i][j], 0, 0, 0);
        __syncthreads();
    }

    // C/D layout: col = lane&15, row = quad*4 + reg
#pragma unroll
    for (int i = 0; i < 4; ++i)
#pragma unroll
        for (int j = 0; j < 4; ++j) {
            int col = n0 + wn * 64 + j * 16 + l16;
            float bv = (bias != nullptr) ? bias[col] : 0.f;
#pragma unroll
            for (int r = 0; r < 4; ++r) {
                int row = m0 + wm * 64 + i * 16 + quad * 4 + r;
                if (row < M) C[(size_t)row * N + col] = __float2bfloat16(acc[i][j][r] + bv);
            }
        }
}

// YL/YR[M,2] fp32 = (A*s+t)[M,K](bf16,BN-folded inline) @ {Wl,Wr}[K,2](fp32)
__global__ void gemm_n22_bn(const __hip_bfloat16* __restrict__ A,
                            const float* __restrict__ Wl, const float* __restrict__ Wr,
                            const float* __restrict__ s, const float* __restrict__ t,
                            float* __restrict__ YL, float* __restrict__ YR, int M, int K) {
    int i = blockIdx.x * blockDim.x + threadIdx.x;
    if (i >= M) return;
    float l0 = 0.f, l1 = 0.f, r0 = 0.f, r1 = 0.f;
    const unsigned* a = (const unsigned*)(A + (size_t)i * K);
    for (int k2 = 0; k2 < K / 2; ++k2) {
        unsigned u = a[k2];
        int k = k2 * 2;
        float v0 = fmaf(bf_lo(u), s[k], t[k]);          // BN applied in f32
        float v1 = fmaf(bf_hi(u), s[k + 1], t[k + 1]);
        l0 = fmaf(v0, Wl[k * 2 + 0], l0);
        l1 = fmaf(v0, Wl[k * 2 + 1], l1);
        l0 = fmaf(v1, Wl[k * 2 + 2], l0);
        l1 = fmaf(v1, Wl[k * 2 + 3], l1);
        r0 = fmaf(v0, Wr[k * 2 + 0], r0);
        r1 = fmaf(v0, Wr[k * 2 + 1], r1);
        r0 = fmaf(v1, Wr[k * 2 + 2], r0);
        r1 = fmaf(v1, Wr[k * 2 + 3], r1);
    }
    YL[(size_t)i * 2 + 0] = l0;
    YL[(size_t)i * 2 + 1] = l1;
    YR[(size_t)i * 2 + 0] = r0;
    YR[(size_t)i * 2 + 1] = r1;
}

// ---------------------------------------------------------------- batched prep
// All static weight transposes + input conversions + EHB pad/z init.
__global__ void prep_all(const float* __restrict__ l1Wl, const float* __restrict__ l1Wr,
                         const float* __restrict__ lhWl,
                         const float* __restrict__ h1Wl, const float* __restrict__ h1Wr,
                         const float* __restrict__ x_low, const float* __restrict__ x_high,
                         const float* __restrict__ lhWr, const float* __restrict__ z_std,
                         __hip_bfloat16* __restrict__ w_l1, __hip_bfloat16* __restrict__ w_lh,
                         __hip_bfloat16* __restrict__ w_h1,
                         __hip_bfloat16* __restrict__ XLOWB, __hip_bfloat16* __restrict__ XRo,
                         __hip_bfloat16* __restrict__ EHB,
                         int o1, int o2, int o3, int o4, int o5, int o6, int o7, int o8) {
    int i = blockIdx.x * blockDim.x + threadIdx.x;
    if (i < o1) {                              // xconv: N_low x 128 (pad 125->128)
        int r = i >> 7, c = i & 127;
        XLOWB[i] = __float2bfloat16((c < 125) ? x_low[(size_t)r * 125 + c] : 0.f);
    } else if (i < o2) {                       // outer_xr: N_high x 128
        int j = i - o1; int r = j >> 7, c = j & 127;
        XRo[j] = __float2bfloat16(x_high[r] * lhWr[c]);
    } else if (i < o3) {                       // EHB cols 128..159: z + zero pad
        int j = i - o2; int r = j >> 5, c = (j & 31) + 128;
        EHB[(size_t)r * 160 + c] = __float2bfloat16((c == 128) ? z_std[r] : 0.f);
    } else if (i < o4) {                       // w_l1 Wl [256][128], K=125
        int j = i - o3; int n = j >> 7, k = j & 127;
        w_l1[j] = __float2bfloat16((k < 125) ? l1Wl[(size_t)k * 256 + n] : 0.f);
    } else if (i < o5) {                       // w_l1 Wr
        int j = i - o4; int n = j >> 7, k = j & 127;
        w_l1[256 * 128 + j] = __float2bfloat16((k < 125) ? l1Wr[(size_t)k * 256 + n] : 0.f);
    } else if (i < o6) {                       // w_lh [128][128], K=128
        int j = i - o5; int n = j >> 7, k = j & 127;
        w_lh[j] = __float2bfloat16(lhWl[(size_t)k * 128 + n]);
    } else if (i < o7) {                       // w_h1 Wl perm [256][160]
        int j = i - o6; int n = j / 160, k = j - n * 160;
        float v = 0.f;
        if (k < 128) v = h1Wl[(size_t)(k + 1) * 256 + n];
        else if (k == 128) v = h1Wl[n];
        w_h1[j] = __float2bfloat16(v);
    } else if (i < o8) {                       // w_h1 Wr perm
        int j = i - o7; int n = j / 160, k = j - n * 160;
        float v = 0.f;
        if (k < 128) v = h1Wr[(size_t)(k + 1) * 256 + n];
        else if (k == 128) v = h1Wr[n];
        w_h1[256 * 160 + j] = __float2bfloat16(v);
    }
}

// BN-folded weight transpose, both Wl and Wr via blockIdx.y:
// Wt[y][n][k] = scale[k]*W[k][n] (bf16), bout[y*N+n] = sum_k shift[k]*W[k][n].
__global__ void wconv_bnfold2(const float* __restrict__ Wl, const float* __restrict__ Wr,
                              const float* __restrict__ scale, const float* __restrict__ shift,
                              __hip_bfloat16* __restrict__ Wt, float* __restrict__ bout,
                              int K, int N, int Kp) {
    __shared__ float red[256];
    const float* W = blockIdx.y ? Wr : Wl;
    __hip_bfloat16* wt = Wt + (size_t)blockIdx.y * N * Kp;
    float* bo = bout + blockIdx.y * N;
    int n = blockIdx.x;
    int tid = threadIdx.x;
    float acc = 0.f;
    for (int k = tid; k < Kp; k += 256) {
        float v = 0.f;
        if (k < K) {
            float w = W[(size_t)k * N + n];
            v = w * scale[k];
            acc = fmaf(w, shift[k], acc);
        }
        wt[(size_t)n * Kp + k] = __float2bfloat16(v);
    }
    red[tid] = acc;
    __syncthreads();
    for (int o = 128; o; o >>= 1) {
        if (tid < o) red[tid] += red[tid + o];
        __syncthreads();
    }
    if (tid == 0) bo[n] = red[0];
}

// ---------------------------------------------------------------- fused GATv2 edge phase v4
// (verbatim best-measured version: 64.6us hot dispatch)
__global__ void gat_c128_v4(const __hip_bfloat16* __restrict__ xl, int xls,
                            const __hip_bfloat16* __restrict__ xr, int xrs,
                            const int* __restrict__ row_off, const int* __restrict__ col,
                            const float* __restrict__ att, const float* __restrict__ bias,
                            __hip_bfloat16* __restrict__ outb, int obstride,
                            int n_dst, int H) {
    int wid = (blockIdx.x * blockDim.x + threadIdx.x) >> 6;
    int lane = threadIdx.x & 63;
    int total = n_dst * H;
    if (wid >= total) return;
    int dst = wid / H;
    int h = wid - dst * H;
    int g = lane >> 4;        // edge slot 0..3
    int q = lane & 15;        // channel block: channels 8q..8q+7
    int cb = h * 128 + q * 8;
    int beg = row_off[dst], end = row_off[dst + 1];

    float xrv[8], av[8];
    unpack8(*(const uint4*)(xr + (size_t)dst * xrs + cb), xrv);
    {
        float4 a0 = *(const float4*)(att + cb);
        float4 a1 = *(const float4*)(att + cb + 4);
        av[0] = a0.x; av[1] = a0.y; av[2] = a0.z; av[3] = a0.w;
        av[4] = a1.x; av[5] = a1.y; av[6] = a1.z; av[7] = a1.w;
    }

    float s = 0.f;
    float acc[8] = {0.f, 0.f, 0.f, 0.f, 0.f, 0.f, 0.f, 0.f};

    if (beg < end) {
        // prologue: chunk0 row data, chunk1 col index
        int e0g = beg + g;
        bool pv = e0g < end;
        int i0 = col[pv ? e0g : beg];
        uint4 u = *(const uint4*)(xl + (size_t)i0 * xls + cb);
        int e1g = beg + 4 + g;
        int i1 = (beg + 4 < end) ? col[(e1g < end) ? e1g : beg] : 0;

        for (int e0 = beg; e0 < end; e0 += 4) {
            bool have_next = (e0 + 4) < end;
            uint4 un;
            if (have_next)
                un = *(const uint4*)(xl + (size_t)i1 * xls + cb);   // issue early
            int e2g = e0 + 8 + g;
            int i2 = (e0 + 8 < end) ? col[(e2g < end) ? e2g : beg] : 0;
            bool nv = (e0 + 4 + g) < end;

            // process current chunk
            float v[8];
            unpack8(u, v);
            float p = 0.f;
#pragma unroll
            for (int c = 0; c < 8; ++c) {
                float z = v[c] + xrv[c];
                z = fmaxf(z, NEG_SLOPE * z);    // leaky-relu, slope<1
                p = fmaf(z, av[c], p);
            }
            p += __shfl_xor(p, 8, 64);
            p += __shfl_xor(p, 4, 64);
            p += __shfl_xor(p, 2, 64);
            p += __shfl_xor(p, 1, 64);
            if (!pv) p = -INFINITY;
            float w = __expf(fminf(p, 85.f));   // 0 for invalid slots
            s += w;
#pragma unroll
            for (int c = 0; c < 8; ++c) acc[c] = fmaf(w, v[c], acc[c]);

            if (have_next) { u = un; pv = nv; }
            i1 = i2;
        }
    }

    // merge the 4 edge-groups (lane^16 / lane^32 hold matching channels)
#pragma unroll
    for (int o = 16; o <= 32; o <<= 1) {
        s += __shfl_xor(s, o, 64);
#pragma unroll
        for (int c = 0; c < 8; ++c) acc[c] += __shfl_xor(acc[c], o, 64);
    }

    int deg = end - beg;
    float inv = (deg > 0) ? 1.f / (s * (float)deg) : 0.f;
    float o8[8];
#pragma unroll
    for (int c = 0; c < 8; ++c) o8[c] = acc[c] * inv;
    if (bias != nullptr) {
#pragma unroll
        for (int c = 0; c < 8; ++c) o8[c] += bias[cb + c];
    }
    if (g == 0) {
        union { uint4 u; __hip_bfloat16 hh[8]; } pk;
#pragma unroll
        for (int c = 0; c < 8; ++c) pk.hh[c] = __float2bfloat16(o8[c]);
        *(uint4*)(outb + (size_t)dst * obstride + cb) = pk.u;
    }
}

// C=2, H=1 final layer: one thread per dst (fp32 xl/xr).
__global__ void gat_c2(const float* __restrict__ xl, const float* __restrict__ xr,
                       const int* __restrict__ row_off, const int* __restrict__ col,
                       const float* __restrict__ att, const float* __restrict__ bias,
                       float* __restrict__ out, int n_dst) {
    int dst = blockIdx.x * blockDim.x + threadIdx.x;
    if (dst >= n_dst) return;
    float x0 = xr[(size_t)dst * 2], x1 = xr[(size_t)dst * 2 + 1];
    float a0 = att[0], a1 = att[1];
    int beg = row_off[dst], end = row_off[dst + 1];
    float s = 0.f, acc0 = 0.f, acc1 = 0.f;
    for (int e = beg; e < end; ++e) {
        int src = col[e];
        float v0 = xl[(size_t)src * 2], v1 = xl[(size_t)src * 2 + 1];
        float z0 = v0 + x0; z0 = fmaxf(z0, NEG_SLOPE * z0);
        float z1 = v1 + x1; z1 = fmaxf(z1, NEG_SLOPE * z1);
        float p = fmaf(z0, a0, z1 * a1);
        float w = __expf(fminf(p, 85.f));
        s += w;
        acc0 = fmaf(w, v0, acc0);
        acc1 = fmaf(w, v1, acc1);
    }
    int deg = end - beg;
    float o0 = 0.f, o1 = 0.f;
    if (deg > 0) {
        float inv = 1.f / (s * (float)deg);
        o0 = acc0 * inv;
        o1 = acc1 * inv;
    }
    out[(size_t)dst * 2 + 0] = o0 + bias[0];
    out[(size_t)dst * 2 + 1] = o1 + bias[1];
}

// ---------------------------------------------------------------- BatchNorm stats (deterministic)
__global__ void bn_partial_d(const __hip_bfloat16* __restrict__ x, float* __restrict__ part,
                             int Nr, int rpb) {
    int C = blockDim.x;
    int c = threadIdx.x;
    int b = blockIdx.x;
    int r0 = b * rpb;
    int r1 = r0 + rpb; if (r1 > Nr) r1 = Nr;
    float s = 0.f, q = 0.f;
    for (int r = r0; r < r1; ++r) {
        float v = __bfloat162float(x[(size_t)r * C + c]);
        s += v;
        q = fmaf(v, v, q);
    }
    part[(size_t)b * C + c] = s;
    part[65536 + (size_t)b * C + c] = q;   // 256*256 slot offset
}

__global__ void bn_finalize_w(const float* __restrict__ part,
                              const float* __restrict__ g, const float* __restrict__ b,
                              float* __restrict__ scale, float* __restrict__ shift,
                              int Nr, int C) {
    int c = (blockIdx.x * blockDim.x + threadIdx.x) >> 6;
    int lane = threadIdx.x & 63;
    if (c >= C) return;
    float s = 0.f, q = 0.f;
    for (int blk = lane; blk < 256; blk += 64) {
        s += part[(size_t)blk * C + c];
        q += part[65536 + (size_t)blk * C + c];
    }
#pragma unroll
    for (int o = 32; o; o >>= 1) {
        s += __shfl_xor(s, o, 64);
        q += __shfl_xor(q, o, 64);
    }
    if (lane == 0) {
        float mu = s / (float)Nr;
        float var = q / (float)Nr - mu * mu;
        float inv = rsqrtf(var + 1e-5f);
        float a = g[c] * inv;
        scale[c] = a;
        shift[c] = b[c] - mu * a;
    }
}

// ---------------------------------------------------------------- driver
extern "C" void kernel_launch(void* const* d_in, const int* in_sizes, int n_in,
                              void* d_out, int out_size, void* d_ws, size_t ws_size,
                              hipStream_t stream) {
    const float* x_low  = (const float*)d_in[0];
    const float* x_high = (const float*)d_in[1];
    const float* z_std  = (const float*)d_in[2];
    const int* e_low  = (const int*)d_in[3];
    const int* e_l2h  = (const int*)d_in[4];
    const int* e_high = (const int*)d_in[5];
    const float* l1_Wl = (const float*)d_in[6];
    const float* l1_Wr = (const float*)d_in[7];
    const float* l1_att = (const float*)d_in[8];
    const float* l1_b  = (const float*)d_in[9];
    const float* bn1_g = (const float*)d_in[10];
    const float* bn1_b = (const float*)d_in[11];
    const float* l2_Wl = (const float*)d_in[12];
    const float* l2_Wr = (const float*)d_in[13];
    const float* l2_att = (const float*)d_in[14];
    const float* l2_b  = (const float*)d_in[15];
    const float* bn2_g = (const float*)d_in[16];
    const float* bn2_b = (const float*)d_in[17];
    const float* l3_Wl = (const float*)d_in[18];
    const float* l3_Wr = (const float*)d_in[19];
    const float* l3_att = (const float*)d_in[20];
    const float* l3_b  = (const float*)d_in[21];
    const float* lh_Wl = (const float*)d_in[22];
    const float* lh_Wr = (const float*)d_in[23];
    const float* lh_att = (const float*)d_in[24];
    const float* h1_Wl = (const float*)d_in[25];
    const float* h1_Wr = (const float*)d_in[26];
    const float* h1_att = (const float*)d_in[27];
    const float* h1_b  = (const float*)d_in[28];
    const float* bn3_g = (const float*)d_in[29];
    const float* bn3_b = (const float*)d_in[30];
    const float* h2_Wl = (const float*)d_in[31];
    const float* h2_Wr = (const float*)d_in[32];
    const float* h2_att = (const float*)d_in[33];
    const float* h2_b  = (const float*)d_in[34];
    const float* bn4_g = (const float*)d_in[35];
    const float* bn4_b = (const float*)d_in[36];
    const float* h3_Wl = (const float*)d_in[37];
    const float* h3_Wr = (const float*)d_in[38];
    const float* h3_att = (const float*)d_in[39];
    const float* h3_b  = (const float*)d_in[40];

    const int N_low = in_sizes[0] / 125;
    const int N_high = in_sizes[1];
    const int E_low = in_sizes[3] / 2;
    const int E_l2h = in_sizes[4] / 2;
    const int E_high = in_sizes[5] / 2;

    char* ws = (char*)d_ws;
    size_t woff = 0;
    auto walloc = [&](size_t bytes) -> void* {
        void* p = (void*)(ws + woff);
        woff += (bytes + 255) & ~(size_t)255;
        return p;
    };
    // XLR holds merged [XL|XR] GEMM outputs (max N_high x 512 bf16 = 61 MB).
    // Before the first GEMM it is dead -> the CSR stage array aliases it.
    __hip_bfloat16* XLR = (__hip_bfloat16*)walloc((size_t)N_high * 512 * 2);
    __hip_bfloat16* A1  = (__hip_bfloat16*)walloc((size_t)N_high * 256 * 2);
    __hip_bfloat16* A2  = (__hip_bfloat16*)walloc((size_t)N_high * 128 * 2);
    __hip_bfloat16* XRo = (__hip_bfloat16*)walloc((size_t)N_high * 128 * 2); // lh outer xr
    __hip_bfloat16* XLOWB = (__hip_bfloat16*)walloc((size_t)N_low * 128 * 2);
    __hip_bfloat16* EHB = (__hip_bfloat16*)walloc((size_t)N_high * 160 * 2);
    float* YL = (float*)walloc((size_t)N_high * 2 * 4);
    float* YR = (float*)walloc((size_t)N_high * 2 * 4);
    int* off_low  = (int*)walloc((size_t)(N_low + 1) * 4);
    int* col_low  = (int*)walloc((size_t)E_low * 4);
    int* off_l2h  = (int*)walloc((size_t)(N_high + 1) * 4);
    int* col_l2h  = (int*)walloc((size_t)E_l2h * 4);
    int* off_high = (int*)walloc((size_t)(N_high + 1) * 4);
    int* col_high = (int*)walloc((size_t)E_high * 4);
    // multisplit CSR state
    const int nc0 = (N_low + CBS - 1) >> CSH;
    const int nc1 = (N_high + CBS - 1) >> CSH;
    const int nc2 = (N_high + CBS - 1) >> CSH;
    const int NBC = nc0 + nc1 + nc2;
    const long Etot = (long)E_low + E_l2h + E_high;
    const long chunk = (Etot + PB - 1) / PB;
    auto capf = [&](int ng) {
        double m = (double)chunk * CBS / ng;
        int c = (int)(m + 8.0 * sqrt(m) + 16.0);
        return (c + 15) & ~15;
    };
    const int cap0 = capf(N_low);
    const int cap1 = capf(N_high);
    const int cap2 = capf(N_high);
    int* cnt2   = (int*)walloc((size_t)PB * NBC * 4);
    int* cstart = (int*)walloc((size_t)(NBC + 1) * 4);
    int* ctot   = (int*)walloc((size_t)(NBC + 1) * 4);
    float* bnpart = (float*)walloc(2 * 256 * 256 * 4);   // deterministic BN partials
    float* bnsc   = (float*)walloc(512 * 4);             // scale | shift
    float* bb     = (float*)walloc(512 * 4);             // folded gemm bias
    // merged [Wl|Wr] bf16 transposed weights [Ncat][Kp]
    __hip_bfloat16* w_l1 = (__hip_bfloat16*)walloc(512 * 128 * 2);
    __hip_bfloat16* w_l2 = (__hip_bfloat16*)walloc(256 * 256 * 2);
    __hip_bfloat16* w_l3 = (__hip_bfloat16*)walloc(256 * 128 * 2);
    __hip_bfloat16* w_lh = (__hip_bfloat16*)walloc(128 * 128 * 2);
    __hip_bfloat16* w_h1 = (__hip_bfloat16*)walloc(512 * 160 * 2);
    __hip_bfloat16* w_h2 = (__hip_bfloat16*)walloc(256 * 256 * 2);

    int* stage = (int*)XLR;   // PB=1024: ~52 MB needed, 61 MB available; dead until first gemm

    // ---- batched prep: all static converts + EHB pad/z init in ONE launch
    {
        int o1 = N_low * 128;              // xconv
        int o2 = o1 + N_high * 128;        // outer_xr
        int o3 = o2 + N_high * 32;         // EHB cols 128..159
        int o4 = o3 + 256 * 128;           // w_l1 Wl
        int o5 = o4 + 256 * 128;           // w_l1 Wr
        int o6 = o5 + 128 * 128;           // w_lh
        int o7 = o6 + 256 * 160;           // w_h1 Wl
        int o8 = o7 + 256 * 160;           // w_h1 Wr
        prep_all<<<(o8 + 255) / 256, 256, 0, stream>>>(
            l1_Wl, l1_Wr, lh_Wl, h1_Wl, h1_Wr, x_low, x_high, lh_Wr, z_std,
            w_l1, w_lh, w_h1, XLOWB, XRo, EHB,
            o1, o2, o3, o4, o5, o6, o7, o8);
    }

    // ---- multisplit CSR build for all 3 graphs (4 launches, no global atomics)
    msplitA<<<PB, 256, 0, stream>>>(
        e_low, e_low + E_low, E_low,
        e_l2h, e_l2h + E_l2h, E_l2h,
        e_high, e_high + E_high, E_high,
        nc0, nc1, nc2, cap0, cap1, cap2, stage, cnt2);
    scanC1<<<NBC, 256, 0, stream>>>(cnt2, ctot, NBC);
    scanC2<<<1, 64, 0, stream>>>(ctot, cstart, NBC, nc0, nc1);
    fineB<<<NBC, 1024, 0, stream>>>(cnt2, cstart, stage,
                                    nc0, nc1, nc2, cap0, cap1, cap2,
                                    off_low, col_low, N_low,
                                    off_l2h, col_l2h, N_high,
                                    off_high, col_high, N_high);

    auto gemm = [&](const __hip_bfloat16* A, const __hip_bfloat16* Bt, __hip_bfloat16* C,
                    int M, int N, int Kp, const float* bias) {
        dim3 g(N / 128, (M + 127) / 128);
        gemm_bf16_mfma<<<g, 256, 0, stream>>>(A, Bt, C, bias, M, N, Kp);
    };
    auto gat = [&](const __hip_bfloat16* xl, int xls, const __hip_bfloat16* xr, int xrs,
                   const int* roff, const int* colv,
                   const float* att, const float* bias,
                   __hip_bfloat16* outb, int obs, int n_dst, int H) {
        long thr = (long)n_dst * H * 64;
        gat_c128_v4<<<(unsigned)((thr + 255) / 256), 256, 0, stream>>>(
            xl, xls, xr, xrs, roff, colv, att, bias, outb, obs, n_dst, H);
    };
    // deterministic BN stats only (apply is folded into the consumer GEMM weights)
    auto bn_stats = [&](__hip_bfloat16* x, const float* g, const float* b, int Nr, int C) {
        int rpb = (Nr + 255) / 256;
        bn_partial_d<<<256, C, 0, stream>>>(x, bnpart, Nr, rpb);
        bn_finalize_w<<<(C * 64 + 255) / 256, 256, 0, stream>>>(bnpart, g, b, bnsc, bnsc + 256, Nr, C);
    };
    // fold bn (bnsc) into a merged [Wl|Wr] weight + bias pair (one launch)
    auto fold2 = [&](const float* Wl, const float* Wr, __hip_bfloat16* Wt,
                     int K, int Nn, int Kp) {
        dim3 g(Nn, 2);
        wconv_bnfold2<<<g, 256, 0, stream>>>(Wl, Wr, bnsc, bnsc + 256, Wt, bb, K, Nn, Kp);
    };

    // ---- low_net layer 1: 125 -> (H=2) 256   (merged [XL|XR], stride 512)
    gemm(XLOWB, w_l1, XLR, N_low, 512, 128, nullptr);
    gat(XLR, 512, XLR + 256, 512, off_low, col_low, l1_att, l1_b, A1, 256, N_low, 2);
    bn_stats(A1, bn1_g, bn1_b, N_low, 256);

    // ---- low_net layer 2: 256 -> 128 (BN1 folded into w_l2 + bias)
    fold2(l2_Wl, l2_Wr, w_l2, 256, 128, 256);
    gemm(A1, w_l2, XLR, N_low, 256, 256, bb);
    gat(XLR, 256, XLR + 128, 256, off_low, col_low, l2_att, l2_b, A2, 128, N_low, 1);
    bn_stats(A2, bn2_g, bn2_b, N_low, 128);

    // ---- low_net layer 3: 128 -> 128 (BN2 folded into w_l3 + bias)
    fold2(l3_Wl, l3_Wr, w_l3, 128, 128, 128);
    gemm(A2, w_l3, XLR, N_low, 256, 128, bb);
    gat(XLR, 256, XLR + 128, 256, off_low, col_low, l3_att, l3_b, A1, 128, N_low, 1);

    // ---- bipartite low2high -> EHB[N_high][160] = [gat 0..127 | z | pad] (pad/z pre-inited)
    gemm(A1, w_lh, XLR, N_low, 128, 128, nullptr);   // xl only, stride 128
    gat(XLR, 128, XRo, 128, off_l2h, col_l2h, lh_att, nullptr, EHB, 160, N_high, 1);

    // ---- high_net layer 1: 129(perm,pad160) -> (H=2) 256   (merged, stride 512)
    gemm(EHB, w_h1, XLR, N_high, 512, 160, nullptr);
    gat(XLR, 512, XLR + 256, 512, off_high, col_high, h1_att, h1_b, A1, 256, N_high, 2);
    bn_stats(A1, bn3_g, bn3_b, N_high, 256);

    // ---- high_net layer 2: 256 -> 128 (BN3 folded into w_h2 + bias)
    fold2(h2_Wl, h2_Wr, w_h2, 256, 128, 256);
    gemm(A1, w_h2, XLR, N_high, 256, 256, bb);
    gat(XLR, 256, XLR + 128, 256, off_high, col_high, h2_att, h2_b, A2, 128, N_high, 1);
    bn_stats(A2, bn4_g, bn4_b, N_high, 128);

    // ---- high_net layer 3: 128 -> 2 (BN4 applied inline in f32; one pass over A2)
    gemm_n22_bn<<<(N_high + 255) / 256, 256, 0, stream>>>(A2, h3_Wl, h3_Wr,
                                                          bnsc, bnsc + 256, YL, YR, N_high, 128);
    gat_c2<<<(N_high + 255) / 256, 256, 0, stream>>>(YL, YR, off_high, col_high,
                                                     h3_att, h3_b, (float*)d_out, N_high);
}